// Round 1
// baseline (2045.001 us; speedup 1.0000x reference)
//
#include <hip/hip_runtime.h>
#include <math.h>

#define B_ 4
#define N_ 4096
#define KP 512
#define C_ 384

constexpr float TAU_INV  = 10.0f;   // 1/max(0.1,1e-6)
constexpr float BETA_    = 0.85f;
constexpr float JITTER_  = 1e-6f;
constexpr float ALPHA_   = 1.5f;
constexpr float SFLOOR_  = 1e-3f;
constexpr float SCEIL_   = 100.0f;
constexpr float MU_SCALE_= 0.25f;
constexpr float NEGV     = -1e9f;
constexpr float BIG_     = 1e9f;

__device__ __forceinline__ float dot4f(float4 a, float4 b) {
  return a.x*b.x + a.y*b.y + a.z*b.z + a.w*b.w;
}

// ---------------- K1: parents -> kkT (transposed) and vv ----------------
// grid: B*KP/8 blocks, 128 threads. Rows = 8 parent rows per block.
__global__ __launch_bounds__(128) void k_kvproj(
    const float* __restrict__ sp, const float* __restrict__ mu_p,
    const float* __restrict__ gk, const float* __restrict__ bk,
    const float* __restrict__ gv, const float* __restrict__ bv,
    const float* __restrict__ Wk, const float* __restrict__ Wv,
    const float* __restrict__ Wpos,
    float* __restrict__ kkT, float* __restrict__ vvo) {
  __shared__ float xk[8*C_];
  __shared__ float xvn[8*C_];
  int t = threadIdx.x;
  int pr0 = blockIdx.x * 8;
  {
    int r = t >> 4, l = t & 15;
    const float* xr = sp + (size_t)(pr0 + r) * C_;
    float xv[24]; float s = 0.f;
    #pragma unroll
    for (int j = 0; j < 24; ++j) { xv[j] = xr[l + 16*j]; s += xv[j]; }
    #pragma unroll
    for (int m = 1; m < 16; m <<= 1) s += __shfl_xor(s, m);
    float mean = s * (1.0f/C_);
    float vs = 0.f;
    #pragma unroll
    for (int j = 0; j < 24; ++j) { float d = xv[j]-mean; vs += d*d; }
    #pragma unroll
    for (int m = 1; m < 16; m <<= 1) vs += __shfl_xor(vs, m);
    float rs = 1.0f / sqrtf(vs * (1.0f/C_) + 1e-5f);
    #pragma unroll
    for (int j = 0; j < 24; ++j) {
      int c = l + 16*j;
      float xc = (xv[j]-mean)*rs;
      xk [r*C_ + c] = xc*gk[c] + bk[c];
      xvn[r*C_ + c] = xc*gv[c] + bv[c];
    }
  }
  __syncthreads();
  int rg = t >> 6, ch = t & 63, r0 = rg * 4;
  float accK[4][6], accV[4][6];
  #pragma unroll
  for (int j=0;j<4;++j)
    #pragma unroll
    for (int sI=0;sI<6;++sI) { accK[j][sI]=0.f; accV[j][sI]=0.f; }
  for (int c4 = 0; c4 < C_; c4 += 4) {
    float4 a4[4], b4[4];
    #pragma unroll
    for (int j=0;j<4;++j) {
      a4[j] = *(const float4*)&xk [(r0+j)*C_ + c4];
      b4[j] = *(const float4*)&xvn[(r0+j)*C_ + c4];
    }
    #pragma unroll
    for (int sI=0;sI<6;++sI) {
      int i = ch + 64*sI;
      float4 wk4 = *(const float4*)&Wk[(size_t)i*C_ + c4];
      float4 wv4 = *(const float4*)&Wv[(size_t)i*C_ + c4];
      #pragma unroll
      for (int j=0;j<4;++j) {
        accK[j][sI] += dot4f(a4[j], wk4);
        accV[j][sI] += dot4f(b4[j], wv4);
      }
    }
  }
  #pragma unroll
  for (int j=0;j<4;++j) {
    int prow = pr0 + r0 + j;
    int b = prow >> 9, kp = prow & (KP-1);
    float m0 = mu_p[(size_t)prow*3+0];
    float m1 = mu_p[(size_t)prow*3+1];
    float m2 = mu_p[(size_t)prow*3+2];
    #pragma unroll
    for (int sI=0;sI<6;++sI) {
      int i = ch + 64*sI;
      float kvv = accK[j][sI] + m0*Wpos[i*3+0] + m1*Wpos[i*3+1] + m2*Wpos[i*3+2];
      kkT[((size_t)b*C_ + i)*KP + kp] = kvv;
      vvo[(size_t)prow*C_ + i] = accV[j][sI];
    }
  }
}

// ---------------- K2: s_trunk -> q ----------------
__global__ __launch_bounds__(128) void k_qproj(
    const float* __restrict__ st, const float* __restrict__ g,
    const float* __restrict__ bb, const float* __restrict__ W,
    float* __restrict__ qout) {
  __shared__ float xln[8*C_];
  int t = threadIdx.x;
  int row0 = blockIdx.x * 8;
  {
    int r = t >> 4, l = t & 15;
    const float* xr = st + (size_t)(row0 + r) * C_;
    float xv[24]; float s = 0.f;
    #pragma unroll
    for (int j = 0; j < 24; ++j) { xv[j] = xr[l + 16*j]; s += xv[j]; }
    #pragma unroll
    for (int m = 1; m < 16; m <<= 1) s += __shfl_xor(s, m);
    float mean = s * (1.0f/C_);
    float vs = 0.f;
    #pragma unroll
    for (int j = 0; j < 24; ++j) { float d = xv[j]-mean; vs += d*d; }
    #pragma unroll
    for (int m = 1; m < 16; m <<= 1) vs += __shfl_xor(vs, m);
    float rs = 1.0f / sqrtf(vs * (1.0f/C_) + 1e-5f);
    #pragma unroll
    for (int j = 0; j < 24; ++j) {
      int c = l + 16*j;
      xln[r*C_ + c] = (xv[j]-mean)*rs*g[c] + bb[c];
    }
  }
  __syncthreads();
  int rg = t >> 6, ch = t & 63, r0 = rg * 4;
  float acc[4][6];
  #pragma unroll
  for (int j=0;j<4;++j)
    #pragma unroll
    for (int sI=0;sI<6;++sI) acc[j][sI]=0.f;
  for (int c4 = 0; c4 < C_; c4 += 4) {
    float4 xr4[4];
    #pragma unroll
    for (int j=0;j<4;++j) xr4[j] = *(const float4*)&xln[(r0+j)*C_ + c4];
    #pragma unroll
    for (int sI=0;sI<6;++sI) {
      int i = ch + 64*sI;
      float4 wv = *(const float4*)&W[(size_t)i*C_ + c4];
      #pragma unroll
      for (int j=0;j<4;++j) acc[j][sI] += dot4f(xr4[j], wv);
    }
  }
  #pragma unroll
  for (int j=0;j<4;++j)
    #pragma unroll
    for (int sI=0;sI<6;++sI)
      qout[(size_t)(row0 + r0 + j)*C_ + ch + 64*sI] = acc[j][sI];
}

// ---------------- K3: logits -> softmax -> weighted sums ----------------
// grid: (N/16, B), 256 threads. LDS: q tile 24KB + w 32KB.
__global__ __launch_bounds__(256) void k_route(
    const float* __restrict__ q, const float* __restrict__ kkT,
    const float* __restrict__ vvm, const float* __restrict__ sp,
    const float* __restrict__ mu_p, const float* __restrict__ Sig_p,
    const float* __restrict__ mask_parent, const float* __restrict__ node_mask,
    float* __restrict__ out, float* __restrict__ pf,
    float* __restrict__ mu0, float* __restrict__ sigpc) {
  __shared__ float qs[16*C_];
  __shared__ float w[16*KP];
  int t = threadIdx.x;
  int b = blockIdx.y;
  int n0 = blockIdx.x * 16;
  {
    const float* qrow = q + ((size_t)b*N_ + n0)*C_;
    for (int idx = t; idx < 16*C_; idx += 256) qs[idx] = qrow[idx];
  }
  __syncthreads();
  // phase 1: logits
  {
    int rg = t >> 6, ch = t & 63, r0 = rg*4;
    float acc[4][8];
    #pragma unroll
    for (int j=0;j<4;++j)
      #pragma unroll
      for (int e=0;e<8;++e) acc[j][e]=0.f;
    const float* kbase = kkT + (size_t)b*C_*KP;
    for (int c = 0; c < C_; ++c) {
      float qv[4];
      #pragma unroll
      for (int j=0;j<4;++j) qv[j] = qs[(r0+j)*C_ + c];
      #pragma unroll
      for (int sI=0;sI<2;++sI) {
        float4 kv = *(const float4*)&kbase[(size_t)c*KP + ch*4 + 256*sI];
        #pragma unroll
        for (int j=0;j<4;++j) {
          acc[j][sI*4+0] += qv[j]*kv.x;
          acc[j][sI*4+1] += qv[j]*kv.y;
          acc[j][sI*4+2] += qv[j]*kv.z;
          acc[j][sI*4+3] += qv[j]*kv.w;
        }
      }
    }
    #pragma unroll
    for (int sI=0;sI<2;++sI) {
      int k0 = ch*4 + 256*sI;
      float4 mp4 = *(const float4*)&mask_parent[(size_t)b*KP + k0];
      #pragma unroll
      for (int j=0;j<4;++j) {
        float4 lv;
        lv.x = (mp4.x > 0.5f) ? acc[j][sI*4+0]*TAU_INV : NEGV;
        lv.y = (mp4.y > 0.5f) ? acc[j][sI*4+1]*TAU_INV : NEGV;
        lv.z = (mp4.z > 0.5f) ? acc[j][sI*4+2]*TAU_INV : NEGV;
        lv.w = (mp4.w > 0.5f) ? acc[j][sI*4+3]*TAU_INV : NEGV;
        *(float4*)&w[(r0+j)*KP + k0] = lv;
      }
    }
  }
  __syncthreads();
  // phase 2: softmax (16 lanes per row)
  {
    int r = t >> 4, l = t & 15;
    float* wr = &w[r*KP];
    float mx = -3.4e38f;
    #pragma unroll
    for (int j=0;j<32;++j) mx = fmaxf(mx, wr[l + 16*j]);
    #pragma unroll
    for (int m = 1; m < 16; m <<= 1) mx = fmaxf(mx, __shfl_xor(mx, m));
    float sm = 0.f;
    #pragma unroll
    for (int j=0;j<32;++j) {
      float e = expf(wr[l+16*j] - mx);
      wr[l+16*j] = e; sm += e;
    }
    #pragma unroll
    for (int m = 1; m < 16; m <<= 1) sm += __shfl_xor(sm, m);
    float nm = node_mask[(size_t)b*N_ + n0 + r];
    if (nm > 0.5f) {
      float sc = nm / sm;
      #pragma unroll
      for (int j=0;j<32;++j) wr[l+16*j] *= sc;
    } else {
      // reference: whole logits row -> NEG -> uniform softmax, then * nm
      float u = nm * (1.0f/KP);
      #pragma unroll
      for (int j=0;j<32;++j) wr[l+16*j] = u;
    }
  }
  __syncthreads();
  // phase 3: s0 = w@vv, pf = w@s_parent
  {
    int rg = t >> 6, ch = t & 63, r0 = rg*4;
    float accS[4][3][2], accP[4][3][2];
    #pragma unroll
    for (int j=0;j<4;++j)
      #pragma unroll
      for (int sI=0;sI<3;++sI) {
        accS[j][sI][0]=0.f; accS[j][sI][1]=0.f;
        accP[j][sI][0]=0.f; accP[j][sI][1]=0.f;
      }
    const float* vb = vvm + (size_t)b*KP*C_;
    const float* pb = sp  + (size_t)b*KP*C_;
    for (int k4 = 0; k4 < KP; k4 += 4) {
      float wcomp[4][4];
      #pragma unroll
      for (int j=0;j<4;++j) {
        float4 t4 = *(const float4*)&w[(r0+j)*KP + k4];
        wcomp[0][j]=t4.x; wcomp[1][j]=t4.y; wcomp[2][j]=t4.z; wcomp[3][j]=t4.w;
      }
      #pragma unroll
      for (int kk=0; kk<4; ++kk) {
        size_t k = (size_t)(k4 + kk);
        #pragma unroll
        for (int sI=0;sI<3;++sI) {
          int i = ch*2 + 128*sI;
          float2 v2 = *(const float2*)&vb[k*C_ + i];
          float2 p2 = *(const float2*)&pb[k*C_ + i];
          #pragma unroll
          for (int j=0;j<4;++j) {
            float wj = wcomp[kk][j];
            accS[j][sI][0] += wj*v2.x; accS[j][sI][1] += wj*v2.y;
            accP[j][sI][0] += wj*p2.x; accP[j][sI][1] += wj*p2.y;
          }
        }
      }
    }
    #pragma unroll
    for (int j=0;j<4;++j) {
      int n = n0 + r0 + j;
      size_t row = (size_t)b*N_ + n;
      size_t orow = row * 396;
      #pragma unroll
      for (int sI=0;sI<3;++sI) {
        int i = ch*2 + 128*sI;
        *(float2*)&out[orow + i] = make_float2(accS[j][sI][0], accS[j][sI][1]);
        *(float2*)&pf[row*C_ + i] = make_float2(accP[j][sI][0], accP[j][sI][1]);
      }
    }
  }
  // tail: mu0 = w@mu_p, sigpc = w@sym(Sig_p) + J*I  (w is read-only now)
  if (t < 192) {
    int r = t / 12, cm = t % 12;
    int n = n0 + r;
    const float* wr = &w[r*KP];
    size_t row = (size_t)b*N_ + n;
    float a = 0.f;
    if (cm < 3) {
      const float* mb = mu_p + (size_t)b*KP*3;
      for (int k=0;k<KP;++k) a += wr[k]*mb[k*3+cm];
      mu0[row*3+cm] = a;
    } else {
      int e = cm - 3; int ii = e/3, jj = e%3;
      const float* sb = Sig_p + (size_t)b*KP*9;
      for (int k=0;k<KP;++k)
        a += wr[k]*0.5f*(sb[k*9 + ii*3 + jj] + sb[k*9 + jj*3 + ii]);
      if (ii == jj) a += JITTER_;
      sigpc[row*9+e] = a;
    }
  }
}

// ---------------- K4: mu-offset MLP, update mu0 ----------------
__global__ __launch_bounds__(128) void k_mlp(
    const float* __restrict__ pf, const float* __restrict__ g,
    const float* __restrict__ bb, const float* __restrict__ W1,
    const float* __restrict__ b1, const float* __restrict__ W2,
    const float* __restrict__ b2v, const float* __restrict__ node_mask,
    float* __restrict__ mu0) {
  __shared__ float xln[8*C_];
  __shared__ float h[8*C_];
  int t = threadIdx.x;
  int row0 = blockIdx.x * 8;
  {
    int r = t >> 4, l = t & 15;
    const float* xr = pf + (size_t)(row0 + r) * C_;
    float xv[24]; float s = 0.f;
    #pragma unroll
    for (int j = 0; j < 24; ++j) { xv[j] = xr[l + 16*j]; s += xv[j]; }
    #pragma unroll
    for (int m = 1; m < 16; m <<= 1) s += __shfl_xor(s, m);
    float mean = s * (1.0f/C_);
    float vs = 0.f;
    #pragma unroll
    for (int j = 0; j < 24; ++j) { float d = xv[j]-mean; vs += d*d; }
    #pragma unroll
    for (int m = 1; m < 16; m <<= 1) vs += __shfl_xor(vs, m);
    float rs = 1.0f / sqrtf(vs * (1.0f/C_) + 1e-5f);
    #pragma unroll
    for (int j = 0; j < 24; ++j) {
      int c = l + 16*j;
      xln[r*C_ + c] = (xv[j]-mean)*rs*g[c] + bb[c];
    }
  }
  __syncthreads();
  {
    int rg = t >> 6, ch = t & 63, r0 = rg*4;
    float acc[4][6];
    #pragma unroll
    for (int j=0;j<4;++j)
      #pragma unroll
      for (int sI=0;sI<6;++sI) acc[j][sI]=0.f;
    for (int c4 = 0; c4 < C_; c4 += 4) {
      float4 xr4[4];
      #pragma unroll
      for (int j=0;j<4;++j) xr4[j] = *(const float4*)&xln[(r0+j)*C_ + c4];
      #pragma unroll
      for (int sI=0;sI<6;++sI) {
        int i = ch + 64*sI;
        float4 wv = *(const float4*)&W1[(size_t)i*C_ + c4];
        #pragma unroll
        for (int j=0;j<4;++j) acc[j][sI] += dot4f(xr4[j], wv);
      }
    }
    #pragma unroll
    for (int j=0;j<4;++j)
      #pragma unroll
      for (int sI=0;sI<6;++sI) {
        int i = ch + 64*sI;
        float v = acc[j][sI] + b1[i];
        h[(r0+j)*C_ + i] = v / (1.0f + expf(-v));   // silu
      }
  }
  __syncthreads();
  {
    int r = t >> 4, l = t & 15;
    const float* hr = &h[r*C_];
    float pd0=0.f, pd1=0.f, pd2=0.f;
    #pragma unroll
    for (int j=0;j<24;++j) {
      int c = l + 16*j;
      float hv = hr[c];
      pd0 += hv*W2[c];
      pd1 += hv*W2[C_ + c];
      pd2 += hv*W2[2*C_ + c];
    }
    #pragma unroll
    for (int m = 1; m < 16; m <<= 1) {
      pd0 += __shfl_xor(pd0, m);
      pd1 += __shfl_xor(pd1, m);
      pd2 += __shfl_xor(pd2, m);
    }
    if (l == 0) {
      size_t row = (size_t)(row0 + r);
      float nm = node_mask[row];
      float d0 = (pd0 + b2v[0]) * MU_SCALE_;
      float d1 = (pd1 + b2v[1]) * MU_SCALE_;
      float d2 = (pd2 + b2v[2]) * MU_SCALE_;
      mu0[row*3+0] = (mu0[row*3+0] + d0) * nm;
      mu0[row*3+1] = (mu0[row*3+1] + d1) * nm;
      mu0[row*3+2] = (mu0[row*3+2] + d2) * nm;
    }
  }
}

// ---------------- K5: kNN sigma + Sig0 + final mu0 write ----------------
// grid (N/64, B), 256 threads: 64 rows x 4 threads per row.
__global__ __launch_bounds__(256) void k_knn(
    const float* __restrict__ mu0, const float* __restrict__ node_mask,
    const float* __restrict__ sigpc, float* __restrict__ out) {
  __shared__ float mxs[N_];
  __shared__ float mys[N_];
  __shared__ float mzs[N_];
  __shared__ float mrg[64*32];
  int t = threadIdx.x;
  int b = blockIdx.y;
  int n0 = blockIdx.x * 64;
  const float* mb = mu0 + (size_t)b*N_*3;
  for (int idx = t; idx < N_; idx += 256) {
    mxs[idx] = mb[idx*3+0];
    mys[idx] = mb[idx*3+1];
    mzs[idx] = mb[idx*3+2];
  }
  __syncthreads();
  int r = t >> 2, qq = t & 3;
  int n = n0 + r;
  float ex = mxs[n], ey = mys[n], ez = mzs[n];
  const float* nmB = node_mask + (size_t)b*N_;
  float best[8];
  #pragma unroll
  for (int i=0;i<8;++i) best[i] = BIG_;
  int m0 = qq * (N_/4);
  for (int m = m0; m < m0 + N_/4; ++m) {
    float dx = mxs[m]-ex, dy = mys[m]-ey, dz = mzs[m]-ez;
    float d2 = dx*dx + dy*dy + dz*dz;
    if (m == n || nmB[m] <= 0.5f) d2 = BIG_;
    if (d2 < best[7]) {
      #pragma unroll
      for (int i = 7; i >= 1; --i)
        best[i] = (best[i] > d2) ? ((best[i-1] > d2) ? best[i-1] : d2) : best[i];
      best[0] = (best[0] > d2) ? d2 : best[0];
    }
  }
  #pragma unroll
  for (int i=0;i<8;++i) mrg[(r*4+qq)*8 + i] = best[i];
  __syncthreads();
  if (qq == 0) {
    float arr[32];
    #pragma unroll
    for (int i=0;i<32;++i) arr[i] = mrg[r*32 + i];
    float ssum = 0.f;
    #pragma unroll
    for (int sel=0; sel<8; ++sel) {
      float mn = arr[0];
      #pragma unroll
      for (int i=1;i<32;++i) mn = fminf(mn, arr[i]);
      ssum += sqrtf(fmaxf(mn, 0.f));
      bool done = false;
      #pragma unroll
      for (int i=0;i<32;++i) {
        bool hit = (!done) && (arr[i] == mn);
        arr[i] = hit ? BIG_ : arr[i];
        done = done || hit;
      }
    }
    float sigma = fminf(fmaxf(ALPHA_ * (ssum * 0.125f), SFLOOR_), SCEIL_);
    float s2 = sigma*sigma + JITTER_;   // Sig_sp diagonal
    size_t row = (size_t)b*N_ + n;
    float nm = nmB[n];
    size_t orow = row * 396;
    const float* sg = &sigpc[row*9];
    #pragma unroll
    for (int e=0;e<9;++e) {
      bool diag = (e==0)||(e==4)||(e==8);
      float v = BETA_*sg[e] + (diag ? ((1.0f-BETA_)*s2 + JITTER_) : 0.0f);
      out[orow + 387 + e] = v * nm;
    }
    out[orow + 384] = mxs[n];
    out[orow + 385] = mys[n];
    out[orow + 386] = mzs[n];
  }
}

extern "C" void kernel_launch(void* const* d_in, const int* in_sizes, int n_in,
                              void* d_out, int out_size, void* d_ws, size_t ws_size,
                              hipStream_t stream) {
  const float* s_parent    = (const float*)d_in[0];
  const float* mu_p        = (const float*)d_in[1];
  const float* Sig_p       = (const float*)d_in[2];
  const float* mask_parent = (const float*)d_in[3];
  const float* node_mask   = (const float*)d_in[4];
  const float* s_trunk     = (const float*)d_in[5];
  const float* Wq   = (const float*)d_in[6];
  const float* Wk   = (const float*)d_in[7];
  const float* Wv   = (const float*)d_in[8];
  const float* Wpos = (const float*)d_in[9];
  const float* lnq_g = (const float*)d_in[10];
  const float* lnq_b = (const float*)d_in[11];
  const float* lnk_g = (const float*)d_in[12];
  const float* lnk_b = (const float*)d_in[13];
  const float* lnv_g = (const float*)d_in[14];
  const float* lnv_b = (const float*)d_in[15];
  const float* mo_ln_g = (const float*)d_in[16];
  const float* mo_ln_b = (const float*)d_in[17];
  const float* mo_W1 = (const float*)d_in[18];
  const float* mo_b1 = (const float*)d_in[19];
  const float* mo_W2 = (const float*)d_in[20];
  const float* mo_b2 = (const float*)d_in[21];

  float* ws  = (float*)d_ws;
  float* q   = ws;
  float* kkT = q   + (size_t)B_*N_*C_;
  float* vv  = kkT + (size_t)B_*C_*KP;
  float* pf  = vv  + (size_t)B_*KP*C_;
  float* mu0 = pf  + (size_t)B_*N_*C_;
  float* sg  = mu0 + (size_t)B_*N_*3;
  float* out = (float*)d_out;

  // K1: parents -> kkT, vv
  k_kvproj<<<dim3(B_*KP/8), dim3(128), 0, stream>>>(
      s_parent, mu_p, lnk_g, lnk_b, lnv_g, lnv_b, Wk, Wv, Wpos, kkT, vv);
  // K2: s_trunk -> q
  k_qproj<<<dim3(B_*N_/8), dim3(128), 0, stream>>>(
      s_trunk, lnq_g, lnq_b, Wq, q);
  // K3: router + weighted sums
  k_route<<<dim3(N_/16, B_), dim3(256), 0, stream>>>(
      q, kkT, vv, s_parent, mu_p, Sig_p, mask_parent, node_mask,
      out, pf, mu0, sg);
  // K4: mu-offset MLP
  k_mlp<<<dim3(B_*N_/8), dim3(128), 0, stream>>>(
      pf, mo_ln_g, mo_ln_b, mo_W1, mo_b1, mo_W2, mo_b2, node_mask, mu0);
  // K5: kNN sigma + Sig0 + mu0 out
  k_knn<<<dim3(N_/64, B_), dim3(256), 0, stream>>>(
      mu0, node_mask, sg, out);
}

// Round 2
// 948.011 us; speedup vs baseline: 2.1571x; 2.1571x over previous
//
#include <hip/hip_runtime.h>
#include <math.h>

#define B_ 4
#define N_ 4096
#define KP 512
#define C_ 384

constexpr float TAU_INV  = 10.0f;
constexpr float BETA_    = 0.85f;
constexpr float JITTER_  = 1e-6f;
constexpr float ALPHA_   = 1.5f;
constexpr float SFLOOR_  = 1e-3f;
constexpr float SCEIL_   = 100.0f;
constexpr float MU_SCALE_= 0.25f;
constexpr float NEGV     = -1e9f;
constexpr float BIG_     = 1e9f;

// ---------------- K0: 384x384 transpose (W[i][c] -> WT[c][i]) ----------------
__global__ __launch_bounds__(256) void k_transpose(
    const float* __restrict__ W, float* __restrict__ WT) {
  __shared__ float tile[32][33];
  int bx = blockIdx.x * 32, by = blockIdx.y * 32;
  int tx = threadIdx.x, ty = threadIdx.y;   // 32 x 8
  #pragma unroll
  for (int j = 0; j < 32; j += 8)
    tile[ty + j][tx] = W[(size_t)(by + ty + j) * C_ + bx + tx];
  __syncthreads();
  #pragma unroll
  for (int j = 0; j < 32; j += 8)
    WT[(size_t)(bx + ty + j) * C_ + by + tx] = tile[tx][ty + j];
}

// ---------------- K1: parents -> kkT (transposed) and vv ----------------
// 8 parent rows / block, 256 threads.
__global__ __launch_bounds__(256) void k_kvproj(
    const float* __restrict__ sp, const float* __restrict__ mu_p,
    const float* __restrict__ gk, const float* __restrict__ bk,
    const float* __restrict__ gv, const float* __restrict__ bv,
    const float* __restrict__ wkT, const float* __restrict__ wvT,
    const float* __restrict__ Wpos,
    float* __restrict__ kkT, float* __restrict__ vvo) {
  __shared__ float sm[2*8*C_];     // xk | xvn ; later kres[384][9] aliases sm
  float* xk  = sm;
  float* xvn = sm + 8*C_;
  int t = threadIdx.x;
  int pr0 = blockIdx.x * 8;
  if (t < 128) {
    int r = t >> 4, l = t & 15;
    const float* xr = sp + (size_t)(pr0 + r) * C_;
    float xv[24]; float s = 0.f;
    #pragma unroll
    for (int j = 0; j < 24; ++j) { xv[j] = xr[l + 16*j]; s += xv[j]; }
    #pragma unroll
    for (int m = 1; m < 16; m <<= 1) s += __shfl_xor(s, m);
    float mean = s * (1.0f/C_);
    float vs = 0.f;
    #pragma unroll
    for (int j = 0; j < 24; ++j) { float d = xv[j]-mean; vs += d*d; }
    #pragma unroll
    for (int m = 1; m < 16; m <<= 1) vs += __shfl_xor(vs, m);
    float rs = 1.0f / sqrtf(vs * (1.0f/C_) + 1e-5f);
    #pragma unroll
    for (int j = 0; j < 24; ++j) {
      int c = l + 16*j;
      float xc = (xv[j]-mean)*rs;
      xk [r*C_ + c] = xc*gk[c] + bk[c];
      xvn[r*C_ + c] = xc*gv[c] + bv[c];
    }
  }
  __syncthreads();
  int w = t >> 6, ch = t & 63;
  int r0 = w * 2;
  float accK[2][6], accV[2][6];
  #pragma unroll
  for (int j=0;j<2;++j)
    #pragma unroll
    for (int sI=0;sI<6;++sI) { accK[j][sI]=0.f; accV[j][sI]=0.f; }
  #pragma unroll 2
  for (int c = 0; c < C_; ++c) {
    float a0 = xk [(r0+0)*C_+c], a1 = xk [(r0+1)*C_+c];
    float b0 = xvn[(r0+0)*C_+c], b1 = xvn[(r0+1)*C_+c];
    #pragma unroll
    for (int sI=0;sI<6;++sI) {
      float wk = wkT[(size_t)c*C_ + ch + 64*sI];
      float wv = wvT[(size_t)c*C_ + ch + 64*sI];
      accK[0][sI] += a0*wk; accK[1][sI] += a1*wk;
      accV[0][sI] += b0*wv; accV[1][sI] += b1*wv;
    }
  }
  // mu-pos add + V store (coalesced scalar over lanes)
  #pragma unroll
  for (int j=0;j<2;++j) {
    int prow = pr0 + r0 + j;
    float m0 = mu_p[(size_t)prow*3+0];
    float m1 = mu_p[(size_t)prow*3+1];
    float m2 = mu_p[(size_t)prow*3+2];
    #pragma unroll
    for (int sI=0;sI<6;++sI) {
      int i = ch + 64*sI;
      accK[j][sI] += m0*Wpos[i*3+0] + m1*Wpos[i*3+1] + m2*Wpos[i*3+2];
      vvo[(size_t)prow*C_ + i] = accV[j][sI];
    }
  }
  __syncthreads();          // xk/xvn dead — reuse as kres[384][9]
  float* kres = sm;
  #pragma unroll
  for (int j=0;j<2;++j)
    #pragma unroll
    for (int sI=0;sI<6;++sI)
      kres[(ch + 64*sI)*9 + (r0+j)] = accK[j][sI];
  __syncthreads();
  int b = pr0 >> 9, kp0 = pr0 & (KP-1);
  #pragma unroll
  for (int p = 0; p < 2; ++p) {
    int i = p*256 + t;
    if (i < C_) {
      const float* kr = &kres[i*9];
      float4 v0 = make_float4(kr[0], kr[1], kr[2], kr[3]);
      float4 v1 = make_float4(kr[4], kr[5], kr[6], kr[7]);
      float* dst = &kkT[((size_t)b*C_ + i)*KP + kp0];
      *(float4*)dst = v0;
      *(float4*)(dst+4) = v1;
    }
  }
}

// ---------------- K2: s_trunk -> q  (16 rows, 384 threads) ----------------
__global__ __launch_bounds__(384) void k_qproj(
    const float* __restrict__ st, const float* __restrict__ g,
    const float* __restrict__ bb, const float* __restrict__ WT,
    float* __restrict__ qout) {
  __shared__ float xln[16*C_];
  int t = threadIdx.x;
  int row0 = blockIdx.x * 16;
  if (t < 256) {
    int r = t >> 4, l = t & 15;
    const float* xr = st + (size_t)(row0 + r) * C_;
    float xv[24]; float s = 0.f;
    #pragma unroll
    for (int j = 0; j < 24; ++j) { xv[j] = xr[l + 16*j]; s += xv[j]; }
    #pragma unroll
    for (int m = 1; m < 16; m <<= 1) s += __shfl_xor(s, m);
    float mean = s * (1.0f/C_);
    float vs = 0.f;
    #pragma unroll
    for (int j = 0; j < 24; ++j) { float d = xv[j]-mean; vs += d*d; }
    #pragma unroll
    for (int m = 1; m < 16; m <<= 1) vs += __shfl_xor(vs, m);
    float rs = 1.0f / sqrtf(vs * (1.0f/C_) + 1e-5f);
    #pragma unroll
    for (int j = 0; j < 24; ++j) {
      int c = l + 16*j;
      xln[r*C_ + c] = (xv[j]-mean)*rs*g[c] + bb[c];
    }
  }
  __syncthreads();
  int g96 = t % 96, rg = t / 96;
  int i0 = g96 * 4, r0 = rg * 4;
  float4 a0 = make_float4(0,0,0,0), a1 = a0, a2 = a0, a3 = a0;
  #pragma unroll 4
  for (int c = 0; c < C_; ++c) {
    float4 wv = *(const float4*)&WT[(size_t)c*C_ + i0];
    float x0 = xln[(r0+0)*C_+c];
    float x1 = xln[(r0+1)*C_+c];
    float x2 = xln[(r0+2)*C_+c];
    float x3 = xln[(r0+3)*C_+c];
    a0.x += x0*wv.x; a0.y += x0*wv.y; a0.z += x0*wv.z; a0.w += x0*wv.w;
    a1.x += x1*wv.x; a1.y += x1*wv.y; a1.z += x1*wv.z; a1.w += x1*wv.w;
    a2.x += x2*wv.x; a2.y += x2*wv.y; a2.z += x2*wv.z; a2.w += x2*wv.w;
    a3.x += x3*wv.x; a3.y += x3*wv.y; a3.z += x3*wv.z; a3.w += x3*wv.w;
  }
  size_t base = ((size_t)row0 + r0)*C_ + i0;
  *(float4*)&qout[base        ] = a0;
  *(float4*)&qout[base +   C_ ] = a1;
  *(float4*)&qout[base + 2*C_ ] = a2;
  *(float4*)&qout[base + 3*C_ ] = a3;
}

// ---------------- K3: logits -> softmax -> weighted sums ----------------
__global__ __launch_bounds__(256) void k_route(
    const float* __restrict__ q, const float* __restrict__ kkT,
    const float* __restrict__ vvm, const float* __restrict__ sp,
    const float* __restrict__ mu_p, const float* __restrict__ Sig_p,
    const float* __restrict__ mask_parent, const float* __restrict__ node_mask,
    float* __restrict__ out, float* __restrict__ pf,
    float* __restrict__ mu0, float* __restrict__ sigpc) {
  __shared__ float qs[16*C_];      // later: mu_p tile [512][3] + Sig_p tile [512][9]
  __shared__ float w[16*KP];
  int t = threadIdx.x;
  int b = blockIdx.y;
  int n0 = blockIdx.x * 16;
  {
    const float* qrow = q + ((size_t)b*N_ + n0)*C_;
    for (int idx = t; idx < 16*C_; idx += 256) qs[idx] = qrow[idx];
  }
  __syncthreads();
  // phase 1: logits
  {
    int rg = t >> 6, ch = t & 63, r0 = rg*4;
    float acc[4][8];
    #pragma unroll
    for (int j=0;j<4;++j)
      #pragma unroll
      for (int e=0;e<8;++e) acc[j][e]=0.f;
    const float* kbase = kkT + (size_t)b*C_*KP;
    for (int c4 = 0; c4 < C_; c4 += 4) {
      float4 qv0 = *(const float4*)&qs[(r0+0)*C_ + c4];
      float4 qv1 = *(const float4*)&qs[(r0+1)*C_ + c4];
      float4 qv2 = *(const float4*)&qs[(r0+2)*C_ + c4];
      float4 qv3 = *(const float4*)&qs[(r0+3)*C_ + c4];
      #pragma unroll
      for (int cc = 0; cc < 4; ++cc) {
        float q0 = cc==0?qv0.x:cc==1?qv0.y:cc==2?qv0.z:qv0.w;
        float q1 = cc==0?qv1.x:cc==1?qv1.y:cc==2?qv1.z:qv1.w;
        float q2 = cc==0?qv2.x:cc==1?qv2.y:cc==2?qv2.z:qv2.w;
        float q3 = cc==0?qv3.x:cc==1?qv3.y:cc==2?qv3.z:qv3.w;
        #pragma unroll
        for (int sI=0;sI<2;++sI) {
          float4 kv = *(const float4*)&kbase[(size_t)(c4+cc)*KP + ch*4 + 256*sI];
          acc[0][sI*4+0] += q0*kv.x; acc[0][sI*4+1] += q0*kv.y;
          acc[0][sI*4+2] += q0*kv.z; acc[0][sI*4+3] += q0*kv.w;
          acc[1][sI*4+0] += q1*kv.x; acc[1][sI*4+1] += q1*kv.y;
          acc[1][sI*4+2] += q1*kv.z; acc[1][sI*4+3] += q1*kv.w;
          acc[2][sI*4+0] += q2*kv.x; acc[2][sI*4+1] += q2*kv.y;
          acc[2][sI*4+2] += q2*kv.z; acc[2][sI*4+3] += q2*kv.w;
          acc[3][sI*4+0] += q3*kv.x; acc[3][sI*4+1] += q3*kv.y;
          acc[3][sI*4+2] += q3*kv.z; acc[3][sI*4+3] += q3*kv.w;
        }
      }
    }
    #pragma unroll
    for (int sI=0;sI<2;++sI) {
      int k0 = ch*4 + 256*sI;
      float4 mp4 = *(const float4*)&mask_parent[(size_t)b*KP + k0];
      #pragma unroll
      for (int j=0;j<4;++j) {
        float4 lv;
        lv.x = (mp4.x > 0.5f) ? acc[j][sI*4+0]*TAU_INV : NEGV;
        lv.y = (mp4.y > 0.5f) ? acc[j][sI*4+1]*TAU_INV : NEGV;
        lv.z = (mp4.z > 0.5f) ? acc[j][sI*4+2]*TAU_INV : NEGV;
        lv.w = (mp4.w > 0.5f) ? acc[j][sI*4+3]*TAU_INV : NEGV;
        *(float4*)&w[(r0+j)*KP + k0] = lv;
      }
    }
  }
  __syncthreads();
  // phase 2: softmax (16 lanes per row)
  {
    int r = t >> 4, l = t & 15;
    float* wr = &w[r*KP];
    float mx = -3.4e38f;
    #pragma unroll
    for (int j=0;j<32;++j) mx = fmaxf(mx, wr[l + 16*j]);
    #pragma unroll
    for (int m = 1; m < 16; m <<= 1) mx = fmaxf(mx, __shfl_xor(mx, m));
    float sm = 0.f;
    #pragma unroll
    for (int j=0;j<32;++j) {
      float e = expf(wr[l+16*j] - mx);
      wr[l+16*j] = e; sm += e;
    }
    #pragma unroll
    for (int m = 1; m < 16; m <<= 1) sm += __shfl_xor(sm, m);
    float nm = node_mask[(size_t)b*N_ + n0 + r];
    if (nm > 0.5f) {
      float sc = nm / sm;
      #pragma unroll
      for (int j=0;j<32;++j) wr[l+16*j] *= sc;
    } else {
      float u = nm * (1.0f/KP);
      #pragma unroll
      for (int j=0;j<32;++j) wr[l+16*j] = u;
    }
  }
  __syncthreads();
  // stage mu_p/Sig_p tiles into qs space (qs dead after phase 1)
  {
    const float4* msrc = (const float4*)(mu_p  + (size_t)b*KP*3);
    const float4* ssrc = (const float4*)(Sig_p + (size_t)b*KP*9);
    float4* mdst = (float4*)qs;            // [512*3 floats]
    float4* sdst = (float4*)(qs + 1536);   // [512*9 floats]
    for (int idx = t; idx < 384;  idx += 256) mdst[idx] = msrc[idx];
    for (int idx = t; idx < 1152; idx += 256) sdst[idx] = ssrc[idx];
  }
  // phase 3: s0 = w@vv, pf = w@s_parent
  {
    int rg = t >> 6, ch = t & 63, r0 = rg*4;
    float accS[4][3][2], accP[4][3][2];
    #pragma unroll
    for (int j=0;j<4;++j)
      #pragma unroll
      for (int sI=0;sI<3;++sI) {
        accS[j][sI][0]=0.f; accS[j][sI][1]=0.f;
        accP[j][sI][0]=0.f; accP[j][sI][1]=0.f;
      }
    const float* vb = vvm + (size_t)b*KP*C_;
    const float* pb = sp  + (size_t)b*KP*C_;
    for (int k4 = 0; k4 < KP; k4 += 4) {
      float wcomp[4][4];
      #pragma unroll
      for (int j=0;j<4;++j) {
        float4 t4 = *(const float4*)&w[(r0+j)*KP + k4];
        wcomp[0][j]=t4.x; wcomp[1][j]=t4.y; wcomp[2][j]=t4.z; wcomp[3][j]=t4.w;
      }
      #pragma unroll
      for (int kk=0; kk<4; ++kk) {
        size_t k = (size_t)(k4 + kk);
        #pragma unroll
        for (int sI=0;sI<3;++sI) {
          int i = ch*2 + 128*sI;
          float2 v2 = *(const float2*)&vb[k*C_ + i];
          float2 p2 = *(const float2*)&pb[k*C_ + i];
          #pragma unroll
          for (int j=0;j<4;++j) {
            float wj = wcomp[kk][j];
            accS[j][sI][0] += wj*v2.x; accS[j][sI][1] += wj*v2.y;
            accP[j][sI][0] += wj*p2.x; accP[j][sI][1] += wj*p2.y;
          }
        }
      }
    }
    #pragma unroll
    for (int j=0;j<4;++j) {
      int n = n0 + r0 + j;
      size_t row = (size_t)b*N_ + n;
      size_t orow = row * 396;
      #pragma unroll
      for (int sI=0;sI<3;++sI) {
        int i = ch*2 + 128*sI;
        *(float2*)&out[orow + i] = make_float2(accS[j][sI][0], accS[j][sI][1]);
        *(float2*)&pf[row*C_ + i] = make_float2(accP[j][sI][0], accP[j][sI][1]);
      }
    }
  }
  __syncthreads();   // staged mu/sig visible
  // tail: mu0 = w@mu_p, sigpc = w@sym(Sig_p) + J*I  (all reads from LDS)
  if (t < 192) {
    int r = t / 12, cm = t % 12;
    int n = n0 + r;
    const float* wr = &w[r*KP];
    size_t row = (size_t)b*N_ + n;
    float a = 0.f;
    if (cm < 3) {
      for (int k=0;k<KP;++k) a += wr[k]*qs[k*3+cm];
      mu0[row*3+cm] = a;
    } else {
      int e = cm - 3; int ii = e/3, jj = e%3;
      const float* sb = qs + 1536;
      for (int k=0;k<KP;++k)
        a += wr[k]*0.5f*(sb[k*9 + ii*3 + jj] + sb[k*9 + jj*3 + ii]);
      if (ii == jj) a += JITTER_;
      sigpc[row*9+e] = a;
    }
  }
}

// ---------------- K4: mu-offset MLP (16 rows, 384 threads) ----------------
__global__ __launch_bounds__(384) void k_mlp(
    const float* __restrict__ pf, const float* __restrict__ g,
    const float* __restrict__ bb, const float* __restrict__ W1T,
    const float* __restrict__ b1, const float* __restrict__ W2,
    const float* __restrict__ b2v, const float* __restrict__ node_mask,
    float* __restrict__ mu0) {
  __shared__ float xln[16*C_];
  __shared__ float h[16*C_];
  int t = threadIdx.x;
  int row0 = blockIdx.x * 16;
  if (t < 256) {
    int r = t >> 4, l = t & 15;
    const float* xr = pf + (size_t)(row0 + r) * C_;
    float xv[24]; float s = 0.f;
    #pragma unroll
    for (int j = 0; j < 24; ++j) { xv[j] = xr[l + 16*j]; s += xv[j]; }
    #pragma unroll
    for (int m = 1; m < 16; m <<= 1) s += __shfl_xor(s, m);
    float mean = s * (1.0f/C_);
    float vs = 0.f;
    #pragma unroll
    for (int j = 0; j < 24; ++j) { float d = xv[j]-mean; vs += d*d; }
    #pragma unroll
    for (int m = 1; m < 16; m <<= 1) vs += __shfl_xor(vs, m);
    float rs = 1.0f / sqrtf(vs * (1.0f/C_) + 1e-5f);
    #pragma unroll
    for (int j = 0; j < 24; ++j) {
      int c = l + 16*j;
      xln[r*C_ + c] = (xv[j]-mean)*rs*g[c] + bb[c];
    }
  }
  __syncthreads();
  {
    int g96 = t % 96, rg = t / 96;
    int i0 = g96 * 4, r0 = rg * 4;
    float4 a0 = make_float4(0,0,0,0), a1 = a0, a2 = a0, a3 = a0;
    #pragma unroll 4
    for (int c = 0; c < C_; ++c) {
      float4 wv = *(const float4*)&W1T[(size_t)c*C_ + i0];
      float x0 = xln[(r0+0)*C_+c];
      float x1 = xln[(r0+1)*C_+c];
      float x2 = xln[(r0+2)*C_+c];
      float x3 = xln[(r0+3)*C_+c];
      a0.x += x0*wv.x; a0.y += x0*wv.y; a0.z += x0*wv.z; a0.w += x0*wv.w;
      a1.x += x1*wv.x; a1.y += x1*wv.y; a1.z += x1*wv.z; a1.w += x1*wv.w;
      a2.x += x2*wv.x; a2.y += x2*wv.y; a2.z += x2*wv.z; a2.w += x2*wv.w;
      a3.x += x3*wv.x; a3.y += x3*wv.y; a3.z += x3*wv.z; a3.w += x3*wv.w;
    }
    float4 bv4 = *(const float4*)&b1[i0];
    float4 av[4] = {a0, a1, a2, a3};
    #pragma unroll
    for (int j = 0; j < 4; ++j) {
      float4 v = av[j];
      v.x += bv4.x; v.y += bv4.y; v.z += bv4.z; v.w += bv4.w;
      v.x = v.x / (1.0f + expf(-v.x));
      v.y = v.y / (1.0f + expf(-v.y));
      v.z = v.z / (1.0f + expf(-v.z));
      v.w = v.w / (1.0f + expf(-v.w));
      *(float4*)&h[(r0+j)*C_ + i0] = v;
    }
  }
  __syncthreads();
  if (t < 256) {
    int r = t >> 4, l = t & 15;
    const float* hr = &h[r*C_];
    float pd0=0.f, pd1=0.f, pd2=0.f;
    #pragma unroll
    for (int j=0;j<24;++j) {
      int c = l + 16*j;
      float hv = hr[c];
      pd0 += hv*W2[c];
      pd1 += hv*W2[C_ + c];
      pd2 += hv*W2[2*C_ + c];
    }
    #pragma unroll
    for (int m = 1; m < 16; m <<= 1) {
      pd0 += __shfl_xor(pd0, m);
      pd1 += __shfl_xor(pd1, m);
      pd2 += __shfl_xor(pd2, m);
    }
    if (l == 0) {
      size_t row = (size_t)(row0 + r);
      float nm = node_mask[row];
      float d0 = (pd0 + b2v[0]) * MU_SCALE_;
      float d1 = (pd1 + b2v[1]) * MU_SCALE_;
      float d2 = (pd2 + b2v[2]) * MU_SCALE_;
      mu0[row*3+0] = (mu0[row*3+0] + d0) * nm;
      mu0[row*3+1] = (mu0[row*3+1] + d1) * nm;
      mu0[row*3+2] = (mu0[row*3+2] + d2) * nm;
    }
  }
}

// ---------------- K5: kNN sigma + Sig0 + final mu0 write ----------------
__global__ __launch_bounds__(256) void k_knn(
    const float* __restrict__ mu0, const float* __restrict__ node_mask,
    const float* __restrict__ sigpc, float* __restrict__ out) {
  __shared__ float mxs[N_];
  __shared__ float mys[N_];
  __shared__ float mzs[N_];
  __shared__ float mrg[64*32];
  int t = threadIdx.x;
  int b = blockIdx.y;
  int n0 = blockIdx.x * 64;
  const float* mb = mu0 + (size_t)b*N_*3;
  for (int idx = t; idx < N_; idx += 256) {
    mxs[idx] = mb[idx*3+0];
    mys[idx] = mb[idx*3+1];
    mzs[idx] = mb[idx*3+2];
  }
  __syncthreads();
  int r = t >> 2, qq = t & 3;
  int n = n0 + r;
  float ex = mxs[n], ey = mys[n], ez = mzs[n];
  const float* nmB = node_mask + (size_t)b*N_;
  float best[8];
  #pragma unroll
  for (int i=0;i<8;++i) best[i] = BIG_;
  int m0 = qq * (N_/4);
  for (int m = m0; m < m0 + N_/4; ++m) {
    float dx = mxs[m]-ex, dy = mys[m]-ey, dz = mzs[m]-ez;
    float d2 = dx*dx + dy*dy + dz*dz;
    if (m == n || nmB[m] <= 0.5f) d2 = BIG_;
    if (d2 < best[7]) {
      #pragma unroll
      for (int i = 7; i >= 1; --i)
        best[i] = (best[i] > d2) ? ((best[i-1] > d2) ? best[i-1] : d2) : best[i];
      best[0] = (best[0] > d2) ? d2 : best[0];
    }
  }
  #pragma unroll
  for (int i=0;i<8;++i) mrg[(r*4+qq)*8 + i] = best[i];
  __syncthreads();
  if (qq == 0) {
    float arr[32];
    #pragma unroll
    for (int i=0;i<32;++i) arr[i] = mrg[r*32 + i];
    float ssum = 0.f;
    #pragma unroll
    for (int sel=0; sel<8; ++sel) {
      float mn = arr[0];
      #pragma unroll
      for (int i=1;i<32;++i) mn = fminf(mn, arr[i]);
      ssum += sqrtf(fmaxf(mn, 0.f));
      bool done = false;
      #pragma unroll
      for (int i=0;i<32;++i) {
        bool hit = (!done) && (arr[i] == mn);
        arr[i] = hit ? BIG_ : arr[i];
        done = done || hit;
      }
    }
    float sigma = fminf(fmaxf(ALPHA_ * (ssum * 0.125f), SFLOOR_), SCEIL_);
    float s2 = sigma*sigma + JITTER_;
    size_t row = (size_t)b*N_ + n;
    float nm = nmB[n];
    size_t orow = row * 396;
    const float* sg = &sigpc[row*9];
    #pragma unroll
    for (int e=0;e<9;++e) {
      bool diag = (e==0)||(e==4)||(e==8);
      float v = BETA_*sg[e] + (diag ? ((1.0f-BETA_)*s2 + JITTER_) : 0.0f);
      out[orow + 387 + e] = v * nm;
    }
    out[orow + 384] = mxs[n];
    out[orow + 385] = mys[n];
    out[orow + 386] = mzs[n];
  }
}

extern "C" void kernel_launch(void* const* d_in, const int* in_sizes, int n_in,
                              void* d_out, int out_size, void* d_ws, size_t ws_size,
                              hipStream_t stream) {
  const float* s_parent    = (const float*)d_in[0];
  const float* mu_p        = (const float*)d_in[1];
  const float* Sig_p       = (const float*)d_in[2];
  const float* mask_parent = (const float*)d_in[3];
  const float* node_mask   = (const float*)d_in[4];
  const float* s_trunk     = (const float*)d_in[5];
  const float* Wq   = (const float*)d_in[6];
  const float* Wk   = (const float*)d_in[7];
  const float* Wv   = (const float*)d_in[8];
  const float* Wpos = (const float*)d_in[9];
  const float* lnq_g = (const float*)d_in[10];
  const float* lnq_b = (const float*)d_in[11];
  const float* lnk_g = (const float*)d_in[12];
  const float* lnk_b = (const float*)d_in[13];
  const float* lnv_g = (const float*)d_in[14];
  const float* lnv_b = (const float*)d_in[15];
  const float* mo_ln_g = (const float*)d_in[16];
  const float* mo_ln_b = (const float*)d_in[17];
  const float* mo_W1 = (const float*)d_in[18];
  const float* mo_b1 = (const float*)d_in[19];
  const float* mo_W2 = (const float*)d_in[20];
  const float* mo_b2 = (const float*)d_in[21];

  float* ws  = (float*)d_ws;
  float* q   = ws;                               // 6291456
  float* kkT = q   + (size_t)B_*N_*C_;           // 786432  (later: W1T)
  float* vv  = kkT + (size_t)B_*C_*KP;           // 786432
  float* pf  = vv  + (size_t)B_*KP*C_;           // 6291456 (first 442368: WqT/WkT/WvT)
  float* mu0 = pf  + (size_t)B_*N_*C_;           // 49152
  float* sg  = mu0 + (size_t)B_*N_*3;            // 442368
  float* out = (float*)d_out;

  float* wqT = pf;                 // dead once k_route writes pf
  float* wkT = pf + (size_t)C_*C_;
  float* wvT = pf + (size_t)2*C_*C_;
  float* w1T = kkT;                // kkT dead after k_route

  dim3 tb(32, 8);
  dim3 tg(C_/32, C_/32);
  k_transpose<<<tg, tb, 0, stream>>>(Wq, wqT);
  k_transpose<<<tg, tb, 0, stream>>>(Wk, wkT);
  k_transpose<<<tg, tb, 0, stream>>>(Wv, wvT);

  k_kvproj<<<dim3(B_*KP/8), dim3(256), 0, stream>>>(
      s_parent, mu_p, lnk_g, lnk_b, lnv_g, lnv_b, wkT, wvT, Wpos, kkT, vv);
  k_qproj<<<dim3(B_*N_/16), dim3(384), 0, stream>>>(
      s_trunk, lnq_g, lnq_b, wqT, q);
  k_route<<<dim3(N_/16, B_), dim3(256), 0, stream>>>(
      q, kkT, vv, s_parent, mu_p, Sig_p, mask_parent, node_mask,
      out, pf, mu0, sg);
  // kkT now dead: transpose W1 into its space
  k_transpose<<<tg, tb, 0, stream>>>(mo_W1, w1T);
  k_mlp<<<dim3(B_*N_/16), dim3(384), 0, stream>>>(
      pf, mo_ln_g, mo_ln_b, w1T, mo_b1, mo_W2, mo_b2, node_mask, mu0);
  k_knn<<<dim3(N_/64, B_), dim3(256), 0, stream>>>(
      mu0, node_mask, sg, out);
}

// Round 3
// 761.613 us; speedup vs baseline: 2.6851x; 1.2447x over previous
//
#include <hip/hip_runtime.h>
#include <math.h>

#define B_ 4
#define N_ 4096
#define KP 512
#define C_ 384

typedef unsigned short u16;
typedef short s8v __attribute__((ext_vector_type(8)));
typedef float f4v __attribute__((ext_vector_type(4)));
#define MFMA(a,b,c) __builtin_amdgcn_mfma_f32_16x16x32_bf16(a,b,c,0,0,0)

constexpr float TAU_INV  = 10.0f;
constexpr float BETA_    = 0.85f;
constexpr float JITTER_  = 1e-6f;
constexpr float ALPHA_   = 1.5f;
constexpr float SFLOOR_  = 1e-3f;
constexpr float SCEIL_   = 100.0f;
constexpr float MU_SCALE_= 0.25f;
constexpr float NEGV     = -1e9f;
constexpr float BIG_     = 1e9f;

__device__ __forceinline__ u16 f2b_rne(float f) {
  unsigned int u = __float_as_uint(f);
  return (u16)((u + 0x7FFFu + ((u >> 16) & 1u)) >> 16);
}
__device__ __forceinline__ float b2f(u16 h) {
  return __uint_as_float(((unsigned int)h) << 16);
}
__device__ __forceinline__ void split_hl(float f, u16& hi, u16& lo) {
  unsigned int u = __float_as_uint(f);
  hi = (u16)(u >> 16);                         // truncation: remainder exact-ish
  float fh = __uint_as_float(u & 0xFFFF0000u);
  lo = f2b_rne(f - fh);
}
__device__ __forceinline__ float dot4f(float4 a, float4 b) {
  return a.x*b.x + a.y*b.y + a.z*b.z + a.w*b.w;
}

// ---------------- K0: 384x384 fp32 transpose ----------------
__global__ __launch_bounds__(256) void k_transpose(
    const float* __restrict__ W, float* __restrict__ WT) {
  __shared__ float tile[32][33];
  int bx = blockIdx.x * 32, by = blockIdx.y * 32;
  int tx = threadIdx.x, ty = threadIdx.y;   // 32 x 8
  #pragma unroll
  for (int j = 0; j < 32; j += 8)
    tile[ty + j][tx] = W[(size_t)(by + ty + j) * C_ + bx + tx];
  __syncthreads();
  #pragma unroll
  for (int j = 0; j < 32; j += 8)
    WT[(size_t)(bx + ty + j) * C_ + by + tx] = tile[tx][ty + j];
}

// ---------------- K0b: s_parent [b][kp][c] -> spT bf16 [b][c][kp] ----------------
__global__ __launch_bounds__(256) void k_sptr(
    const float* __restrict__ sp, u16* __restrict__ spt) {
  __shared__ float tl[32][33];
  int bx = blockIdx.x * 32;   // kp
  int by = blockIdx.y * 32;   // c
  int bz = blockIdx.z;        // b
  const float* s = sp + (size_t)bz * KP * C_;
  u16* d = spt + (size_t)bz * C_ * KP;
  int tx = threadIdx.x, ty = threadIdx.y;
  #pragma unroll
  for (int j = 0; j < 32; j += 8)
    tl[ty + j][tx] = s[(size_t)(bx + ty + j) * C_ + by + tx];
  __syncthreads();
  #pragma unroll
  for (int j = 0; j < 32; j += 8)
    d[(size_t)(by + ty + j) * KP + bx + tx] = f2b_rne(tl[tx][ty + j]);
}

// ---------------- K1: parents -> k hi/lo [b][kp][c], vT hi/lo [b][c][kp] ----------------
__global__ __launch_bounds__(256) void k_kvproj(
    const float* __restrict__ sp, const float* __restrict__ mu_p,
    const float* __restrict__ gk, const float* __restrict__ bk,
    const float* __restrict__ gv, const float* __restrict__ bv,
    const float* __restrict__ wkT, const float* __restrict__ wvT,
    const float* __restrict__ Wpos,
    u16* __restrict__ khi, u16* __restrict__ klo,
    u16* __restrict__ vthi, u16* __restrict__ vtlo) {
  __shared__ float sm[2*8*C_];     // xk | xvn ; later vstage[384][9] aliases sm
  float* xk  = sm;
  float* xvn = sm + 8*C_;
  int t = threadIdx.x;
  int pr0 = blockIdx.x * 8;
  if (t < 128) {
    int r = t >> 4, l = t & 15;
    const float* xr = sp + (size_t)(pr0 + r) * C_;
    float xv[24]; float s = 0.f;
    #pragma unroll
    for (int j = 0; j < 24; ++j) { xv[j] = xr[l + 16*j]; s += xv[j]; }
    #pragma unroll
    for (int m = 1; m < 16; m <<= 1) s += __shfl_xor(s, m);
    float mean = s * (1.0f/C_);
    float vs = 0.f;
    #pragma unroll
    for (int j = 0; j < 24; ++j) { float d = xv[j]-mean; vs += d*d; }
    #pragma unroll
    for (int m = 1; m < 16; m <<= 1) vs += __shfl_xor(vs, m);
    float rs = 1.0f / sqrtf(vs * (1.0f/C_) + 1e-5f);
    #pragma unroll
    for (int j = 0; j < 24; ++j) {
      int c = l + 16*j;
      float xc = (xv[j]-mean)*rs;
      xk [r*C_ + c] = xc*gk[c] + bk[c];
      xvn[r*C_ + c] = xc*gv[c] + bv[c];
    }
  }
  __syncthreads();
  int w = t >> 6, ch = t & 63;
  int r0 = w * 2;
  float accK[2][6], accV[2][6];
  #pragma unroll
  for (int j=0;j<2;++j)
    #pragma unroll
    for (int sI=0;sI<6;++sI) { accK[j][sI]=0.f; accV[j][sI]=0.f; }
  #pragma unroll 2
  for (int c = 0; c < C_; ++c) {
    float a0 = xk [(r0+0)*C_+c], a1 = xk [(r0+1)*C_+c];
    float b0 = xvn[(r0+0)*C_+c], b1 = xvn[(r0+1)*C_+c];
    #pragma unroll
    for (int sI=0;sI<6;++sI) {
      float wk = wkT[(size_t)c*C_ + ch + 64*sI];
      float wv = wvT[(size_t)c*C_ + ch + 64*sI];
      accK[0][sI] += a0*wk; accK[1][sI] += a1*wk;
      accV[0][sI] += b0*wv; accV[1][sI] += b1*wv;
    }
  }
  // K store (row-major [b][kp][c] hi/lo) + stage V for transpose
  __syncthreads();          // xk/xvn reads done; sm will be reused below
  float* vst = sm;          // vstage[384][9]
  #pragma unroll
  for (int j=0;j<2;++j) {
    int prow = pr0 + r0 + j;
    float m0 = mu_p[(size_t)prow*3+0];
    float m1 = mu_p[(size_t)prow*3+1];
    float m2 = mu_p[(size_t)prow*3+2];
    #pragma unroll
    for (int sI=0;sI<6;++sI) {
      int i = ch + 64*sI;
      float kvv = accK[j][sI] + m0*Wpos[i*3+0] + m1*Wpos[i*3+1] + m2*Wpos[i*3+2];
      u16 h, l; split_hl(kvv, h, l);
      khi[(size_t)prow*C_ + i] = h;
      klo[(size_t)prow*C_ + i] = l;
      vst[i*9 + (r0 + j)] = accV[j][sI];
    }
  }
  __syncthreads();
  int b = pr0 >> 9, kp0 = pr0 & (KP-1);
  for (int i2 = t; i2 < C_; i2 += 256) {
    u16 h[8], l[8];
    #pragma unroll
    for (int e = 0; e < 8; ++e) split_hl(vst[i2*9 + e], h[e], l[e]);
    size_t base = ((size_t)b*C_ + i2)*KP + kp0;
    *(ushort4*)&vthi[base]   = make_ushort4(h[0],h[1],h[2],h[3]);
    *(ushort4*)&vthi[base+4] = make_ushort4(h[4],h[5],h[6],h[7]);
    *(ushort4*)&vtlo[base]   = make_ushort4(l[0],l[1],l[2],l[3]);
    *(ushort4*)&vtlo[base+4] = make_ushort4(l[4],l[5],l[6],l[7]);
  }
}

// ---------------- K2: s_trunk -> q hi/lo bf16 [b][n][c] ----------------
__global__ __launch_bounds__(384) void k_qproj(
    const float* __restrict__ st, const float* __restrict__ g,
    const float* __restrict__ bb, const float* __restrict__ WT,
    u16* __restrict__ qhi, u16* __restrict__ qlo) {
  __shared__ float xln[16*C_];
  int t = threadIdx.x;
  int row0 = blockIdx.x * 16;
  if (t < 256) {
    int r = t >> 4, l = t & 15;
    const float* xr = st + (size_t)(row0 + r) * C_;
    float xv[24]; float s = 0.f;
    #pragma unroll
    for (int j = 0; j < 24; ++j) { xv[j] = xr[l + 16*j]; s += xv[j]; }
    #pragma unroll
    for (int m = 1; m < 16; m <<= 1) s += __shfl_xor(s, m);
    float mean = s * (1.0f/C_);
    float vs = 0.f;
    #pragma unroll
    for (int j = 0; j < 24; ++j) { float d = xv[j]-mean; vs += d*d; }
    #pragma unroll
    for (int m = 1; m < 16; m <<= 1) vs += __shfl_xor(vs, m);
    float rs = 1.0f / sqrtf(vs * (1.0f/C_) + 1e-5f);
    #pragma unroll
    for (int j = 0; j < 24; ++j) {
      int c = l + 16*j;
      xln[r*C_ + c] = (xv[j]-mean)*rs*g[c] + bb[c];
    }
  }
  __syncthreads();
  int g96 = t % 96, rg = t / 96;
  int i0 = g96 * 4, r0 = rg * 4;
  float4 a0 = make_float4(0,0,0,0), a1 = a0, a2 = a0, a3 = a0;
  #pragma unroll 4
  for (int c = 0; c < C_; ++c) {
    float4 wv = *(const float4*)&WT[(size_t)c*C_ + i0];
    float x0 = xln[(r0+0)*C_+c];
    float x1 = xln[(r0+1)*C_+c];
    float x2 = xln[(r0+2)*C_+c];
    float x3 = xln[(r0+3)*C_+c];
    a0.x += x0*wv.x; a0.y += x0*wv.y; a0.z += x0*wv.z; a0.w += x0*wv.w;
    a1.x += x1*wv.x; a1.y += x1*wv.y; a1.z += x1*wv.z; a1.w += x1*wv.w;
    a2.x += x2*wv.x; a2.y += x2*wv.y; a2.z += x2*wv.z; a2.w += x2*wv.w;
    a3.x += x3*wv.x; a3.y += x3*wv.y; a3.z += x3*wv.z; a3.w += x3*wv.w;
  }
  float4 av[4] = {a0, a1, a2, a3};
  #pragma unroll
  for (int j = 0; j < 4; ++j) {
    size_t base = ((size_t)row0 + r0 + j)*C_ + i0;
    u16 h0,l0,h1,l1,h2,l2,h3,l3;
    split_hl(av[j].x, h0, l0); split_hl(av[j].y, h1, l1);
    split_hl(av[j].z, h2, l2); split_hl(av[j].w, h3, l3);
    *(ushort4*)&qhi[base] = make_ushort4(h0,h1,h2,h3);
    *(ushort4*)&qlo[base] = make_ushort4(l0,l1,l2,l3);
  }
}

// ---------------- K3: MFMA router ----------------
// Block: 256 thr = 4 waves. Tile: 32 n-rows. wave = (wg = n-group, wh = kp-half / c-half)
__global__ __launch_bounds__(256, 2) void k_route(
    const u16* __restrict__ qhi, const u16* __restrict__ qlo,
    const u16* __restrict__ khi, const u16* __restrict__ klo,
    const u16* __restrict__ vthi, const u16* __restrict__ vtlo,
    const u16* __restrict__ spt,
    const float* __restrict__ mu_p, const float* __restrict__ Sig_p,
    const float* __restrict__ mask_parent, const float* __restrict__ node_mask,
    float* __restrict__ out, u16* __restrict__ pf,
    float* __restrict__ mu0, float* __restrict__ sigpc) {
  __shared__ u16   wlds[2*16*512];     // 32 KB, XOR-swizzled rows
  __shared__ float smask[KP];          // 2 KB
  __shared__ float smu[KP*3];          // 6 KB
  __shared__ float ssig[KP*9];         // 18 KB
  __shared__ float red[2][2][2][16];   // [wg][wh][max/sum][n]

  int t = threadIdx.x;
  int bb = blockIdx.y;
  int nb = blockIdx.x * 32;
  int wave = t >> 6, lane = t & 63;
  int wg = wave >> 1, wh = wave & 1;
  int l15 = lane & 15, l4 = lane >> 4;

  // stage mask / mu_p / Sig_p
  {
    const float4* ms = (const float4*)(mask_parent + (size_t)bb*KP);
    const float4* mu = (const float4*)(mu_p  + (size_t)bb*KP*3);
    const float4* sg4= (const float4*)(Sig_p + (size_t)bb*KP*9);
    for (int i = t; i < 128;  i += 256) ((float4*)smask)[i] = ms[i];
    for (int i = t; i < 384;  i += 256) ((float4*)smu)[i]   = mu[i];
    for (int i = t; i < 1152; i += 256) ((float4*)ssig)[i]  = sg4[i];
  }
  __syncthreads();

  // ---- phase 1: logits^T tiles, D[kp][n], split bf16 (3 MFMA) ----
  const u16* qhB = qhi + ((size_t)bb*N_ + nb + wg*16)*C_;
  const u16* qlB = qlo + ((size_t)bb*N_ + nb + wg*16)*C_;
  const u16* khB = khi + ((size_t)bb*KP + wh*256)*C_;
  const u16* klB = klo + ((size_t)bb*KP + wh*256)*C_;
  f4v acc[16];
  #pragma unroll
  for (int kt = 0; kt < 16; ++kt) acc[kt] = (f4v){0.f,0.f,0.f,0.f};
  for (int cs = 0; cs < 12; ++cs) {
    int c0 = cs*32 + l4*8;
    s8v bqh = *(const s8v*)&qhB[(size_t)l15*C_ + c0];
    s8v bql = *(const s8v*)&qlB[(size_t)l15*C_ + c0];
    #pragma unroll
    for (int kt = 0; kt < 16; ++kt) {
      s8v ah = *(const s8v*)&khB[(size_t)(kt*16 + l15)*C_ + c0];
      s8v al = *(const s8v*)&klB[(size_t)(kt*16 + l15)*C_ + c0];
      acc[kt] = MFMA(ah, bqh, acc[kt]);
      acc[kt] = MFMA(ah, bql, acc[kt]);
      acc[kt] = MFMA(al, bqh, acc[kt]);
    }
  }

  // ---- mask + scale, wave-local softmax over kp (lane-local + shfl 16/32) ----
  float mx = -3.4e38f;
  #pragma unroll
  for (int kt = 0; kt < 16; ++kt) {
    const float4 m4 = *(const float4*)&smask[wh*256 + kt*16 + l4*4];
    acc[kt][0] = (m4.x > 0.5f) ? acc[kt][0]*TAU_INV : NEGV;
    acc[kt][1] = (m4.y > 0.5f) ? acc[kt][1]*TAU_INV : NEGV;
    acc[kt][2] = (m4.z > 0.5f) ? acc[kt][2]*TAU_INV : NEGV;
    acc[kt][3] = (m4.w > 0.5f) ? acc[kt][3]*TAU_INV : NEGV;
    mx = fmaxf(mx, fmaxf(fmaxf(acc[kt][0], acc[kt][1]), fmaxf(acc[kt][2], acc[kt][3])));
  }
  mx = fmaxf(mx, __shfl_xor(mx, 16));
  mx = fmaxf(mx, __shfl_xor(mx, 32));
  if (lane < 16) red[wg][wh][0][lane] = mx;
  __syncthreads();
  mx = fmaxf(red[wg][0][0][l15], red[wg][1][0][l15]);
  float smv = 0.f;
  #pragma unroll
  for (int kt = 0; kt < 16; ++kt) {
    #pragma unroll
    for (int r = 0; r < 4; ++r) {
      float e = __expf(acc[kt][r] - mx);
      acc[kt][r] = e; smv += e;
    }
  }
  smv += __shfl_xor(smv, 16);
  smv += __shfl_xor(smv, 32);
  if (lane < 16) red[wg][wh][1][lane] = smv;
  __syncthreads();
  smv = red[wg][0][1][l15] + red[wg][1][1][l15];
  float nm = node_mask[(size_t)bb*N_ + nb + wg*16 + l15];
  float scl = nm / smv;
  bool uni = !(nm > 0.5f);
  float uval = nm * (1.0f/KP);
  #pragma unroll
  for (int kt = 0; kt < 16; ++kt) {
    ushort4 wv;
    wv.x = f2b_rne(uni ? uval : acc[kt][0]*scl);
    wv.y = f2b_rne(uni ? uval : acc[kt][1]*scl);
    wv.z = f2b_rne(uni ? uval : acc[kt][2]*scl);
    wv.w = f2b_rne(uni ? uval : acc[kt][3]*scl);
    int kpl = wh*256 + kt*16 + l4*4;
    int bo = (l15*1024 + kpl*2) ^ ((l15 & 7) << 4);
    *(ushort4*)&wlds[wg*8192 + (bo >> 1)] = wv;
  }
  __syncthreads();

  // ---- phase 3: s0 = w@V (hi+lo), pf = w@sp ; wave does 16n x 192c ----
  {
    int cb = wh * 192;
    for (int ct = 0; ct < 12; ++ct) {
      int c = cb + ct*16 + l15;
      f4v aS = (f4v){0.f,0.f,0.f,0.f};
      f4v aP = (f4v){0.f,0.f,0.f,0.f};
      const u16* vhB = vthi + ((size_t)bb*C_ + c)*KP;
      const u16* vlB = vtlo + ((size_t)bb*C_ + c)*KP;
      const u16* spB = spt  + ((size_t)bb*C_ + c)*KP;
      #pragma unroll
      for (int ks = 0; ks < 16; ++ks) {
        int kp = ks*32 + l4*8;
        int bo = (l15*1024 + kp*2) ^ ((l15 & 7) << 4);
        s8v aw = *(const s8v*)&wlds[wg*8192 + (bo >> 1)];
        s8v bh = *(const s8v*)&vhB[kp];
        s8v bl = *(const s8v*)&vlB[kp];
        s8v bs = *(const s8v*)&spB[kp];
        aS = MFMA(aw, bh, aS);
        aS = MFMA(aw, bl, aS);
        aP = MFMA(aw, bs, aP);
      }
      #pragma unroll
      for (int r = 0; r < 4; ++r) {
        int n = nb + wg*16 + l4*4 + r;
        size_t row = (size_t)bb*N_ + n;
        out[row*396 + c] = aS[r];
        pf[row*C_ + c] = f2b_rne(aP[r]);
      }
    }
  }

  // ---- tail: mu0 = w@mu_p, sigpc = w@sym(Sig_p)+J*I (fp32 VALU, w from LDS) ----
  for (int it = t; it < 384; it += 256) {
    int r = it / 12, cm = it % 12;
    int wgr = r >> 4, nl = r & 15;
    int base = wgr * 8192;
    size_t row = (size_t)bb*N_ + nb + r;
    float a = 0.f;
    if (cm < 3) {
      for (int k = 0; k < KP; ++k) {
        int bo = (nl*1024 + k*2) ^ ((nl & 7) << 4);
        a += b2f(wlds[base + (bo >> 1)]) * smu[k*3 + cm];
      }
      mu0[row*3 + cm] = a;
    } else {
      int e = cm - 3; int ii = e/3, jj = e%3;
      for (int k = 0; k < KP; ++k) {
        int bo = (nl*1024 + k*2) ^ ((nl & 7) << 4);
        a += b2f(wlds[base + (bo >> 1)]) * 0.5f*(ssig[k*9 + ii*3 + jj] + ssig[k*9 + jj*3 + ii]);
      }
      if (ii == jj) a += JITTER_;
      sigpc[row*9 + e] = a;
    }
  }
}

// ---------------- K4: mu-offset MLP (pf bf16 in) ----------------
__global__ __launch_bounds__(384) void k_mlp(
    const u16* __restrict__ pf, const float* __restrict__ g,
    const float* __restrict__ bb, const float* __restrict__ W1T,
    const float* __restrict__ b1, const float* __restrict__ W2,
    const float* __restrict__ b2v, const float* __restrict__ node_mask,
    float* __restrict__ mu0) {
  __shared__ float xln[16*C_];
  __shared__ float h[16*C_];
  int t = threadIdx.x;
  int row0 = blockIdx.x * 16;
  if (t < 256) {
    int r = t >> 4, l = t & 15;
    const u16* xr = pf + (size_t)(row0 + r) * C_;
    float xv[24]; float s = 0.f;
    #pragma unroll
    for (int j = 0; j < 24; ++j) { xv[j] = b2f(xr[l + 16*j]); s += xv[j]; }
    #pragma unroll
    for (int m = 1; m < 16; m <<= 1) s += __shfl_xor(s, m);
    float mean = s * (1.0f/C_);
    float vs = 0.f;
    #pragma unroll
    for (int j = 0; j < 24; ++j) { float d = xv[j]-mean; vs += d*d; }
    #pragma unroll
    for (int m = 1; m < 16; m <<= 1) vs += __shfl_xor(vs, m);
    float rs = 1.0f / sqrtf(vs * (1.0f/C_) + 1e-5f);
    #pragma unroll
    for (int j = 0; j < 24; ++j) {
      int c = l + 16*j;
      xln[r*C_ + c] = (xv[j]-mean)*rs*g[c] + bb[c];
    }
  }
  __syncthreads();
  {
    int g96 = t % 96, rg = t / 96;
    int i0 = g96 * 4, r0 = rg * 4;
    float4 a0 = make_float4(0,0,0,0), a1 = a0, a2 = a0, a3 = a0;
    #pragma unroll 4
    for (int c = 0; c < C_; ++c) {
      float4 wv = *(const float4*)&W1T[(size_t)c*C_ + i0];
      float x0 = xln[(r0+0)*C_+c];
      float x1 = xln[(r0+1)*C_+c];
      float x2 = xln[(r0+2)*C_+c];
      float x3 = xln[(r0+3)*C_+c];
      a0.x += x0*wv.x; a0.y += x0*wv.y; a0.z += x0*wv.z; a0.w += x0*wv.w;
      a1.x += x1*wv.x; a1.y += x1*wv.y; a1.z += x1*wv.z; a1.w += x1*wv.w;
      a2.x += x2*wv.x; a2.y += x2*wv.y; a2.z += x2*wv.z; a2.w += x2*wv.w;
      a3.x += x3*wv.x; a3.y += x3*wv.y; a3.z += x3*wv.z; a3.w += x3*wv.w;
    }
    float4 bv4 = *(const float4*)&b1[i0];
    float4 av[4] = {a0, a1, a2, a3};
    #pragma unroll
    for (int j = 0; j < 4; ++j) {
      float4 v = av[j];
      v.x += bv4.x; v.y += bv4.y; v.z += bv4.z; v.w += bv4.w;
      v.x = v.x / (1.0f + __expf(-v.x));
      v.y = v.y / (1.0f + __expf(-v.y));
      v.z = v.z / (1.0f + __expf(-v.z));
      v.w = v.w / (1.0f + __expf(-v.w));
      *(float4*)&h[(r0+j)*C_ + i0] = v;
    }
  }
  __syncthreads();
  if (t < 256) {
    int r = t >> 4, l = t & 15;
    const float* hr = &h[r*C_];
    float pd0=0.f, pd1=0.f, pd2=0.f;
    #pragma unroll
    for (int j=0;j<24;++j) {
      int c = l + 16*j;
      float hv = hr[c];
      pd0 += hv*W2[c];
      pd1 += hv*W2[C_ + c];
      pd2 += hv*W2[2*C_ + c];
    }
    #pragma unroll
    for (int m = 1; m < 16; m <<= 1) {
      pd0 += __shfl_xor(pd0, m);
      pd1 += __shfl_xor(pd1, m);
      pd2 += __shfl_xor(pd2, m);
    }
    if (l == 0) {
      size_t row = (size_t)(row0 + r);
      float nmv = node_mask[row];
      float d0 = (pd0 + b2v[0]) * MU_SCALE_;
      float d1 = (pd1 + b2v[1]) * MU_SCALE_;
      float d2 = (pd2 + b2v[2]) * MU_SCALE_;
      mu0[row*3+0] = (mu0[row*3+0] + d0) * nmv;
      mu0[row*3+1] = (mu0[row*3+1] + d1) * nmv;
      mu0[row*3+2] = (mu0[row*3+2] + d2) * nmv;
    }
  }
}

// ---------------- K5: kNN sigma + Sig0 + mu0 out ----------------
__global__ __launch_bounds__(256) void k_knn(
    const float* __restrict__ mu0, const float* __restrict__ node_mask,
    const float* __restrict__ sigpc, float* __restrict__ out) {
  __shared__ float mxs[N_];
  __shared__ float mys[N_];
  __shared__ float mzs[N_];
  __shared__ float mrg[64*32];
  int t = threadIdx.x;
  int b = blockIdx.y;
  int n0 = blockIdx.x * 64;
  const float* mb = mu0 + (size_t)b*N_*3;
  for (int idx = t; idx < N_; idx += 256) {
    mxs[idx] = mb[idx*3+0];
    mys[idx] = mb[idx*3+1];
    mzs[idx] = mb[idx*3+2];
  }
  __syncthreads();
  int r = t >> 2, qq = t & 3;
  int n = n0 + r;
  float ex = mxs[n], ey = mys[n], ez = mzs[n];
  const float* nmB = node_mask + (size_t)b*N_;
  float best[8];
  #pragma unroll
  for (int i=0;i<8;++i) best[i] = BIG_;
  int m0 = qq * (N_/4);
  for (int m = m0; m < m0 + N_/4; ++m) {
    float dx = mxs[m]-ex, dy = mys[m]-ey, dz = mzs[m]-ez;
    float d2 = dx*dx + dy*dy + dz*dz;
    if (m == n || nmB[m] <= 0.5f) d2 = BIG_;
    if (d2 < best[7]) {
      #pragma unroll
      for (int i = 7; i >= 1; --i)
        best[i] = (best[i] > d2) ? ((best[i-1] > d2) ? best[i-1] : d2) : best[i];
      best[0] = (best[0] > d2) ? d2 : best[0];
    }
  }
  #pragma unroll
  for (int i=0;i<8;++i) mrg[(r*4+qq)*8 + i] = best[i];
  __syncthreads();
  if (qq == 0) {
    float arr[32];
    #pragma unroll
    for (int i=0;i<32;++i) arr[i] = mrg[r*32 + i];
    float ssum = 0.f;
    #pragma unroll
    for (int sel=0; sel<8; ++sel) {
      float mn = arr[0];
      #pragma unroll
      for (int i=1;i<32;++i) mn = fminf(mn, arr[i]);
      ssum += sqrtf(fmaxf(mn, 0.f));
      bool done = false;
      #pragma unroll
      for (int i=0;i<32;++i) {
        bool hit = (!done) && (arr[i] == mn);
        arr[i] = hit ? BIG_ : arr[i];
        done = done || hit;
      }
    }
    float sigma = fminf(fmaxf(ALPHA_ * (ssum * 0.125f), SFLOOR_), SCEIL_);
    float s2 = sigma*sigma + JITTER_;
    size_t row = (size_t)b*N_ + n;
    float nmv = nmB[n];
    size_t orow = row * 396;
    const float* sg = &sigpc[row*9];
    #pragma unroll
    for (int e=0;e<9;++e) {
      bool diag = (e==0)||(e==4)||(e==8);
      float v = BETA_*sg[e] + (diag ? ((1.0f-BETA_)*s2 + JITTER_) : 0.0f);
      out[orow + 387 + e] = v * nmv;
    }
    out[orow + 384] = mxs[n];
    out[orow + 385] = mys[n];
    out[orow + 386] = mzs[n];
  }
}

extern "C" void kernel_launch(void* const* d_in, const int* in_sizes, int n_in,
                              void* d_out, int out_size, void* d_ws, size_t ws_size,
                              hipStream_t stream) {
  const float* s_parent    = (const float*)d_in[0];
  const float* mu_p        = (const float*)d_in[1];
  const float* Sig_p       = (const float*)d_in[2];
  const float* mask_parent = (const float*)d_in[3];
  const float* node_mask   = (const float*)d_in[4];
  const float* s_trunk     = (const float*)d_in[5];
  const float* Wq   = (const float*)d_in[6];
  const float* Wk   = (const float*)d_in[7];
  const float* Wv   = (const float*)d_in[8];
  const float* Wpos = (const float*)d_in[9];
  const float* lnq_g = (const float*)d_in[10];
  const float* lnq_b = (const float*)d_in[11];
  const float* lnk_g = (const float*)d_in[12];
  const float* lnk_b = (const float*)d_in[13];
  const float* lnv_g = (const float*)d_in[14];
  const float* lnv_b = (const float*)d_in[15];
  const float* mo_ln_g = (const float*)d_in[16];
  const float* mo_ln_b = (const float*)d_in[17];
  const float* mo_W1 = (const float*)d_in[18];
  const float* mo_b1 = (const float*)d_in[19];
  const float* mo_W2 = (const float*)d_in[20];
  const float* mo_b2 = (const float*)d_in[21];

  char* wsb = (char*)d_ws;
  // region sizes (bytes): q 25165824 | k 3145728 | vT 3145728 | pf-region 25165824 | mu0 196608 | sg 1769472
  u16* qhi  = (u16*)wsb;
  u16* qlo  = qhi + (size_t)B_*N_*C_;
  u16* khi  = (u16*)(wsb + 25165824);
  u16* klo  = khi + (size_t)B_*KP*C_;
  u16* vthi = (u16*)(wsb + 25165824 + 3145728);
  u16* vtlo = vthi + (size_t)B_*C_*KP;
  char* pfb = wsb + 25165824 + 2*3145728;
  u16* pf   = (u16*)pfb;                                  // 12582912 B
  u16* spt  = (u16*)(pfb + 12582912);                     // 1572864 B
  float* wqT = (float*)(pfb + 12582912 + 1572864);        // 589824 B each
  float* wkT = wqT + (size_t)C_*C_;
  float* wvT = wkT + (size_t)C_*C_;
  float* w1T = (float*)(wsb + 25165824);                  // reuses k region after k_route
  float* mu0 = (float*)(wsb + 25165824 + 2*3145728 + 25165824);
  float* sg  = mu0 + (size_t)B_*N_*3;
  float* out = (float*)d_out;

  dim3 tb(32, 8);
  dim3 tg(C_/32, C_/32);
  k_transpose<<<tg, tb, 0, stream>>>(Wq, wqT);
  k_transpose<<<tg, tb, 0, stream>>>(Wk, wkT);
  k_transpose<<<tg, tb, 0, stream>>>(Wv, wvT);
  k_sptr<<<dim3(KP/32, C_/32, B_), tb, 0, stream>>>(s_parent, spt);

  k_kvproj<<<dim3(B_*KP/8), dim3(256), 0, stream>>>(
      s_parent, mu_p, lnk_g, lnk_b, lnv_g, lnv_b, wkT, wvT, Wpos,
      khi, klo, vthi, vtlo);
  k_qproj<<<dim3(B_*N_/16), dim3(384), 0, stream>>>(
      s_trunk, lnq_g, lnq_b, wqT, qhi, qlo);
  k_route<<<dim3(N_/32, B_), dim3(256), 0, stream>>>(
      qhi, qlo, khi, klo, vthi, vtlo, spt, mu_p, Sig_p,
      mask_parent, node_mask, out, pf, mu0, sg);
  k_transpose<<<tg, tb, 0, stream>>>(mo_W1, w1T);
  k_mlp<<<dim3(B_*N_/16), dim3(384), 0, stream>>>(
      pf, mo_ln_g, mo_ln_b, w1T, mo_b1, mo_W2, mo_b2, node_mask, mu0);
  k_knn<<<dim3(N_/64, B_), dim3(256), 0, stream>>>(
      mu0, node_mask, sg, out);
}

// Round 4
// 648.602 us; speedup vs baseline: 3.1529x; 1.1742x over previous
//
#include <hip/hip_runtime.h>
#include <math.h>

#define B_ 4
#define N_ 4096
#define KP 512
#define C_ 384

typedef unsigned short u16;
typedef short s8v __attribute__((ext_vector_type(8)));
typedef float f4v __attribute__((ext_vector_type(4)));
#define MFMA(a,b,c) __builtin_amdgcn_mfma_f32_16x16x32_bf16(a,b,c,0,0,0)

constexpr float TAU_INV  = 10.0f;
constexpr float BETA_    = 0.85f;
constexpr float JITTER_  = 1e-6f;
constexpr float ALPHA_   = 1.5f;
constexpr float SFLOOR_  = 1e-3f;
constexpr float SCEIL_   = 100.0f;
constexpr float MU_SCALE_= 0.25f;
constexpr float NEGV     = -1e9f;
constexpr float BIG_     = 1e9f;

__device__ __forceinline__ u16 f2b_rne(float f) {
  unsigned int u = __float_as_uint(f);
  return (u16)((u + 0x7FFFu + ((u >> 16) & 1u)) >> 16);
}
__device__ __forceinline__ float b2f(u16 h) {
  return __uint_as_float(((unsigned int)h) << 16);
}
__device__ __forceinline__ void split_hl(float f, u16& hi, u16& lo) {
  unsigned int u = __float_as_uint(f);
  hi = (u16)(u >> 16);
  float fh = __uint_as_float(u & 0xFFFF0000u);
  lo = f2b_rne(f - fh);
}

// Packed fragment layouts (per 16x16x32 MFMA):
//  A/B operand fragment = 64 lanes x 8 u16 = 1KB contiguous.
//  K (A-op, rows=kp, k=c):   [b*32+kp_tile][cc(12)][lane][8], lane=(kp&15)+16*((c>>3)&3)
//  q (B-op, rows=n,  k=c):   [n>>4][cc(12)][lane][8],        lane=(n&15)+16*((c>>3)&3)
//  V^T/spT (B-op, rows=c, k=kp): [b*24+c_tile][ks(16)][lane][8], lane=(c&15)+16*((kp>>3)&3)

// ---------------- K0: 384x384 fp32 transpose (for VALU GEMM weights) ----------------
__global__ __launch_bounds__(256) void k_transpose(
    const float* __restrict__ W, float* __restrict__ WT) {
  __shared__ float tile[32][33];
  int bx = blockIdx.x * 32, by = blockIdx.y * 32;
  int tx = threadIdx.x, ty = threadIdx.y;   // 32 x 8
  #pragma unroll
  for (int j = 0; j < 32; j += 8)
    tile[ty + j][tx] = W[(size_t)(by + ty + j) * C_ + bx + tx];
  __syncthreads();
  #pragma unroll
  for (int j = 0; j < 32; j += 8)
    WT[(size_t)(bx + ty + j) * C_ + by + tx] = tile[tx][ty + j];
}

// ---------------- K0b: s_parent -> spT bf16 packed fragments ----------------
__global__ __launch_bounds__(256) void k_sptr(
    const float* __restrict__ sp, u16* __restrict__ spt) {
  __shared__ float tl[32][33];
  int bx = blockIdx.x * 32;   // kp
  int by = blockIdx.y * 32;   // c
  int bz = blockIdx.z;        // b
  const float* s = sp + (size_t)bz * KP * C_;
  int tx = threadIdx.x & 31, ty4 = threadIdx.x >> 5;
  #pragma unroll
  for (int j = 0; j < 32; j += 8)
    tl[ty4 + j][tx] = s[(size_t)(bx + ty4 + j) * C_ + by + tx];  // tl[kp_l][c_l]
  __syncthreads();
  int t = threadIdx.x;
  if (t < 128) {
    int c_l = t >> 2, krun = t & 3;
    int kp0r = krun * 8;
    u16 hh[8];
    #pragma unroll
    for (int e = 0; e < 8; ++e) hh[e] = f2b_rne(tl[kp0r + e][c_l]);
    int cg = by + c_l;
    int lane = (cg & 15) + 16 * krun;          // bx % 32 == 0
    size_t fo = (((size_t)bz*24 + (cg >> 4))*16 + (bx >> 5))*512 + (size_t)lane*8;
    *(ushort4*)&spt[fo]   = make_ushort4(hh[0],hh[1],hh[2],hh[3]);
    *(ushort4*)&spt[fo+4] = make_ushort4(hh[4],hh[5],hh[6],hh[7]);
  }
}

// ---------------- K1: parents -> K hi/lo packed, V^T hi/lo packed ----------------
__global__ __launch_bounds__(256) void k_kvproj(
    const float* __restrict__ sp, const float* __restrict__ mu_p,
    const float* __restrict__ gk, const float* __restrict__ bk,
    const float* __restrict__ gv, const float* __restrict__ bv,
    const float* __restrict__ wkT, const float* __restrict__ wvT,
    const float* __restrict__ Wpos,
    u16* __restrict__ khi, u16* __restrict__ klo,
    u16* __restrict__ vthi, u16* __restrict__ vtlo) {
  __shared__ float sm[2*8*C_];     // xk | xvn ; later stg[384*9]
  float* xk  = sm;
  float* xvn = sm + 8*C_;
  int t = threadIdx.x;
  int pr0 = blockIdx.x * 8;
  if (t < 128) {
    int r = t >> 4, l = t & 15;
    const float* xr = sp + (size_t)(pr0 + r) * C_;
    float xv[24]; float s = 0.f;
    #pragma unroll
    for (int j = 0; j < 24; ++j) { xv[j] = xr[l + 16*j]; s += xv[j]; }
    #pragma unroll
    for (int m = 1; m < 16; m <<= 1) s += __shfl_xor(s, m);
    float mean = s * (1.0f/C_);
    float vs = 0.f;
    #pragma unroll
    for (int j = 0; j < 24; ++j) { float d = xv[j]-mean; vs += d*d; }
    #pragma unroll
    for (int m = 1; m < 16; m <<= 1) vs += __shfl_xor(vs, m);
    float rs = 1.0f / sqrtf(vs * (1.0f/C_) + 1e-5f);
    #pragma unroll
    for (int j = 0; j < 24; ++j) {
      int c = l + 16*j;
      float xc = (xv[j]-mean)*rs;
      xk [r*C_ + c] = xc*gk[c] + bk[c];
      xvn[r*C_ + c] = xc*gv[c] + bv[c];
    }
  }
  __syncthreads();
  int w = t >> 6, ch = t & 63;
  int r0 = w * 2;
  float accK[2][6], accV[2][6];
  #pragma unroll
  for (int j=0;j<2;++j)
    #pragma unroll
    for (int sI=0;sI<6;++sI) { accK[j][sI]=0.f; accV[j][sI]=0.f; }
  #pragma unroll 2
  for (int c = 0; c < C_; ++c) {
    float a0 = xk [(r0+0)*C_+c], a1 = xk [(r0+1)*C_+c];
    float b0 = xvn[(r0+0)*C_+c], b1 = xvn[(r0+1)*C_+c];
    #pragma unroll
    for (int sI=0;sI<6;++sI) {
      float wk = wkT[(size_t)c*C_ + ch + 64*sI];
      float wv = wvT[(size_t)c*C_ + ch + 64*sI];
      accK[0][sI] += a0*wk; accK[1][sI] += a1*wk;
      accV[0][sI] += b0*wv; accV[1][sI] += b1*wv;
    }
  }
  // mu-pos add into K
  #pragma unroll
  for (int j=0;j<2;++j) {
    int prow = pr0 + r0 + j;
    float m0 = mu_p[(size_t)prow*3+0];
    float m1 = mu_p[(size_t)prow*3+1];
    float m2 = mu_p[(size_t)prow*3+2];
    #pragma unroll
    for (int sI=0;sI<6;++sI) {
      int i = ch + 64*sI;
      accK[j][sI] += m0*Wpos[i*3+0] + m1*Wpos[i*3+1] + m2*Wpos[i*3+2];
    }
  }
  __syncthreads();            // xk/xvn dead
  float* stg = sm;            // [384][9]
  // ---- pass A: K packed ----
  #pragma unroll
  for (int j=0;j<2;++j)
    #pragma unroll
    for (int sI=0;sI<6;++sI)
      stg[(ch + 64*sI)*9 + (r0+j)] = accK[j][sI];
  __syncthreads();
  int kp0 = pr0 & (KP-1);
  int kp_tile_g = pr0 >> 4;        // == b*32 + (kp0>>4)
  int rhalf = kp0 & 8;
  int b = pr0 >> 9;
  for (int u = t; u < 384; u += 256) {
    int cc = u / 32, rem = u % 32, l4g = rem >> 3, row = rem & 7;
    int c0 = cc*32 + l4g*8;
    u16 hh[8], ll[8];
    #pragma unroll
    for (int e = 0; e < 8; ++e) split_hl(stg[(c0+e)*9 + row], hh[e], ll[e]);
    int lane = (rhalf + row) + 16*l4g;
    size_t fo = ((size_t)kp_tile_g*12 + cc)*512 + (size_t)lane*8;
    *(ushort4*)&khi[fo]   = make_ushort4(hh[0],hh[1],hh[2],hh[3]);
    *(ushort4*)&khi[fo+4] = make_ushort4(hh[4],hh[5],hh[6],hh[7]);
    *(ushort4*)&klo[fo]   = make_ushort4(ll[0],ll[1],ll[2],ll[3]);
    *(ushort4*)&klo[fo+4] = make_ushort4(ll[4],ll[5],ll[6],ll[7]);
  }
  __syncthreads();
  // ---- pass B: V^T packed ----
  #pragma unroll
  for (int j=0;j<2;++j)
    #pragma unroll
    for (int sI=0;sI<6;++sI)
      stg[(ch + 64*sI)*9 + (r0+j)] = accV[j][sI];
  __syncthreads();
  int kpc = kp0 >> 5, l4gv = (kp0 >> 3) & 3;
  for (int u = t; u < 384; u += 256) {
    int c = u;
    u16 hh[8], ll[8];
    #pragma unroll
    for (int e = 0; e < 8; ++e) split_hl(stg[c*9 + e], hh[e], ll[e]);
    int lane = (c & 15) + 16*l4gv;
    size_t fo = (((size_t)b*24 + (c >> 4))*16 + kpc)*512 + (size_t)lane*8;
    *(ushort4*)&vthi[fo]   = make_ushort4(hh[0],hh[1],hh[2],hh[3]);
    *(ushort4*)&vthi[fo+4] = make_ushort4(hh[4],hh[5],hh[6],hh[7]);
    *(ushort4*)&vtlo[fo]   = make_ushort4(ll[0],ll[1],ll[2],ll[3]);
    *(ushort4*)&vtlo[fo+4] = make_ushort4(ll[4],ll[5],ll[6],ll[7]);
  }
}

// ---------------- K2: s_trunk -> q hi/lo packed ----------------
__global__ __launch_bounds__(384) void k_qproj(
    const float* __restrict__ st, const float* __restrict__ g,
    const float* __restrict__ bb, const float* __restrict__ WT,
    u16* __restrict__ qhi, u16* __restrict__ qlo) {
  __shared__ float xln[16*C_];
  int t = threadIdx.x;
  int row0 = blockIdx.x * 16;
  if (t < 256) {
    int r = t >> 4, l = t & 15;
    const float* xr = st + (size_t)(row0 + r) * C_;
    float xv[24]; float s = 0.f;
    #pragma unroll
    for (int j = 0; j < 24; ++j) { xv[j] = xr[l + 16*j]; s += xv[j]; }
    #pragma unroll
    for (int m = 1; m < 16; m <<= 1) s += __shfl_xor(s, m);
    float mean = s * (1.0f/C_);
    float vs = 0.f;
    #pragma unroll
    for (int j = 0; j < 24; ++j) { float d = xv[j]-mean; vs += d*d; }
    #pragma unroll
    for (int m = 1; m < 16; m <<= 1) vs += __shfl_xor(vs, m);
    float rs = 1.0f / sqrtf(vs * (1.0f/C_) + 1e-5f);
    #pragma unroll
    for (int j = 0; j < 24; ++j) {
      int c = l + 16*j;
      xln[r*C_ + c] = (xv[j]-mean)*rs*g[c] + bb[c];
    }
  }
  __syncthreads();
  int g96 = t % 96, rg = t / 96;
  int i0 = g96 * 4, r0 = rg * 4;
  float4 a0 = make_float4(0,0,0,0), a1 = a0, a2 = a0, a3 = a0;
  #pragma unroll 4
  for (int c = 0; c < C_; ++c) {
    float4 wv = *(const float4*)&WT[(size_t)c*C_ + i0];
    float x0 = xln[(r0+0)*C_+c];
    float x1 = xln[(r0+1)*C_+c];
    float x2 = xln[(r0+2)*C_+c];
    float x3 = xln[(r0+3)*C_+c];
    a0.x += x0*wv.x; a0.y += x0*wv.y; a0.z += x0*wv.z; a0.w += x0*wv.w;
    a1.x += x1*wv.x; a1.y += x1*wv.y; a1.z += x1*wv.z; a1.w += x1*wv.w;
    a2.x += x2*wv.x; a2.y += x2*wv.y; a2.z += x2*wv.z; a2.w += x2*wv.w;
    a3.x += x3*wv.x; a3.y += x3*wv.y; a3.z += x3*wv.z; a3.w += x3*wv.w;
  }
  float4 av[4] = {a0, a1, a2, a3};
  #pragma unroll
  for (int j = 0; j < 4; ++j) {
    int nrow = row0 + r0 + j;
    u16 h0,l0,h1,l1,h2,l2,h3,l3;
    split_hl(av[j].x, h0, l0); split_hl(av[j].y, h1, l1);
    split_hl(av[j].z, h2, l2); split_hl(av[j].w, h3, l3);
    size_t fo = (((size_t)(nrow >> 4))*12 + (i0 >> 5))*512
              + (size_t)(((nrow & 15) + 16*((i0 >> 3) & 3))*8 + (i0 & 7));
    *(ushort4*)&qhi[fo] = make_ushort4(h0,h1,h2,h3);
    *(ushort4*)&qlo[fo] = make_ushort4(l0,l1,l2,l3);
  }
}

// ---------------- K3: MFMA router (packed-fragment loads) ----------------
__global__ __launch_bounds__(256, 2) void k_route(
    const u16* __restrict__ qhi, const u16* __restrict__ qlo,
    const u16* __restrict__ khi, const u16* __restrict__ klo,
    const u16* __restrict__ vthi, const u16* __restrict__ vtlo,
    const u16* __restrict__ spt,
    const float* __restrict__ mu_p, const float* __restrict__ Sig_p,
    const float* __restrict__ mask_parent, const float* __restrict__ node_mask,
    float* __restrict__ out, u16* __restrict__ pf,
    float* __restrict__ mu0, float* __restrict__ sigpc) {
  __shared__ u16   wlds[2*16*512];     // 32 KB, XOR-swizzled rows
  __shared__ float smask[KP];
  __shared__ float smuT[3*KP];         // transposed [cm][k]
  __shared__ float ssigT[9*KP];        // pre-symmetrized [e][k]
  __shared__ float red[2][2][2][16];

  int t = threadIdx.x;
  int bb = blockIdx.y;
  int nb = blockIdx.x * 32;
  int wave = t >> 6, lane = t & 63;
  int wg = wave >> 1, wh = wave & 1;
  int l15 = lane & 15, l4 = lane >> 4;

  // stage mask / muT / sigT(sym)
  {
    const float4* ms = (const float4*)(mask_parent + (size_t)bb*KP);
    for (int i = t; i < 128; i += 256) ((float4*)smask)[i] = ms[i];
    const float* mu = mu_p + (size_t)bb*KP*3;
    for (int i = t; i < 3*KP; i += 256) {
      int cm = i >> 9, k = i & 511;
      smuT[i] = mu[k*3 + cm];
    }
    const float* sb = Sig_p + (size_t)bb*KP*9;
    for (int i = t; i < 9*KP; i += 256) {
      int e = i >> 9, k = i & 511;
      int ii = e / 3, jj = e % 3;
      ssigT[i] = 0.5f*(sb[k*9 + ii*3 + jj] + sb[k*9 + jj*3 + ii]);
    }
  }
  __syncthreads();

  // ---- phase 1: logits^T, D[kp][n], split bf16 (3 MFMA) ----
  const u16* qhB = qhi + ((size_t)(bb*256 + (nb >> 4) + wg))*12*512;
  const u16* qlB = qlo + ((size_t)(bb*256 + (nb >> 4) + wg))*12*512;
  const u16* khB = khi + ((size_t)(bb*32 + wh*16))*12*512;
  const u16* klB = klo + ((size_t)(bb*32 + wh*16))*12*512;
  f4v acc[16];
  #pragma unroll
  for (int kt = 0; kt < 16; ++kt) acc[kt] = (f4v){0.f,0.f,0.f,0.f};
  for (int cs = 0; cs < 12; ++cs) {
    s8v bqh = *(const s8v*)&qhB[(size_t)cs*512 + lane*8];
    s8v bql = *(const s8v*)&qlB[(size_t)cs*512 + lane*8];
    #pragma unroll
    for (int kt = 0; kt < 16; ++kt) {
      s8v ah = *(const s8v*)&khB[((size_t)kt*12 + cs)*512 + lane*8];
      s8v al = *(const s8v*)&klB[((size_t)kt*12 + cs)*512 + lane*8];
      acc[kt] = MFMA(ah, bqh, acc[kt]);
      acc[kt] = MFMA(ah, bql, acc[kt]);
      acc[kt] = MFMA(al, bqh, acc[kt]);
    }
  }

  // ---- mask + scale + softmax over kp ----
  float mx = -3.4e38f;
  #pragma unroll
  for (int kt = 0; kt < 16; ++kt) {
    const float4 m4 = *(const float4*)&smask[wh*256 + kt*16 + l4*4];
    acc[kt][0] = (m4.x > 0.5f) ? acc[kt][0]*TAU_INV : NEGV;
    acc[kt][1] = (m4.y > 0.5f) ? acc[kt][1]*TAU_INV : NEGV;
    acc[kt][2] = (m4.z > 0.5f) ? acc[kt][2]*TAU_INV : NEGV;
    acc[kt][3] = (m4.w > 0.5f) ? acc[kt][3]*TAU_INV : NEGV;
    mx = fmaxf(mx, fmaxf(fmaxf(acc[kt][0], acc[kt][1]), fmaxf(acc[kt][2], acc[kt][3])));
  }
  mx = fmaxf(mx, __shfl_xor(mx, 16));
  mx = fmaxf(mx, __shfl_xor(mx, 32));
  if (lane < 16) red[wg][wh][0][lane] = mx;
  __syncthreads();
  mx = fmaxf(red[wg][0][0][l15], red[wg][1][0][l15]);
  float smv = 0.f;
  #pragma unroll
  for (int kt = 0; kt < 16; ++kt) {
    #pragma unroll
    for (int r = 0; r < 4; ++r) {
      float e = __expf(acc[kt][r] - mx);
      acc[kt][r] = e; smv += e;
    }
  }
  smv += __shfl_xor(smv, 16);
  smv += __shfl_xor(smv, 32);
  if (lane < 16) red[wg][wh][1][lane] = smv;
  __syncthreads();
  smv = red[wg][0][1][l15] + red[wg][1][1][l15];
  float nm = node_mask[(size_t)bb*N_ + nb + wg*16 + l15];
  float scl = nm / smv;
  bool uni = !(nm > 0.5f);
  float uval = nm * (1.0f/KP);
  #pragma unroll
  for (int kt = 0; kt < 16; ++kt) {
    ushort4 wv;
    wv.x = f2b_rne(uni ? uval : acc[kt][0]*scl);
    wv.y = f2b_rne(uni ? uval : acc[kt][1]*scl);
    wv.z = f2b_rne(uni ? uval : acc[kt][2]*scl);
    wv.w = f2b_rne(uni ? uval : acc[kt][3]*scl);
    int kpl = wh*256 + kt*16 + l4*4;
    int bo = (l15*1024 + kpl*2) ^ ((l15 & 7) << 4);
    *(ushort4*)&wlds[wg*8192 + (bo >> 1)] = wv;
  }
  __syncthreads();

  // ---- phase 3: s0 = w@V (hi+lo), pf = w@sp ----
  {
    int cb = wh * 192;
    for (int ct = 0; ct < 12; ++ct) {
      int c_tile = wh*12 + ct;
      int c = cb + ct*16 + l15;
      f4v aS = (f4v){0.f,0.f,0.f,0.f};
      f4v aP = (f4v){0.f,0.f,0.f,0.f};
      const u16* vhB = vthi + (((size_t)bb*24 + c_tile)*16)*512;
      const u16* vlB = vtlo + (((size_t)bb*24 + c_tile)*16)*512;
      const u16* spB = spt  + (((size_t)bb*24 + c_tile)*16)*512;
      #pragma unroll
      for (int ks = 0; ks < 16; ++ks) {
        int kp = ks*32 + l4*8;
        int bo = (l15*1024 + kp*2) ^ ((l15 & 7) << 4);
        s8v aw = *(const s8v*)&wlds[wg*8192 + (bo >> 1)];
        s8v bh = *(const s8v*)&vhB[(size_t)ks*512 + lane*8];
        s8v bl = *(const s8v*)&vlB[(size_t)ks*512 + lane*8];
        s8v bs = *(const s8v*)&spB[(size_t)ks*512 + lane*8];
        aS = MFMA(aw, bh, aS);
        aS = MFMA(aw, bl, aS);
        aP = MFMA(aw, bs, aP);
      }
      #pragma unroll
      for (int r = 0; r < 4; ++r) {
        int n = nb + wg*16 + l4*4 + r;
        size_t row = (size_t)bb*N_ + n;
        out[row*396 + c] = aS[r];
        pf[row*C_ + c] = f2b_rne(aP[r]);
      }
    }
  }

  // ---- tail: mu0 = w@mu_p, sigpc = w@sym(Sig_p)+J*I ----
  for (int u = t; u < 384; u += 256) {
    int r = u / 12, cm = u % 12;
    int wgr = r >> 4, nl = r & 15;
    const u16* wbase = &wlds[wgr * 8192];
    const float* tb = (cm < 3) ? &smuT[cm*512] : &ssigT[(cm-3)*512];
    float a = 0.f;
    for (int k4 = 0; k4 < 512; k4 += 4) {
      int bo = (nl*1024 + k4*2) ^ ((nl & 7) << 4);
      ushort4 w4 = *(const ushort4*)&wbase[bo >> 1];
      float4 m4 = *(const float4*)&tb[k4];
      a += b2f(w4.x)*m4.x + b2f(w4.y)*m4.y + b2f(w4.z)*m4.z + b2f(w4.w)*m4.w;
    }
    size_t row = (size_t)bb*N_ + nb + r;
    if (cm < 3) {
      mu0[row*3 + cm] = a;
    } else {
      int e = cm - 3;
      if (e == 0 || e == 4 || e == 8) a += JITTER_;
      sigpc[row*9 + e] = a;
    }
  }
}

// ---------------- K4: mu-offset MLP (pf bf16 in) ----------------
__global__ __launch_bounds__(384) void k_mlp(
    const u16* __restrict__ pf, const float* __restrict__ g,
    const float* __restrict__ bb, const float* __restrict__ W1T,
    const float* __restrict__ b1, const float* __restrict__ W2,
    const float* __restrict__ b2v, const float* __restrict__ node_mask,
    float* __restrict__ mu0) {
  __shared__ float xln[16*C_];
  __shared__ float h[16*C_];
  int t = threadIdx.x;
  int row0 = blockIdx.x * 16;
  if (t < 256) {
    int r = t >> 4, l = t & 15;
    const u16* xr = pf + (size_t)(row0 + r) * C_;
    float xv[24]; float s = 0.f;
    #pragma unroll
    for (int j = 0; j < 24; ++j) { xv[j] = b2f(xr[l + 16*j]); s += xv[j]; }
    #pragma unroll
    for (int m = 1; m < 16; m <<= 1) s += __shfl_xor(s, m);
    float mean = s * (1.0f/C_);
    float vs = 0.f;
    #pragma unroll
    for (int j = 0; j < 24; ++j) { float d = xv[j]-mean; vs += d*d; }
    #pragma unroll
    for (int m = 1; m < 16; m <<= 1) vs += __shfl_xor(vs, m);
    float rs = 1.0f / sqrtf(vs * (1.0f/C_) + 1e-5f);
    #pragma unroll
    for (int j = 0; j < 24; ++j) {
      int c = l + 16*j;
      xln[r*C_ + c] = (xv[j]-mean)*rs*g[c] + bb[c];
    }
  }
  __syncthreads();
  {
    int g96 = t % 96, rg = t / 96;
    int i0 = g96 * 4, r0 = rg * 4;
    float4 a0 = make_float4(0,0,0,0), a1 = a0, a2 = a0, a3 = a0;
    #pragma unroll 4
    for (int c = 0; c < C_; ++c) {
      float4 wv = *(const float4*)&W1T[(size_t)c*C_ + i0];
      float x0 = xln[(r0+0)*C_+c];
      float x1 = xln[(r0+1)*C_+c];
      float x2 = xln[(r0+2)*C_+c];
      float x3 = xln[(r0+3)*C_+c];
      a0.x += x0*wv.x; a0.y += x0*wv.y; a0.z += x0*wv.z; a0.w += x0*wv.w;
      a1.x += x1*wv.x; a1.y += x1*wv.y; a1.z += x1*wv.z; a1.w += x1*wv.w;
      a2.x += x2*wv.x; a2.y += x2*wv.y; a2.z += x2*wv.z; a2.w += x2*wv.w;
      a3.x += x3*wv.x; a3.y += x3*wv.y; a3.z += x3*wv.z; a3.w += x3*wv.w;
    }
    float4 bv4 = *(const float4*)&b1[i0];
    float4 av[4] = {a0, a1, a2, a3};
    #pragma unroll
    for (int j = 0; j < 4; ++j) {
      float4 v = av[j];
      v.x += bv4.x; v.y += bv4.y; v.z += bv4.z; v.w += bv4.w;
      v.x = v.x / (1.0f + __expf(-v.x));
      v.y = v.y / (1.0f + __expf(-v.y));
      v.z = v.z / (1.0f + __expf(-v.z));
      v.w = v.w / (1.0f + __expf(-v.w));
      *(float4*)&h[(r0+j)*C_ + i0] = v;
    }
  }
  __syncthreads();
  if (t < 256) {
    int r = t >> 4, l = t & 15;
    const float* hr = &h[r*C_];
    float pd0=0.f, pd1=0.f, pd2=0.f;
    #pragma unroll
    for (int j=0;j<24;++j) {
      int c = l + 16*j;
      float hv = hr[c];
      pd0 += hv*W2[c];
      pd1 += hv*W2[C_ + c];
      pd2 += hv*W2[2*C_ + c];
    }
    #pragma unroll
    for (int m = 1; m < 16; m <<= 1) {
      pd0 += __shfl_xor(pd0, m);
      pd1 += __shfl_xor(pd1, m);
      pd2 += __shfl_xor(pd2, m);
    }
    if (l == 0) {
      size_t row = (size_t)(row0 + r);
      float nmv = node_mask[row];
      float d0 = (pd0 + b2v[0]) * MU_SCALE_;
      float d1 = (pd1 + b2v[1]) * MU_SCALE_;
      float d2 = (pd2 + b2v[2]) * MU_SCALE_;
      mu0[row*3+0] = (mu0[row*3+0] + d0) * nmv;
      mu0[row*3+1] = (mu0[row*3+1] + d1) * nmv;
      mu0[row*3+2] = (mu0[row*3+2] + d2) * nmv;
    }
  }
}

// ---------------- K5: kNN sigma + Sig0 + mu0 out ----------------
__global__ __launch_bounds__(256) void k_knn(
    const float* __restrict__ mu0, const float* __restrict__ node_mask,
    const float* __restrict__ sigpc, float* __restrict__ out) {
  __shared__ float mxs[N_];
  __shared__ float mys[N_];
  __shared__ float mzs[N_];
  __shared__ float mrg[64*32];
  int t = threadIdx.x;
  int b = blockIdx.y;
  int n0 = blockIdx.x * 64;
  const float* mb = mu0 + (size_t)b*N_*3;
  for (int idx = t; idx < N_; idx += 256) {
    mxs[idx] = mb[idx*3+0];
    mys[idx] = mb[idx*3+1];
    mzs[idx] = mb[idx*3+2];
  }
  __syncthreads();
  int r = t >> 2, qq = t & 3;
  int n = n0 + r;
  float ex = mxs[n], ey = mys[n], ez = mzs[n];
  const float* nmB = node_mask + (size_t)b*N_;
  float best[8];
  #pragma unroll
  for (int i=0;i<8;++i) best[i] = BIG_;
  int m0 = qq * (N_/4);
  for (int m = m0; m < m0 + N_/4; ++m) {
    float dx = mxs[m]-ex, dy = mys[m]-ey, dz = mzs[m]-ez;
    float d2 = dx*dx + dy*dy + dz*dz;
    if (m == n || nmB[m] <= 0.5f) d2 = BIG_;
    if (d2 < best[7]) {
      #pragma unroll
      for (int i = 7; i >= 1; --i)
        best[i] = (best[i] > d2) ? ((best[i-1] > d2) ? best[i-1] : d2) : best[i];
      best[0] = (best[0] > d2) ? d2 : best[0];
    }
  }
  #pragma unroll
  for (int i=0;i<8;++i) mrg[(r*4+qq)*8 + i] = best[i];
  __syncthreads();
  if (qq == 0) {
    float arr[32];
    #pragma unroll
    for (int i=0;i<32;++i) arr[i] = mrg[r*32 + i];
    float ssum = 0.f;
    #pragma unroll
    for (int sel=0; sel<8; ++sel) {
      float mn = arr[0];
      #pragma unroll
      for (int i=1;i<32;++i) mn = fminf(mn, arr[i]);
      ssum += sqrtf(fmaxf(mn, 0.f));
      bool done = false;
      #pragma unroll
      for (int i=0;i<32;++i) {
        bool hit = (!done) && (arr[i] == mn);
        arr[i] = hit ? BIG_ : arr[i];
        done = done || hit;
      }
    }
    float sigma = fminf(fmaxf(ALPHA_ * (ssum * 0.125f), SFLOOR_), SCEIL_);
    float s2 = sigma*sigma + JITTER_;
    size_t row = (size_t)b*N_ + n;
    float nmv = nmB[n];
    size_t orow = row * 396;
    const float* sg = &sigpc[row*9];
    #pragma unroll
    for (int e=0;e<9;++e) {
      bool diag = (e==0)||(e==4)||(e==8);
      float v = BETA_*sg[e] + (diag ? ((1.0f-BETA_)*s2 + JITTER_) : 0.0f);
      out[orow + 387 + e] = v * nmv;
    }
    out[orow + 384] = mxs[n];
    out[orow + 385] = mys[n];
    out[orow + 386] = mzs[n];
  }
}

extern "C" void kernel_launch(void* const* d_in, const int* in_sizes, int n_in,
                              void* d_out, int out_size, void* d_ws, size_t ws_size,
                              hipStream_t stream) {
  const float* s_parent    = (const float*)d_in[0];
  const float* mu_p        = (const float*)d_in[1];
  const float* Sig_p       = (const float*)d_in[2];
  const float* mask_parent = (const float*)d_in[3];
  const float* node_mask   = (const float*)d_in[4];
  const float* s_trunk     = (const float*)d_in[5];
  const float* Wq   = (const float*)d_in[6];
  const float* Wk   = (const float*)d_in[7];
  const float* Wv   = (const float*)d_in[8];
  const float* Wpos = (const float*)d_in[9];
  const float* lnq_g = (const float*)d_in[10];
  const float* lnq_b = (const float*)d_in[11];
  const float* lnk_g = (const float*)d_in[12];
  const float* lnk_b = (const float*)d_in[13];
  const float* lnv_g = (const float*)d_in[14];
  const float* lnv_b = (const float*)d_in[15];
  const float* mo_ln_g = (const float*)d_in[16];
  const float* mo_ln_b = (const float*)d_in[17];
  const float* mo_W1 = (const float*)d_in[18];
  const float* mo_b1 = (const float*)d_in[19];
  const float* mo_W2 = (const float*)d_in[20];
  const float* mo_b2 = (const float*)d_in[21];

  char* wsb = (char*)d_ws;
  u16* qhi  = (u16*)wsb;                                  // 12582912 B
  u16* qlo  = qhi + (size_t)B_*N_*C_;                     // 12582912 B
  u16* khi  = (u16*)(wsb + 25165824);                     // 1572864 B
  u16* klo  = khi + (size_t)B_*KP*C_;                     // 1572864 B
  u16* vthi = (u16*)(wsb + 25165824 + 3145728);           // 1572864 B
  u16* vtlo = vthi + (size_t)B_*C_*KP;                    // 1572864 B
  char* pfb = wsb + 25165824 + 2*3145728;
  u16* pf   = (u16*)pfb;                                  // 12582912 B
  u16* spt  = (u16*)(pfb + 12582912);                     // 1572864 B
  float* wqT = (float*)(pfb + 12582912 + 1572864);        // 589824 B each
  float* wkT = wqT + (size_t)C_*C_;
  float* wvT = wkT + (size_t)C_*C_;
  float* w1T = (float*)(wsb + 25165824);                  // reuses K region after k_route
  float* mu0 = (float*)(wsb + 25165824 + 2*3145728 + 25165824);
  float* sg  = mu0 + (size_t)B_*N_*3;
  float* out = (float*)d_out;

  dim3 tb(32, 8);
  dim3 tg(C_/32, C_/32);
  k_transpose<<<tg, tb, 0, stream>>>(Wq, wqT);
  k_transpose<<<tg, tb, 0, stream>>>(Wk, wkT);
  k_transpose<<<tg, tb, 0, stream>>>(Wv, wvT);
  k_sptr<<<dim3(KP/32, C_/32, B_), dim3(256), 0, stream>>>(s_parent, spt);

  k_kvproj<<<dim3(B_*KP/8), dim3(256), 0, stream>>>(
      s_parent, mu_p, lnk_g, lnk_b, lnv_g, lnv_b, wkT, wvT, Wpos,
      khi, klo, vthi, vtlo);
  k_qproj<<<dim3(B_*N_/16), dim3(384), 0, stream>>>(
      s_trunk, lnq_g, lnq_b, wqT, qhi, qlo);
  k_route<<<dim3(N_/32, B_), dim3(256), 0, stream>>>(
      qhi, qlo, khi, klo, vthi, vtlo, spt, mu_p, Sig_p,
      mask_parent, node_mask, out, pf, mu0, sg);
  k_transpose<<<tg, tb, 0, stream>>>(mo_W1, w1T);
  k_mlp<<<dim3(B_*N_/16), dim3(384), 0, stream>>>(
      pf, mo_ln_g, mo_ln_b, w1T, mo_b1, mo_W2, mo_b2, node_mask, mu0);
  k_knn<<<dim3(N_/64, B_), dim3(256), 0, stream>>>(
      mu0, node_mask, sg, out);
}

// Round 5
// 552.479 us; speedup vs baseline: 3.7015x; 1.1740x over previous
//
#include <hip/hip_runtime.h>
#include <math.h>

#define B_ 4
#define N_ 4096
#define KP 512
#define C_ 384

typedef unsigned short u16;
typedef short s8v __attribute__((ext_vector_type(8)));
typedef float f4v __attribute__((ext_vector_type(4)));
#define MFMA(a,b,c) __builtin_amdgcn_mfma_f32_16x16x32_bf16(a,b,c,0,0,0)

constexpr float TAU_INV  = 10.0f;
constexpr float BETA_    = 0.85f;
constexpr float JITTER_  = 1e-6f;
constexpr float ALPHA_   = 1.5f;
constexpr float SFLOOR_  = 1e-3f;
constexpr float SCEIL_   = 100.0f;
constexpr float MU_SCALE_= 0.25f;
constexpr float NEGV     = -1e9f;
constexpr float BIG_     = 1e9f;

__device__ __forceinline__ u16 f2b_rne(float f) {
  unsigned int u = __float_as_uint(f);
  return (u16)((u + 0x7FFFu + ((u >> 16) & 1u)) >> 16);
}
__device__ __forceinline__ float b2f(u16 h) {
  return __uint_as_float(((unsigned int)h) << 16);
}
__device__ __forceinline__ void split_hl(float f, u16& hi, u16& lo) {
  unsigned int u = __float_as_uint(f);
  hi = (u16)(u >> 16);
  float fh = __uint_as_float(u & 0xFFFF0000u);
  lo = f2b_rne(f - fh);
}

// Packed fragment layouts (per 16x16x32 MFMA):
//  A/B operand fragment = 64 lanes x 8 u16 = 1KB contiguous.
//  K (A-op):   [b*32+kp_tile][cc(12)][lane][8], lane=(kp&15)+16*((c>>3)&3)
//  q (B-op):   [n>>4][cc(12)][lane][8],        lane=(n&15)+16*((c>>3)&3)
//  V^T/spT (B-op): [b*24+c_tile][ks(16)][lane][8], lane=(c&15)+16*((kp>>3)&3)

// ---------------- K0: 384x384 fp32 transpose ----------------
__global__ __launch_bounds__(256) void k_transpose(
    const float* __restrict__ W, float* __restrict__ WT) {
  __shared__ float tile[32][33];
  int bx = blockIdx.x * 32, by = blockIdx.y * 32;
  int tx = threadIdx.x, ty = threadIdx.y;   // 32 x 8
  #pragma unroll
  for (int j = 0; j < 32; j += 8)
    tile[ty + j][tx] = W[(size_t)(by + ty + j) * C_ + bx + tx];
  __syncthreads();
  #pragma unroll
  for (int j = 0; j < 32; j += 8)
    WT[(size_t)(bx + ty + j) * C_ + by + tx] = tile[tx][ty + j];
}

// ---------------- K0b: s_parent -> spT bf16 packed fragments ----------------
__global__ __launch_bounds__(256) void k_sptr(
    const float* __restrict__ sp, u16* __restrict__ spt) {
  __shared__ float tl[32][33];
  int bx = blockIdx.x * 32;   // kp
  int by = blockIdx.y * 32;   // c
  int bz = blockIdx.z;        // b
  const float* s = sp + (size_t)bz * KP * C_;
  int tx = threadIdx.x & 31, ty4 = threadIdx.x >> 5;
  #pragma unroll
  for (int j = 0; j < 32; j += 8)
    tl[ty4 + j][tx] = s[(size_t)(bx + ty4 + j) * C_ + by + tx];  // tl[kp_l][c_l]
  __syncthreads();
  int t = threadIdx.x;
  if (t < 128) {
    int c_l = t >> 2, krun = t & 3;
    int kp0r = krun * 8;
    u16 hh[8];
    #pragma unroll
    for (int e = 0; e < 8; ++e) hh[e] = f2b_rne(tl[kp0r + e][c_l]);
    int cg = by + c_l;
    int lane = (cg & 15) + 16 * krun;
    size_t fo = (((size_t)bz*24 + (cg >> 4))*16 + (bx >> 5))*512 + (size_t)lane*8;
    *(ushort4*)&spt[fo]   = make_ushort4(hh[0],hh[1],hh[2],hh[3]);
    *(ushort4*)&spt[fo+4] = make_ushort4(hh[4],hh[5],hh[6],hh[7]);
  }
}

// ---------------- K1: parents -> K hi/lo packed, V^T hi/lo packed ----------------
__global__ __launch_bounds__(256) void k_kvproj(
    const float* __restrict__ sp, const float* __restrict__ mu_p,
    const float* __restrict__ gk, const float* __restrict__ bk,
    const float* __restrict__ gv, const float* __restrict__ bv,
    const float* __restrict__ wkT, const float* __restrict__ wvT,
    const float* __restrict__ Wpos,
    u16* __restrict__ khi, u16* __restrict__ klo,
    u16* __restrict__ vthi, u16* __restrict__ vtlo) {
  __shared__ float sm[2*8*C_];
  float* xk  = sm;
  float* xvn = sm + 8*C_;
  int t = threadIdx.x;
  int pr0 = blockIdx.x * 8;
  if (t < 128) {
    int r = t >> 4, l = t & 15;
    const float* xr = sp + (size_t)(pr0 + r) * C_;
    float xv[24]; float s = 0.f;
    #pragma unroll
    for (int j = 0; j < 24; ++j) { xv[j] = xr[l + 16*j]; s += xv[j]; }
    #pragma unroll
    for (int m = 1; m < 16; m <<= 1) s += __shfl_xor(s, m);
    float mean = s * (1.0f/C_);
    float vs = 0.f;
    #pragma unroll
    for (int j = 0; j < 24; ++j) { float d = xv[j]-mean; vs += d*d; }
    #pragma unroll
    for (int m = 1; m < 16; m <<= 1) vs += __shfl_xor(vs, m);
    float rs = 1.0f / sqrtf(vs * (1.0f/C_) + 1e-5f);
    #pragma unroll
    for (int j = 0; j < 24; ++j) {
      int c = l + 16*j;
      float xc = (xv[j]-mean)*rs;
      xk [r*C_ + c] = xc*gk[c] + bk[c];
      xvn[r*C_ + c] = xc*gv[c] + bv[c];
    }
  }
  __syncthreads();
  int w = t >> 6, ch = t & 63;
  int r0 = w * 2;
  float accK[2][6], accV[2][6];
  #pragma unroll
  for (int j=0;j<2;++j)
    #pragma unroll
    for (int sI=0;sI<6;++sI) { accK[j][sI]=0.f; accV[j][sI]=0.f; }
  #pragma unroll 2
  for (int c = 0; c < C_; ++c) {
    float a0 = xk [(r0+0)*C_+c], a1 = xk [(r0+1)*C_+c];
    float b0 = xvn[(r0+0)*C_+c], b1 = xvn[(r0+1)*C_+c];
    #pragma unroll
    for (int sI=0;sI<6;++sI) {
      float wk = wkT[(size_t)c*C_ + ch + 64*sI];
      float wv = wvT[(size_t)c*C_ + ch + 64*sI];
      accK[0][sI] += a0*wk; accK[1][sI] += a1*wk;
      accV[0][sI] += b0*wv; accV[1][sI] += b1*wv;
    }
  }
  #pragma unroll
  for (int j=0;j<2;++j) {
    int prow = pr0 + r0 + j;
    float m0 = mu_p[(size_t)prow*3+0];
    float m1 = mu_p[(size_t)prow*3+1];
    float m2 = mu_p[(size_t)prow*3+2];
    #pragma unroll
    for (int sI=0;sI<6;++sI) {
      int i = ch + 64*sI;
      accK[j][sI] += m0*Wpos[i*3+0] + m1*Wpos[i*3+1] + m2*Wpos[i*3+2];
    }
  }
  __syncthreads();
  float* stg = sm;
  #pragma unroll
  for (int j=0;j<2;++j)
    #pragma unroll
    for (int sI=0;sI<6;++sI)
      stg[(ch + 64*sI)*9 + (r0+j)] = accK[j][sI];
  __syncthreads();
  int kp0 = pr0 & (KP-1);
  int kp_tile_g = pr0 >> 4;
  int rhalf = kp0 & 8;
  int b = pr0 >> 9;
  for (int u = t; u < 384; u += 256) {
    int cc = u / 32, rem = u % 32, l4g = rem >> 3, row = rem & 7;
    int c0 = cc*32 + l4g*8;
    u16 hh[8], ll[8];
    #pragma unroll
    for (int e = 0; e < 8; ++e) split_hl(stg[(c0+e)*9 + row], hh[e], ll[e]);
    int lane = (rhalf + row) + 16*l4g;
    size_t fo = ((size_t)kp_tile_g*12 + cc)*512 + (size_t)lane*8;
    *(ushort4*)&khi[fo]   = make_ushort4(hh[0],hh[1],hh[2],hh[3]);
    *(ushort4*)&khi[fo+4] = make_ushort4(hh[4],hh[5],hh[6],hh[7]);
    *(ushort4*)&klo[fo]   = make_ushort4(ll[0],ll[1],ll[2],ll[3]);
    *(ushort4*)&klo[fo+4] = make_ushort4(ll[4],ll[5],ll[6],ll[7]);
  }
  __syncthreads();
  #pragma unroll
  for (int j=0;j<2;++j)
    #pragma unroll
    for (int sI=0;sI<6;++sI)
      stg[(ch + 64*sI)*9 + (r0+j)] = accV[j][sI];
  __syncthreads();
  int kpc = kp0 >> 5, l4gv = (kp0 >> 3) & 3;
  for (int u = t; u < 384; u += 256) {
    int c = u;
    u16 hh[8], ll[8];
    #pragma unroll
    for (int e = 0; e < 8; ++e) split_hl(stg[c*9 + e], hh[e], ll[e]);
    int lane = (c & 15) + 16*l4gv;
    size_t fo = (((size_t)b*24 + (c >> 4))*16 + kpc)*512 + (size_t)lane*8;
    *(ushort4*)&vthi[fo]   = make_ushort4(hh[0],hh[1],hh[2],hh[3]);
    *(ushort4*)&vthi[fo+4] = make_ushort4(hh[4],hh[5],hh[6],hh[7]);
    *(ushort4*)&vtlo[fo]   = make_ushort4(ll[0],ll[1],ll[2],ll[3]);
    *(ushort4*)&vtlo[fo+4] = make_ushort4(ll[4],ll[5],ll[6],ll[7]);
  }
}

// ---------------- K2: s_trunk -> q hi/lo packed ----------------
__global__ __launch_bounds__(384) void k_qproj(
    const float* __restrict__ st, const float* __restrict__ g,
    const float* __restrict__ bb, const float* __restrict__ WT,
    u16* __restrict__ qhi, u16* __restrict__ qlo) {
  __shared__ float xln[16*C_];
  int t = threadIdx.x;
  int row0 = blockIdx.x * 16;
  if (t < 256) {
    int r = t >> 4, l = t & 15;
    const float* xr = st + (size_t)(row0 + r) * C_;
    float xv[24]; float s = 0.f;
    #pragma unroll
    for (int j = 0; j < 24; ++j) { xv[j] = xr[l + 16*j]; s += xv[j]; }
    #pragma unroll
    for (int m = 1; m < 16; m <<= 1) s += __shfl_xor(s, m);
    float mean = s * (1.0f/C_);
    float vs = 0.f;
    #pragma unroll
    for (int j = 0; j < 24; ++j) { float d = xv[j]-mean; vs += d*d; }
    #pragma unroll
    for (int m = 1; m < 16; m <<= 1) vs += __shfl_xor(vs, m);
    float rs = 1.0f / sqrtf(vs * (1.0f/C_) + 1e-5f);
    #pragma unroll
    for (int j = 0; j < 24; ++j) {
      int c = l + 16*j;
      xln[r*C_ + c] = (xv[j]-mean)*rs*g[c] + bb[c];
    }
  }
  __syncthreads();
  int g96 = t % 96, rg = t / 96;
  int i0 = g96 * 4, r0 = rg * 4;
  float4 a0 = make_float4(0,0,0,0), a1 = a0, a2 = a0, a3 = a0;
  #pragma unroll 4
  for (int c = 0; c < C_; ++c) {
    float4 wv = *(const float4*)&WT[(size_t)c*C_ + i0];
    float x0 = xln[(r0+0)*C_+c];
    float x1 = xln[(r0+1)*C_+c];
    float x2 = xln[(r0+2)*C_+c];
    float x3 = xln[(r0+3)*C_+c];
    a0.x += x0*wv.x; a0.y += x0*wv.y; a0.z += x0*wv.z; a0.w += x0*wv.w;
    a1.x += x1*wv.x; a1.y += x1*wv.y; a1.z += x1*wv.z; a1.w += x1*wv.w;
    a2.x += x2*wv.x; a2.y += x2*wv.y; a2.z += x2*wv.z; a2.w += x2*wv.w;
    a3.x += x3*wv.x; a3.y += x3*wv.y; a3.z += x3*wv.z; a3.w += x3*wv.w;
  }
  float4 av[4] = {a0, a1, a2, a3};
  #pragma unroll
  for (int j = 0; j < 4; ++j) {
    int nrow = row0 + r0 + j;
    u16 h0,l0,h1,l1,h2,l2,h3,l3;
    split_hl(av[j].x, h0, l0); split_hl(av[j].y, h1, l1);
    split_hl(av[j].z, h2, l2); split_hl(av[j].w, h3, l3);
    size_t fo = (((size_t)(nrow >> 4))*12 + (i0 >> 5))*512
              + (size_t)(((nrow & 15) + 16*((i0 >> 3) & 3))*8 + (i0 & 7));
    *(ushort4*)&qhi[fo] = make_ushort4(h0,h1,h2,h3);
    *(ushort4*)&qlo[fo] = make_ushort4(l0,l1,l2,l3);
  }
}

// ---------------- K3: MFMA router (packed-fragment loads) ----------------
__global__ __launch_bounds__(256, 2) void k_route(
    const u16* __restrict__ qhi, const u16* __restrict__ qlo,
    const u16* __restrict__ khi, const u16* __restrict__ klo,
    const u16* __restrict__ vthi, const u16* __restrict__ vtlo,
    const u16* __restrict__ spt,
    const float* __restrict__ mu_p, const float* __restrict__ Sig_p,
    const float* __restrict__ mask_parent, const float* __restrict__ node_mask,
    float* __restrict__ out, u16* __restrict__ pf,
    float* __restrict__ mu0, float* __restrict__ sigpc) {
  __shared__ u16   wlds[2*16*512];
  __shared__ float smask[KP];
  __shared__ float smuT[3*KP];
  __shared__ float ssigT[9*KP];
  __shared__ float red[2][2][2][16];

  int t = threadIdx.x;
  int bb = blockIdx.y;
  int nb = blockIdx.x * 32;
  int wave = t >> 6, lane = t & 63;
  int wg = wave >> 1, wh = wave & 1;
  int l15 = lane & 15, l4 = lane >> 4;

  {
    const float4* ms = (const float4*)(mask_parent + (size_t)bb*KP);
    for (int i = t; i < 128; i += 256) ((float4*)smask)[i] = ms[i];
    const float* mu = mu_p + (size_t)bb*KP*3;
    for (int i = t; i < 3*KP; i += 256) {
      int cm = i >> 9, k = i & 511;
      smuT[i] = mu[k*3 + cm];
    }
    const float* sb = Sig_p + (size_t)bb*KP*9;
    for (int i = t; i < 9*KP; i += 256) {
      int e = i >> 9, k = i & 511;
      int ii = e / 3, jj = e % 3;
      ssigT[i] = 0.5f*(sb[k*9 + ii*3 + jj] + sb[k*9 + jj*3 + ii]);
    }
  }
  __syncthreads();

  const u16* qhB = qhi + ((size_t)(bb*256 + (nb >> 4) + wg))*12*512;
  const u16* qlB = qlo + ((size_t)(bb*256 + (nb >> 4) + wg))*12*512;
  const u16* khB = khi + ((size_t)(bb*32 + wh*16))*12*512;
  const u16* klB = klo + ((size_t)(bb*32 + wh*16))*12*512;
  f4v acc[16];
  #pragma unroll
  for (int kt = 0; kt < 16; ++kt) acc[kt] = (f4v){0.f,0.f,0.f,0.f};
  for (int cs = 0; cs < 12; ++cs) {
    s8v bqh = *(const s8v*)&qhB[(size_t)cs*512 + lane*8];
    s8v bql = *(const s8v*)&qlB[(size_t)cs*512 + lane*8];
    #pragma unroll
    for (int kt = 0; kt < 16; ++kt) {
      s8v ah = *(const s8v*)&khB[((size_t)kt*12 + cs)*512 + lane*8];
      s8v al = *(const s8v*)&klB[((size_t)kt*12 + cs)*512 + lane*8];
      acc[kt] = MFMA(ah, bqh, acc[kt]);
      acc[kt] = MFMA(ah, bql, acc[kt]);
      acc[kt] = MFMA(al, bqh, acc[kt]);
    }
  }

  float mx = -3.4e38f;
  #pragma unroll
  for (int kt = 0; kt < 16; ++kt) {
    const float4 m4 = *(const float4*)&smask[wh*256 + kt*16 + l4*4];
    acc[kt][0] = (m4.x > 0.5f) ? acc[kt][0]*TAU_INV : NEGV;
    acc[kt][1] = (m4.y > 0.5f) ? acc[kt][1]*TAU_INV : NEGV;
    acc[kt][2] = (m4.z > 0.5f) ? acc[kt][2]*TAU_INV : NEGV;
    acc[kt][3] = (m4.w > 0.5f) ? acc[kt][3]*TAU_INV : NEGV;
    mx = fmaxf(mx, fmaxf(fmaxf(acc[kt][0], acc[kt][1]), fmaxf(acc[kt][2], acc[kt][3])));
  }
  mx = fmaxf(mx, __shfl_xor(mx, 16));
  mx = fmaxf(mx, __shfl_xor(mx, 32));
  if (lane < 16) red[wg][wh][0][lane] = mx;
  __syncthreads();
  mx = fmaxf(red[wg][0][0][l15], red[wg][1][0][l15]);
  float smv = 0.f;
  #pragma unroll
  for (int kt = 0; kt < 16; ++kt) {
    #pragma unroll
    for (int r = 0; r < 4; ++r) {
      float e = __expf(acc[kt][r] - mx);
      acc[kt][r] = e; smv += e;
    }
  }
  smv += __shfl_xor(smv, 16);
  smv += __shfl_xor(smv, 32);
  if (lane < 16) red[wg][wh][1][lane] = smv;
  __syncthreads();
  smv = red[wg][0][1][l15] + red[wg][1][1][l15];
  float nm = node_mask[(size_t)bb*N_ + nb + wg*16 + l15];
  float scl = nm / smv;
  bool uni = !(nm > 0.5f);
  float uval = nm * (1.0f/KP);
  #pragma unroll
  for (int kt = 0; kt < 16; ++kt) {
    ushort4 wv;
    wv.x = f2b_rne(uni ? uval : acc[kt][0]*scl);
    wv.y = f2b_rne(uni ? uval : acc[kt][1]*scl);
    wv.z = f2b_rne(uni ? uval : acc[kt][2]*scl);
    wv.w = f2b_rne(uni ? uval : acc[kt][3]*scl);
    int kpl = wh*256 + kt*16 + l4*4;
    int bo = (l15*1024 + kpl*2) ^ ((l15 & 7) << 4);
    *(ushort4*)&wlds[wg*8192 + (bo >> 1)] = wv;
  }
  __syncthreads();

  {
    int cb = wh * 192;
    for (int ct = 0; ct < 12; ++ct) {
      int c_tile = wh*12 + ct;
      int c = cb + ct*16 + l15;
      f4v aS = (f4v){0.f,0.f,0.f,0.f};
      f4v aP = (f4v){0.f,0.f,0.f,0.f};
      const u16* vhB = vthi + (((size_t)bb*24 + c_tile)*16)*512;
      const u16* vlB = vtlo + (((size_t)bb*24 + c_tile)*16)*512;
      const u16* spB = spt  + (((size_t)bb*24 + c_tile)*16)*512;
      #pragma unroll
      for (int ks = 0; ks < 16; ++ks) {
        int kp = ks*32 + l4*8;
        int bo = (l15*1024 + kp*2) ^ ((l15 & 7) << 4);
        s8v aw = *(const s8v*)&wlds[wg*8192 + (bo >> 1)];
        s8v bh = *(const s8v*)&vhB[(size_t)ks*512 + lane*8];
        s8v bl = *(const s8v*)&vlB[(size_t)ks*512 + lane*8];
        s8v bs = *(const s8v*)&spB[(size_t)ks*512 + lane*8];
        aS = MFMA(aw, bh, aS);
        aS = MFMA(aw, bl, aS);
        aP = MFMA(aw, bs, aP);
      }
      #pragma unroll
      for (int r = 0; r < 4; ++r) {
        int n = nb + wg*16 + l4*4 + r;
        size_t row = (size_t)bb*N_ + n;
        out[row*396 + c] = aS[r];
        pf[row*C_ + c] = f2b_rne(aP[r]);
      }
    }
  }

  for (int u = t; u < 384; u += 256) {
    int r = u / 12, cm = u % 12;
    int wgr = r >> 4, nl = r & 15;
    const u16* wbase = &wlds[wgr * 8192];
    const float* tb = (cm < 3) ? &smuT[cm*512] : &ssigT[(cm-3)*512];
    float a = 0.f;
    for (int k4 = 0; k4 < 512; k4 += 4) {
      int bo = (nl*1024 + k4*2) ^ ((nl & 7) << 4);
      ushort4 w4 = *(const ushort4*)&wbase[bo >> 1];
      float4 m4 = *(const float4*)&tb[k4];
      a += b2f(w4.x)*m4.x + b2f(w4.y)*m4.y + b2f(w4.z)*m4.z + b2f(w4.w)*m4.w;
    }
    size_t row = (size_t)bb*N_ + nb + r;
    if (cm < 3) {
      mu0[row*3 + cm] = a;
    } else {
      int e = cm - 3;
      if (e == 0 || e == 4 || e == 8) a += JITTER_;
      sigpc[row*9 + e] = a;
    }
  }
}

// ---------------- K4: mu-offset MLP (pf bf16 in) ----------------
__global__ __launch_bounds__(384) void k_mlp(
    const u16* __restrict__ pf, const float* __restrict__ g,
    const float* __restrict__ bb, const float* __restrict__ W1T,
    const float* __restrict__ b1, const float* __restrict__ W2,
    const float* __restrict__ b2v, const float* __restrict__ node_mask,
    float* __restrict__ mu0) {
  __shared__ float xln[16*C_];
  __shared__ float h[16*C_];
  int t = threadIdx.x;
  int row0 = blockIdx.x * 16;
  if (t < 256) {
    int r = t >> 4, l = t & 15;
    const u16* xr = pf + (size_t)(row0 + r) * C_;
    float xv[24]; float s = 0.f;
    #pragma unroll
    for (int j = 0; j < 24; ++j) { xv[j] = b2f(xr[l + 16*j]); s += xv[j]; }
    #pragma unroll
    for (int m = 1; m < 16; m <<= 1) s += __shfl_xor(s, m);
    float mean = s * (1.0f/C_);
    float vs = 0.f;
    #pragma unroll
    for (int j = 0; j < 24; ++j) { float d = xv[j]-mean; vs += d*d; }
    #pragma unroll
    for (int m = 1; m < 16; m <<= 1) vs += __shfl_xor(vs, m);
    float rs = 1.0f / sqrtf(vs * (1.0f/C_) + 1e-5f);
    #pragma unroll
    for (int j = 0; j < 24; ++j) {
      int c = l + 16*j;
      xln[r*C_ + c] = (xv[j]-mean)*rs*g[c] + bb[c];
    }
  }
  __syncthreads();
  {
    int g96 = t % 96, rg = t / 96;
    int i0 = g96 * 4, r0 = rg * 4;
    float4 a0 = make_float4(0,0,0,0), a1 = a0, a2 = a0, a3 = a0;
    #pragma unroll 4
    for (int c = 0; c < C_; ++c) {
      float4 wv = *(const float4*)&W1T[(size_t)c*C_ + i0];
      float x0 = xln[(r0+0)*C_+c];
      float x1 = xln[(r0+1)*C_+c];
      float x2 = xln[(r0+2)*C_+c];
      float x3 = xln[(r0+3)*C_+c];
      a0.x += x0*wv.x; a0.y += x0*wv.y; a0.z += x0*wv.z; a0.w += x0*wv.w;
      a1.x += x1*wv.x; a1.y += x1*wv.y; a1.z += x1*wv.z; a1.w += x1*wv.w;
      a2.x += x2*wv.x; a2.y += x2*wv.y; a2.z += x2*wv.z; a2.w += x2*wv.w;
      a3.x += x3*wv.x; a3.y += x3*wv.y; a3.z += x3*wv.z; a3.w += x3*wv.w;
    }
    float4 bv4 = *(const float4*)&b1[i0];
    float4 av[4] = {a0, a1, a2, a3};
    #pragma unroll
    for (int j = 0; j < 4; ++j) {
      float4 v = av[j];
      v.x += bv4.x; v.y += bv4.y; v.z += bv4.z; v.w += bv4.w;
      v.x = v.x / (1.0f + __expf(-v.x));
      v.y = v.y / (1.0f + __expf(-v.y));
      v.z = v.z / (1.0f + __expf(-v.z));
      v.w = v.w / (1.0f + __expf(-v.w));
      *(float4*)&h[(r0+j)*C_ + i0] = v;
    }
  }
  __syncthreads();
  if (t < 256) {
    int r = t >> 4, l = t & 15;
    const float* hr = &h[r*C_];
    float pd0=0.f, pd1=0.f, pd2=0.f;
    #pragma unroll
    for (int j=0;j<24;++j) {
      int c = l + 16*j;
      float hv = hr[c];
      pd0 += hv*W2[c];
      pd1 += hv*W2[C_ + c];
      pd2 += hv*W2[2*C_ + c];
    }
    #pragma unroll
    for (int m = 1; m < 16; m <<= 1) {
      pd0 += __shfl_xor(pd0, m);
      pd1 += __shfl_xor(pd1, m);
      pd2 += __shfl_xor(pd2, m);
    }
    if (l == 0) {
      size_t row = (size_t)(row0 + r);
      float nmv = node_mask[row];
      float d0 = (pd0 + b2v[0]) * MU_SCALE_;
      float d1 = (pd1 + b2v[1]) * MU_SCALE_;
      float d2 = (pd2 + b2v[2]) * MU_SCALE_;
      mu0[row*3+0] = (mu0[row*3+0] + d0) * nmv;
      mu0[row*3+1] = (mu0[row*3+1] + d1) * nmv;
      mu0[row*3+2] = (mu0[row*3+2] + d2) * nmv;
    }
  }
}

// ---------------- K5: kNN sigma + Sig0 + mu0 out ----------------
// cand[m] = (x, y, z, maskpenalty); qq-partition starts rotated by qq*2 to
// spread the 4 concurrent b128 reads across disjoint bank groups.
__global__ __launch_bounds__(256) void k_knn(
    const float* __restrict__ mu0, const float* __restrict__ node_mask,
    const float* __restrict__ sigpc, float* __restrict__ out) {
  __shared__ float4 cand[N_];        // 64 KB
  __shared__ float mrg[64*32];       // 8 KB
  int t = threadIdx.x;
  int b = blockIdx.y;
  int n0 = blockIdx.x * 64;
  const float* mb = mu0 + (size_t)b*N_*3;
  const float* nmB = node_mask + (size_t)b*N_;
  for (int idx = t; idx < N_; idx += 256) {
    float x = mb[idx*3+0], y = mb[idx*3+1], z = mb[idx*3+2];
    float w = (nmB[idx] > 0.5f) ? 0.f : BIG_;
    cand[idx] = make_float4(x, y, z, w);
  }
  __syncthreads();
  int r = t >> 2, qq = t & 3;
  int n = n0 + r;
  float4 e = cand[n];
  float best[8];
  #pragma unroll
  for (int i=0;i<8;++i) best[i] = BIG_;
  int base = qq * (N_/4);
  #pragma unroll 4
  for (int i = 0; i < N_/4; ++i) {
    int m = base + ((i + qq*2) & (N_/4 - 1));
    float4 c = cand[m];
    float dx = c.x - e.x, dy = c.y - e.y, dz = c.z - e.z;
    float d2 = dx*dx + dy*dy + dz*dz + c.w;
    if (m == n) d2 = BIG_;
    if (d2 < best[7]) {
      #pragma unroll
      for (int i2 = 7; i2 >= 1; --i2)
        best[i2] = (best[i2] > d2) ? ((best[i2-1] > d2) ? best[i2-1] : d2) : best[i2];
      best[0] = (best[0] > d2) ? d2 : best[0];
    }
  }
  #pragma unroll
  for (int i=0;i<8;++i) mrg[(r*4+qq)*8 + i] = best[i];
  __syncthreads();
  if (qq == 0) {
    float arr[32];
    #pragma unroll
    for (int i=0;i<32;++i) arr[i] = mrg[r*32 + i];
    float ssum = 0.f;
    #pragma unroll
    for (int sel=0; sel<8; ++sel) {
      float mn = arr[0];
      #pragma unroll
      for (int i=1;i<32;++i) mn = fminf(mn, arr[i]);
      ssum += sqrtf(fmaxf(mn, 0.f));
      bool done = false;
      #pragma unroll
      for (int i=0;i<32;++i) {
        bool hit = (!done) && (arr[i] == mn);
        arr[i] = hit ? BIG_ : arr[i];
        done = done || hit;
      }
    }
    float sigma = fminf(fmaxf(ALPHA_ * (ssum * 0.125f), SFLOOR_), SCEIL_);
    float s2 = sigma*sigma + JITTER_;
    size_t row = (size_t)b*N_ + n;
    float nmv = nmB[n];
    size_t orow = row * 396;
    const float* sg = &sigpc[row*9];
    #pragma unroll
    for (int e2=0;e2<9;++e2) {
      bool diag = (e2==0)||(e2==4)||(e2==8);
      float v = BETA_*sg[e2] + (diag ? ((1.0f-BETA_)*s2 + JITTER_) : 0.0f);
      out[orow + 387 + e2] = v * nmv;
    }
    out[orow + 384] = e.x;
    out[orow + 385] = e.y;
    out[orow + 386] = e.z;
  }
}

extern "C" void kernel_launch(void* const* d_in, const int* in_sizes, int n_in,
                              void* d_out, int out_size, void* d_ws, size_t ws_size,
                              hipStream_t stream) {
  const float* s_parent    = (const float*)d_in[0];
  const float* mu_p        = (const float*)d_in[1];
  const float* Sig_p       = (const float*)d_in[2];
  const float* mask_parent = (const float*)d_in[3];
  const float* node_mask   = (const float*)d_in[4];
  const float* s_trunk     = (const float*)d_in[5];
  const float* Wq   = (const float*)d_in[6];
  const float* Wk   = (const float*)d_in[7];
  const float* Wv   = (const float*)d_in[8];
  const float* Wpos = (const float*)d_in[9];
  const float* lnq_g = (const float*)d_in[10];
  const float* lnq_b = (const float*)d_in[11];
  const float* lnk_g = (const float*)d_in[12];
  const float* lnk_b = (const float*)d_in[13];
  const float* lnv_g = (const float*)d_in[14];
  const float* lnv_b = (const float*)d_in[15];
  const float* mo_ln_g = (const float*)d_in[16];
  const float* mo_ln_b = (const float*)d_in[17];
  const float* mo_W1 = (const float*)d_in[18];
  const float* mo_b1 = (const float*)d_in[19];
  const float* mo_W2 = (const float*)d_in[20];
  const float* mo_b2 = (const float*)d_in[21];

  char* wsb = (char*)d_ws;
  u16* qhi  = (u16*)wsb;
  u16* qlo  = qhi + (size_t)B_*N_*C_;
  u16* khi  = (u16*)(wsb + 25165824);
  u16* klo  = khi + (size_t)B_*KP*C_;
  u16* vthi = (u16*)(wsb + 25165824 + 3145728);
  u16* vtlo = vthi + (size_t)B_*C_*KP;
  char* pfb = wsb + 25165824 + 2*3145728;
  u16* pf   = (u16*)pfb;
  u16* spt  = (u16*)(pfb + 12582912);
  float* wqT = (float*)(pfb + 12582912 + 1572864);
  float* wkT = wqT + (size_t)C_*C_;
  float* wvT = wkT + (size_t)C_*C_;
  float* w1T = (float*)(wsb + 25165824);
  float* mu0 = (float*)(wsb + 25165824 + 2*3145728 + 25165824);
  float* sg  = mu0 + (size_t)B_*N_*3;
  float* out = (float*)d_out;

  dim3 tb(32, 8);
  dim3 tg(C_/32, C_/32);
  k_transpose<<<tg, tb, 0, stream>>>(Wq, wqT);
  k_transpose<<<tg, tb, 0, stream>>>(Wk, wkT);
  k_transpose<<<tg, tb, 0, stream>>>(Wv, wvT);
  k_sptr<<<dim3(KP/32, C_/32, B_), dim3(256), 0, stream>>>(s_parent, spt);

  k_kvproj<<<dim3(B_*KP/8), dim3(256), 0, stream>>>(
      s_parent, mu_p, lnk_g, lnk_b, lnv_g, lnv_b, wkT, wvT, Wpos,
      khi, klo, vthi, vtlo);
  k_qproj<<<dim3(B_*N_/16), dim3(384), 0, stream>>>(
      s_trunk, lnq_g, lnq_b, wqT, qhi, qlo);
  k_route<<<dim3(N_/32, B_), dim3(256), 0, stream>>>(
      qhi, qlo, khi, klo, vthi, vtlo, spt, mu_p, Sig_p,
      mask_parent, node_mask, out, pf, mu0, sg);
  k_transpose<<<tg, tb, 0, stream>>>(mo_W1, w1T);
  k_mlp<<<dim3(B_*N_/16), dim3(384), 0, stream>>>(
      pf, mo_ln_g, mo_ln_b, w1T, mo_b1, mo_W2, mo_b2, node_mask, mu0);
  k_knn<<<dim3(N_/64, B_), dim3(256), 0, stream>>>(
      mu0, node_mask, sg, out);
}

// Round 6
// 533.934 us; speedup vs baseline: 3.8301x; 1.0347x over previous
//
#include <hip/hip_runtime.h>
#include <math.h>

#define B_ 4
#define N_ 4096
#define KP 512
#define C_ 384

typedef unsigned short u16;
typedef short s8v __attribute__((ext_vector_type(8)));
typedef float f4v __attribute__((ext_vector_type(4)));
#define MFMA(a,b,c) __builtin_amdgcn_mfma_f32_16x16x32_bf16(a,b,c,0,0,0)

constexpr float TAU_INV  = 10.0f;
constexpr float BETA_    = 0.85f;
constexpr float JITTER_  = 1e-6f;
constexpr float ALPHA_   = 1.5f;
constexpr float SFLOOR_  = 1e-3f;
constexpr float SCEIL_   = 100.0f;
constexpr float MU_SCALE_= 0.25f;
constexpr float NEGV     = -1e9f;
constexpr float BIG_     = 1e9f;

__device__ __forceinline__ u16 f2b_rne(float f) {
  unsigned int u = __float_as_uint(f);
  return (u16)((u + 0x7FFFu + ((u >> 16) & 1u)) >> 16);
}
__device__ __forceinline__ float b2f(u16 h) {
  return __uint_as_float(((unsigned int)h) << 16);
}
__device__ __forceinline__ void split_hl(float f, u16& hi, u16& lo) {
  unsigned int u = __float_as_uint(f);
  hi = (u16)(u >> 16);
  float fh = __uint_as_float(u & 0xFFFF0000u);
  lo = f2b_rne(f - fh);
}

// Packed fragment layouts (per 16x16x32 MFMA), 1KB contiguous per fragment:
//  K (A-op):   [b*32+kp_tile][cc(12)][lane][8], lane=(kp&15)+16*((c>>3)&3)
//  q (B-op):   [n>>4][cc(12)][lane][8],        lane=(n&15)+16*((c>>3)&3)
//  V^T/spT (B-op): [b*24+c_tile][ks(16)][lane][8], lane=(c&15)+16*((kp>>3)&3)
//  musig (B-op): [b][ks(16)][lane][8], cols 0-2=mu, 3-11=symSig, 12-15=0

// ---------------- K0: 384x384 fp32 transpose ----------------
__global__ __launch_bounds__(256) void k_transpose(
    const float* __restrict__ W, float* __restrict__ WT) {
  __shared__ float tile[32][33];
  int bx = blockIdx.x * 32, by = blockIdx.y * 32;
  int tx = threadIdx.x, ty = threadIdx.y;   // 32 x 8
  #pragma unroll
  for (int j = 0; j < 32; j += 8)
    tile[ty + j][tx] = W[(size_t)(by + ty + j) * C_ + bx + tx];
  __syncthreads();
  #pragma unroll
  for (int j = 0; j < 32; j += 8)
    WT[(size_t)(bx + ty + j) * C_ + by + tx] = tile[tx][ty + j];
}

// ---------------- K0b: s_parent -> spT bf16 packed fragments ----------------
__global__ __launch_bounds__(256) void k_sptr(
    const float* __restrict__ sp, u16* __restrict__ spt) {
  __shared__ float tl[32][33];
  int bx = blockIdx.x * 32;   // kp
  int by = blockIdx.y * 32;   // c
  int bz = blockIdx.z;        // b
  const float* s = sp + (size_t)bz * KP * C_;
  int tx = threadIdx.x & 31, ty4 = threadIdx.x >> 5;
  #pragma unroll
  for (int j = 0; j < 32; j += 8)
    tl[ty4 + j][tx] = s[(size_t)(bx + ty4 + j) * C_ + by + tx];  // tl[kp_l][c_l]
  __syncthreads();
  int t = threadIdx.x;
  if (t < 128) {
    int c_l = t >> 2, krun = t & 3;
    int kp0r = krun * 8;
    u16 hh[8];
    #pragma unroll
    for (int e = 0; e < 8; ++e) hh[e] = f2b_rne(tl[kp0r + e][c_l]);
    int cg = by + c_l;
    int lane = (cg & 15) + 16 * krun;
    size_t fo = (((size_t)bz*24 + (cg >> 4))*16 + (bx >> 5))*512 + (size_t)lane*8;
    *(ushort4*)&spt[fo]   = make_ushort4(hh[0],hh[1],hh[2],hh[3]);
    *(ushort4*)&spt[fo+4] = make_ushort4(hh[4],hh[5],hh[6],hh[7]);
  }
}

// ---------------- K0c: mu_p + sym(Sig_p) -> packed hi/lo B fragments ----------------
__global__ __launch_bounds__(256) void k_musig(
    const float* __restrict__ mu_p, const float* __restrict__ Sig_p,
    u16* __restrict__ mshi, u16* __restrict__ mslo) {
  int b = blockIdx.x;
  int t = threadIdx.x;
  for (int s = t; s < 1024; s += 256) {
    int ks = s >> 6, lane = s & 63;
    int col = lane & 15, kb = lane >> 4;
    u16 hh[8], ll[8];
    #pragma unroll
    for (int e = 0; e < 8; ++e) {
      int kp = ks*32 + kb*8 + e;
      float v = 0.f;
      if (col < 3) {
        v = mu_p[((size_t)b*KP + kp)*3 + col];
      } else if (col < 12) {
        int ee = col - 3, ii = ee/3, jj = ee%3;
        const float* sg = &Sig_p[((size_t)b*KP + kp)*9];
        v = 0.5f*(sg[ii*3+jj] + sg[jj*3+ii]);
      }
      split_hl(v, hh[e], ll[e]);
    }
    size_t fo = (((size_t)b*16 + ks)*64 + lane)*8;
    *(ushort4*)&mshi[fo]   = make_ushort4(hh[0],hh[1],hh[2],hh[3]);
    *(ushort4*)&mshi[fo+4] = make_ushort4(hh[4],hh[5],hh[6],hh[7]);
    *(ushort4*)&mslo[fo]   = make_ushort4(ll[0],ll[1],ll[2],ll[3]);
    *(ushort4*)&mslo[fo+4] = make_ushort4(ll[4],ll[5],ll[6],ll[7]);
  }
}

// ---------------- K1: parents -> K hi/lo packed, V^T hi/lo packed ----------------
__global__ __launch_bounds__(256) void k_kvproj(
    const float* __restrict__ sp, const float* __restrict__ mu_p,
    const float* __restrict__ gk, const float* __restrict__ bk,
    const float* __restrict__ gv, const float* __restrict__ bv,
    const float* __restrict__ wkT, const float* __restrict__ wvT,
    const float* __restrict__ Wpos,
    u16* __restrict__ khi, u16* __restrict__ klo,
    u16* __restrict__ vthi, u16* __restrict__ vtlo) {
  __shared__ float sm[2*8*C_];
  float* xk  = sm;
  float* xvn = sm + 8*C_;
  int t = threadIdx.x;
  int pr0 = blockIdx.x * 8;
  if (t < 128) {
    int r = t >> 4, l = t & 15;
    const float* xr = sp + (size_t)(pr0 + r) * C_;
    float xv[24]; float s = 0.f;
    #pragma unroll
    for (int j = 0; j < 24; ++j) { xv[j] = xr[l + 16*j]; s += xv[j]; }
    #pragma unroll
    for (int m = 1; m < 16; m <<= 1) s += __shfl_xor(s, m);
    float mean = s * (1.0f/C_);
    float vs = 0.f;
    #pragma unroll
    for (int j = 0; j < 24; ++j) { float d = xv[j]-mean; vs += d*d; }
    #pragma unroll
    for (int m = 1; m < 16; m <<= 1) vs += __shfl_xor(vs, m);
    float rs = 1.0f / sqrtf(vs * (1.0f/C_) + 1e-5f);
    #pragma unroll
    for (int j = 0; j < 24; ++j) {
      int c = l + 16*j;
      float xc = (xv[j]-mean)*rs;
      xk [r*C_ + c] = xc*gk[c] + bk[c];
      xvn[r*C_ + c] = xc*gv[c] + bv[c];
    }
  }
  __syncthreads();
  int w = t >> 6, ch = t & 63;
  int r0 = w * 2;
  float accK[2][6], accV[2][6];
  #pragma unroll
  for (int j=0;j<2;++j)
    #pragma unroll
    for (int sI=0;sI<6;++sI) { accK[j][sI]=0.f; accV[j][sI]=0.f; }
  #pragma unroll 2
  for (int c = 0; c < C_; ++c) {
    float a0 = xk [(r0+0)*C_+c], a1 = xk [(r0+1)*C_+c];
    float b0 = xvn[(r0+0)*C_+c], b1 = xvn[(r0+1)*C_+c];
    #pragma unroll
    for (int sI=0;sI<6;++sI) {
      float wk = wkT[(size_t)c*C_ + ch + 64*sI];
      float wv = wvT[(size_t)c*C_ + ch + 64*sI];
      accK[0][sI] += a0*wk; accK[1][sI] += a1*wk;
      accV[0][sI] += b0*wv; accV[1][sI] += b1*wv;
    }
  }
  #pragma unroll
  for (int j=0;j<2;++j) {
    int prow = pr0 + r0 + j;
    float m0 = mu_p[(size_t)prow*3+0];
    float m1 = mu_p[(size_t)prow*3+1];
    float m2 = mu_p[(size_t)prow*3+2];
    #pragma unroll
    for (int sI=0;sI<6;++sI) {
      int i = ch + 64*sI;
      accK[j][sI] += m0*Wpos[i*3+0] + m1*Wpos[i*3+1] + m2*Wpos[i*3+2];
    }
  }
  __syncthreads();
  float* stg = sm;
  #pragma unroll
  for (int j=0;j<2;++j)
    #pragma unroll
    for (int sI=0;sI<6;++sI)
      stg[(ch + 64*sI)*9 + (r0+j)] = accK[j][sI];
  __syncthreads();
  int kp0 = pr0 & (KP-1);
  int kp_tile_g = pr0 >> 4;
  int rhalf = kp0 & 8;
  int b = pr0 >> 9;
  for (int u = t; u < 384; u += 256) {
    int cc = u / 32, rem = u % 32, l4g = rem >> 3, row = rem & 7;
    int c0 = cc*32 + l4g*8;
    u16 hh[8], ll[8];
    #pragma unroll
    for (int e = 0; e < 8; ++e) split_hl(stg[(c0+e)*9 + row], hh[e], ll[e]);
    int lane = (rhalf + row) + 16*l4g;
    size_t fo = ((size_t)kp_tile_g*12 + cc)*512 + (size_t)lane*8;
    *(ushort4*)&khi[fo]   = make_ushort4(hh[0],hh[1],hh[2],hh[3]);
    *(ushort4*)&khi[fo+4] = make_ushort4(hh[4],hh[5],hh[6],hh[7]);
    *(ushort4*)&klo[fo]   = make_ushort4(ll[0],ll[1],ll[2],ll[3]);
    *(ushort4*)&klo[fo+4] = make_ushort4(ll[4],ll[5],ll[6],ll[7]);
  }
  __syncthreads();
  #pragma unroll
  for (int j=0;j<2;++j)
    #pragma unroll
    for (int sI=0;sI<6;++sI)
      stg[(ch + 64*sI)*9 + (r0+j)] = accV[j][sI];
  __syncthreads();
  int kpc = kp0 >> 5, l4gv = (kp0 >> 3) & 3;
  for (int u = t; u < 384; u += 256) {
    int c = u;
    u16 hh[8], ll[8];
    #pragma unroll
    for (int e = 0; e < 8; ++e) split_hl(stg[c*9 + e], hh[e], ll[e]);
    int lane = (c & 15) + 16*l4gv;
    size_t fo = (((size_t)b*24 + (c >> 4))*16 + kpc)*512 + (size_t)lane*8;
    *(ushort4*)&vthi[fo]   = make_ushort4(hh[0],hh[1],hh[2],hh[3]);
    *(ushort4*)&vthi[fo+4] = make_ushort4(hh[4],hh[5],hh[6],hh[7]);
    *(ushort4*)&vtlo[fo]   = make_ushort4(ll[0],ll[1],ll[2],ll[3]);
    *(ushort4*)&vtlo[fo+4] = make_ushort4(ll[4],ll[5],ll[6],ll[7]);
  }
}

// ---------------- K2: s_trunk -> q hi/lo packed ----------------
__global__ __launch_bounds__(384) void k_qproj(
    const float* __restrict__ st, const float* __restrict__ g,
    const float* __restrict__ bb, const float* __restrict__ WT,
    u16* __restrict__ qhi, u16* __restrict__ qlo) {
  __shared__ float xln[16*C_];
  int t = threadIdx.x;
  int row0 = blockIdx.x * 16;
  if (t < 256) {
    int r = t >> 4, l = t & 15;
    const float* xr = st + (size_t)(row0 + r) * C_;
    float xv[24]; float s = 0.f;
    #pragma unroll
    for (int j = 0; j < 24; ++j) { xv[j] = xr[l + 16*j]; s += xv[j]; }
    #pragma unroll
    for (int m = 1; m < 16; m <<= 1) s += __shfl_xor(s, m);
    float mean = s * (1.0f/C_);
    float vs = 0.f;
    #pragma unroll
    for (int j = 0; j < 24; ++j) { float d = xv[j]-mean; vs += d*d; }
    #pragma unroll
    for (int m = 1; m < 16; m <<= 1) vs += __shfl_xor(vs, m);
    float rs = 1.0f / sqrtf(vs * (1.0f/C_) + 1e-5f);
    #pragma unroll
    for (int j = 0; j < 24; ++j) {
      int c = l + 16*j;
      xln[r*C_ + c] = (xv[j]-mean)*rs*g[c] + bb[c];
    }
  }
  __syncthreads();
  int g96 = t % 96, rg = t / 96;
  int i0 = g96 * 4, r0 = rg * 4;
  float4 a0 = make_float4(0,0,0,0), a1 = a0, a2 = a0, a3 = a0;
  #pragma unroll 4
  for (int c = 0; c < C_; ++c) {
    float4 wv = *(const float4*)&WT[(size_t)c*C_ + i0];
    float x0 = xln[(r0+0)*C_+c];
    float x1 = xln[(r0+1)*C_+c];
    float x2 = xln[(r0+2)*C_+c];
    float x3 = xln[(r0+3)*C_+c];
    a0.x += x0*wv.x; a0.y += x0*wv.y; a0.z += x0*wv.z; a0.w += x0*wv.w;
    a1.x += x1*wv.x; a1.y += x1*wv.y; a1.z += x1*wv.z; a1.w += x1*wv.w;
    a2.x += x2*wv.x; a2.y += x2*wv.y; a2.z += x2*wv.z; a2.w += x2*wv.w;
    a3.x += x3*wv.x; a3.y += x3*wv.y; a3.z += x3*wv.z; a3.w += x3*wv.w;
  }
  float4 av[4] = {a0, a1, a2, a3};
  #pragma unroll
  for (int j = 0; j < 4; ++j) {
    int nrow = row0 + r0 + j;
    u16 h0,l0,h1,l1,h2,l2,h3,l3;
    split_hl(av[j].x, h0, l0); split_hl(av[j].y, h1, l1);
    split_hl(av[j].z, h2, l2); split_hl(av[j].w, h3, l3);
    size_t fo = (((size_t)(nrow >> 4))*12 + (i0 >> 5))*512
              + (size_t)(((nrow & 15) + 16*((i0 >> 3) & 3))*8 + (i0 & 7));
    *(ushort4*)&qhi[fo] = make_ushort4(h0,h1,h2,h3);
    *(ushort4*)&qlo[fo] = make_ushort4(l0,l1,l2,l3);
  }
}

// ---------------- K3: MFMA router: 16-n tile, 4 waves = 4 kp-quarters ----------------
__global__ __launch_bounds__(256, 4) void k_route(
    const u16* __restrict__ qhi, const u16* __restrict__ qlo,
    const u16* __restrict__ khi, const u16* __restrict__ klo,
    const u16* __restrict__ vthi, const u16* __restrict__ vtlo,
    const u16* __restrict__ spt,
    const u16* __restrict__ mshi, const u16* __restrict__ mslo,
    const float* __restrict__ mask_parent, const float* __restrict__ node_mask,
    float* __restrict__ out, u16* __restrict__ pf,
    float* __restrict__ mu0, float* __restrict__ sigpc) {
  __shared__ u16   wlds[16*512];       // 16 KB, XOR-swizzled rows
  __shared__ float smask[KP];          // 2 KB
  __shared__ float red[4][2][16];      // 512 B
  __shared__ float musred[4][64][4];   // 4 KB

  int t = threadIdx.x;
  int bb = blockIdx.y;
  int nb = blockIdx.x * 16;
  int wh = t >> 6, lane = t & 63;
  int l15 = lane & 15, l4 = lane >> 4;

  {
    const float4* ms = (const float4*)(mask_parent + (size_t)bb*KP);
    for (int i = t; i < 128; i += 256) ((float4*)smask)[i] = ms[i];
  }
  __syncthreads();

  // ---- phase 1: logits^T, wave wh covers kp quarter [wh*128, wh*128+128) ----
  const u16* qhB = qhi + ((size_t)(bb*256 + (nb >> 4)))*12*512;
  const u16* qlB = qlo + ((size_t)(bb*256 + (nb >> 4)))*12*512;
  const u16* khB = khi + ((size_t)(bb*32 + wh*8))*12*512;
  const u16* klB = klo + ((size_t)(bb*32 + wh*8))*12*512;
  f4v acc[8];
  #pragma unroll
  for (int kt = 0; kt < 8; ++kt) acc[kt] = (f4v){0.f,0.f,0.f,0.f};
  for (int cs = 0; cs < 12; ++cs) {
    s8v bqh = *(const s8v*)&qhB[(size_t)cs*512 + lane*8];
    s8v bql = *(const s8v*)&qlB[(size_t)cs*512 + lane*8];
    #pragma unroll
    for (int kt = 0; kt < 8; ++kt) {
      s8v ah = *(const s8v*)&khB[((size_t)kt*12 + cs)*512 + lane*8];
      s8v al = *(const s8v*)&klB[((size_t)kt*12 + cs)*512 + lane*8];
      acc[kt] = MFMA(ah, bqh, acc[kt]);
      acc[kt] = MFMA(ah, bql, acc[kt]);
      acc[kt] = MFMA(al, bqh, acc[kt]);
    }
  }

  // ---- mask + scale + softmax over kp (128 per wave, cross-wave via LDS) ----
  float mx = -3.4e38f;
  #pragma unroll
  for (int kt = 0; kt < 8; ++kt) {
    const float4 m4 = *(const float4*)&smask[wh*128 + kt*16 + l4*4];
    acc[kt][0] = (m4.x > 0.5f) ? acc[kt][0]*TAU_INV : NEGV;
    acc[kt][1] = (m4.y > 0.5f) ? acc[kt][1]*TAU_INV : NEGV;
    acc[kt][2] = (m4.z > 0.5f) ? acc[kt][2]*TAU_INV : NEGV;
    acc[kt][3] = (m4.w > 0.5f) ? acc[kt][3]*TAU_INV : NEGV;
    mx = fmaxf(mx, fmaxf(fmaxf(acc[kt][0], acc[kt][1]), fmaxf(acc[kt][2], acc[kt][3])));
  }
  mx = fmaxf(mx, __shfl_xor(mx, 16));
  mx = fmaxf(mx, __shfl_xor(mx, 32));
  if (lane < 16) red[wh][0][lane] = mx;
  __syncthreads();
  mx = fmaxf(fmaxf(red[0][0][l15], red[1][0][l15]),
             fmaxf(red[2][0][l15], red[3][0][l15]));
  float smv = 0.f;
  #pragma unroll
  for (int kt = 0; kt < 8; ++kt) {
    #pragma unroll
    for (int r = 0; r < 4; ++r) {
      float e = __expf(acc[kt][r] - mx);
      acc[kt][r] = e; smv += e;
    }
  }
  smv += __shfl_xor(smv, 16);
  smv += __shfl_xor(smv, 32);
  if (lane < 16) red[wh][1][lane] = smv;
  __syncthreads();
  smv = red[0][1][l15] + red[1][1][l15] + red[2][1][l15] + red[3][1][l15];
  float nm = node_mask[(size_t)bb*N_ + nb + l15];
  float scl = nm / smv;
  bool uni = !(nm > 0.5f);
  float uval = nm * (1.0f/KP);
  #pragma unroll
  for (int kt = 0; kt < 8; ++kt) {
    ushort4 wv;
    wv.x = f2b_rne(uni ? uval : acc[kt][0]*scl);
    wv.y = f2b_rne(uni ? uval : acc[kt][1]*scl);
    wv.z = f2b_rne(uni ? uval : acc[kt][2]*scl);
    wv.w = f2b_rne(uni ? uval : acc[kt][3]*scl);
    int kpl = wh*128 + kt*16 + l4*4;
    int bo = (l15*1024 + kpl*2) ^ ((l15 & 7) << 4);
    *(ushort4*)&wlds[bo >> 1] = wv;
  }
  __syncthreads();

  // ---- phase 3: s0 = w@V (hi+lo), pf = w@sp ; wave wh covers 96 c ----
  for (int ct = 0; ct < 6; ++ct) {
    int c_tile = wh*6 + ct;
    int c = c_tile*16 + l15;
    f4v aS = (f4v){0.f,0.f,0.f,0.f};
    f4v aP = (f4v){0.f,0.f,0.f,0.f};
    const u16* vhB = vthi + (((size_t)bb*24 + c_tile)*16)*512;
    const u16* vlB = vtlo + (((size_t)bb*24 + c_tile)*16)*512;
    const u16* spB = spt  + (((size_t)bb*24 + c_tile)*16)*512;
    #pragma unroll
    for (int ks = 0; ks < 16; ++ks) {
      int kp = ks*32 + l4*8;
      int bo = (l15*1024 + kp*2) ^ ((l15 & 7) << 4);
      s8v aw = *(const s8v*)&wlds[bo >> 1];
      s8v bh = *(const s8v*)&vhB[(size_t)ks*512 + lane*8];
      s8v bl = *(const s8v*)&vlB[(size_t)ks*512 + lane*8];
      s8v bs = *(const s8v*)&spB[(size_t)ks*512 + lane*8];
      aS = MFMA(aw, bh, aS);
      aS = MFMA(aw, bl, aS);
      aP = MFMA(aw, bs, aP);
    }
    #pragma unroll
    for (int r = 0; r < 4; ++r) {
      int n = nb + l4*4 + r;
      size_t row = (size_t)bb*N_ + n;
      out[row*396 + c] = aS[r];
      pf[row*C_ + c] = f2b_rne(aP[r]);
    }
  }

  // ---- tail via MFMA: D[n][col] = w @ musig (hi+lo), partial per wave ----
  {
    f4v pMS = (f4v){0.f,0.f,0.f,0.f};
    #pragma unroll
    for (int k2 = 0; k2 < 4; ++k2) {
      int ks = wh*4 + k2;
      int kp = ks*32 + l4*8;
      int bo = (l15*1024 + kp*2) ^ ((l15 & 7) << 4);
      s8v aw = *(const s8v*)&wlds[bo >> 1];
      s8v bh = *(const s8v*)&mshi[(((size_t)bb*16 + ks)*64 + lane)*8];
      s8v bl = *(const s8v*)&mslo[(((size_t)bb*16 + ks)*64 + lane)*8];
      pMS = MFMA(aw, bh, pMS);
      pMS = MFMA(aw, bl, pMS);
    }
    #pragma unroll
    for (int r = 0; r < 4; ++r) musred[wh][lane][r] = pMS[r];
  }
  __syncthreads();
  if (wh == 0) {
    int col = l15;
    #pragma unroll
    for (int r = 0; r < 4; ++r) {
      float d = musred[0][lane][r] + musred[1][lane][r]
              + musred[2][lane][r] + musred[3][lane][r];
      int n = nb + l4*4 + r;
      size_t row = (size_t)bb*N_ + n;
      if (col < 3) {
        mu0[row*3 + col] = d;
      } else if (col < 12) {
        int e = col - 3;
        if (e == 0 || e == 4 || e == 8) d += JITTER_;
        sigpc[row*9 + e] = d;
      }
    }
  }
}

// ---------------- K4: mu-offset MLP (pf bf16 in) ----------------
__global__ __launch_bounds__(384) void k_mlp(
    const u16* __restrict__ pf, const float* __restrict__ g,
    const float* __restrict__ bb, const float* __restrict__ W1T,
    const float* __restrict__ b1, const float* __restrict__ W2,
    const float* __restrict__ b2v, const float* __restrict__ node_mask,
    float* __restrict__ mu0) {
  __shared__ float xln[16*C_];
  __shared__ float h[16*C_];
  int t = threadIdx.x;
  int row0 = blockIdx.x * 16;
  if (t < 256) {
    int r = t >> 4, l = t & 15;
    const u16* xr = pf + (size_t)(row0 + r) * C_;
    float xv[24]; float s = 0.f;
    #pragma unroll
    for (int j = 0; j < 24; ++j) { xv[j] = b2f(xr[l + 16*j]); s += xv[j]; }
    #pragma unroll
    for (int m = 1; m < 16; m <<= 1) s += __shfl_xor(s, m);
    float mean = s * (1.0f/C_);
    float vs = 0.f;
    #pragma unroll
    for (int j = 0; j < 24; ++j) { float d = xv[j]-mean; vs += d*d; }
    #pragma unroll
    for (int m = 1; m < 16; m <<= 1) vs += __shfl_xor(vs, m);
    float rs = 1.0f / sqrtf(vs * (1.0f/C_) + 1e-5f);
    #pragma unroll
    for (int j = 0; j < 24; ++j) {
      int c = l + 16*j;
      xln[r*C_ + c] = (xv[j]-mean)*rs*g[c] + bb[c];
    }
  }
  __syncthreads();
  {
    int g96 = t % 96, rg = t / 96;
    int i0 = g96 * 4, r0 = rg * 4;
    float4 a0 = make_float4(0,0,0,0), a1 = a0, a2 = a0, a3 = a0;
    #pragma unroll 4
    for (int c = 0; c < C_; ++c) {
      float4 wv = *(const float4*)&W1T[(size_t)c*C_ + i0];
      float x0 = xln[(r0+0)*C_+c];
      float x1 = xln[(r0+1)*C_+c];
      float x2 = xln[(r0+2)*C_+c];
      float x3 = xln[(r0+3)*C_+c];
      a0.x += x0*wv.x; a0.y += x0*wv.y; a0.z += x0*wv.z; a0.w += x0*wv.w;
      a1.x += x1*wv.x; a1.y += x1*wv.y; a1.z += x1*wv.z; a1.w += x1*wv.w;
      a2.x += x2*wv.x; a2.y += x2*wv.y; a2.z += x2*wv.z; a2.w += x2*wv.w;
      a3.x += x3*wv.x; a3.y += x3*wv.y; a3.z += x3*wv.z; a3.w += x3*wv.w;
    }
    float4 bv4 = *(const float4*)&b1[i0];
    float4 av[4] = {a0, a1, a2, a3};
    #pragma unroll
    for (int j = 0; j < 4; ++j) {
      float4 v = av[j];
      v.x += bv4.x; v.y += bv4.y; v.z += bv4.z; v.w += bv4.w;
      v.x = v.x / (1.0f + __expf(-v.x));
      v.y = v.y / (1.0f + __expf(-v.y));
      v.z = v.z / (1.0f + __expf(-v.z));
      v.w = v.w / (1.0f + __expf(-v.w));
      *(float4*)&h[(r0+j)*C_ + i0] = v;
    }
  }
  __syncthreads();
  if (t < 256) {
    int r = t >> 4, l = t & 15;
    const float* hr = &h[r*C_];
    float pd0=0.f, pd1=0.f, pd2=0.f;
    #pragma unroll
    for (int j=0;j<24;++j) {
      int c = l + 16*j;
      float hv = hr[c];
      pd0 += hv*W2[c];
      pd1 += hv*W2[C_ + c];
      pd2 += hv*W2[2*C_ + c];
    }
    #pragma unroll
    for (int m = 1; m < 16; m <<= 1) {
      pd0 += __shfl_xor(pd0, m);
      pd1 += __shfl_xor(pd1, m);
      pd2 += __shfl_xor(pd2, m);
    }
    if (l == 0) {
      size_t row = (size_t)(row0 + r);
      float nmv = node_mask[row];
      float d0 = (pd0 + b2v[0]) * MU_SCALE_;
      float d1 = (pd1 + b2v[1]) * MU_SCALE_;
      float d2 = (pd2 + b2v[2]) * MU_SCALE_;
      mu0[row*3+0] = (mu0[row*3+0] + d0) * nmv;
      mu0[row*3+1] = (mu0[row*3+1] + d1) * nmv;
      mu0[row*3+2] = (mu0[row*3+2] + d2) * nmv;
    }
  }
}

// ---------------- K5: kNN sigma + Sig0 + mu0 out ----------------
__global__ __launch_bounds__(256) void k_knn(
    const float* __restrict__ mu0, const float* __restrict__ node_mask,
    const float* __restrict__ sigpc, float* __restrict__ out) {
  __shared__ float4 cand[N_];        // 64 KB
  __shared__ float mrg[64*32];       // 8 KB
  int t = threadIdx.x;
  int b = blockIdx.y;
  int n0 = blockIdx.x * 64;
  const float* mb = mu0 + (size_t)b*N_*3;
  const float* nmB = node_mask + (size_t)b*N_;
  for (int idx = t; idx < N_; idx += 256) {
    float x = mb[idx*3+0], y = mb[idx*3+1], z = mb[idx*3+2];
    float w = (nmB[idx] > 0.5f) ? 0.f : BIG_;
    cand[idx] = make_float4(x, y, z, w);
  }
  __syncthreads();
  int r = t >> 2, qq = t & 3;
  int n = n0 + r;
  float4 e = cand[n];
  float best[8];
  #pragma unroll
  for (int i=0;i<8;++i) best[i] = BIG_;
  int base = qq * (N_/4);
  #pragma unroll 4
  for (int i = 0; i < N_/4; ++i) {
    int m = base + ((i + qq*2) & (N_/4 - 1));
    float4 c = cand[m];
    float dx = c.x - e.x, dy = c.y - e.y, dz = c.z - e.z;
    float d2 = dx*dx + dy*dy + dz*dz + c.w;
    if (m == n) d2 = BIG_;
    if (d2 < best[7]) {
      #pragma unroll
      for (int i2 = 7; i2 >= 1; --i2)
        best[i2] = (best[i2] > d2) ? ((best[i2-1] > d2) ? best[i2-1] : d2) : best[i2];
      best[0] = (best[0] > d2) ? d2 : best[0];
    }
  }
  #pragma unroll
  for (int i=0;i<8;++i) mrg[(r*4+qq)*8 + i] = best[i];
  __syncthreads();
  if (qq == 0) {
    float arr[32];
    #pragma unroll
    for (int i=0;i<32;++i) arr[i] = mrg[r*32 + i];
    float ssum = 0.f;
    #pragma unroll
    for (int sel=0; sel<8; ++sel) {
      float mn = arr[0];
      #pragma unroll
      for (int i=1;i<32;++i) mn = fminf(mn, arr[i]);
      ssum += sqrtf(fmaxf(mn, 0.f));
      bool done = false;
      #pragma unroll
      for (int i=0;i<32;++i) {
        bool hit = (!done) && (arr[i] == mn);
        arr[i] = hit ? BIG_ : arr[i];
        done = done || hit;
      }
    }
    float sigma = fminf(fmaxf(ALPHA_ * (ssum * 0.125f), SFLOOR_), SCEIL_);
    float s2 = sigma*sigma + JITTER_;
    size_t row = (size_t)b*N_ + n;
    float nmv = nmB[n];
    size_t orow = row * 396;
    const float* sg = &sigpc[row*9];
    #pragma unroll
    for (int e2=0;e2<9;++e2) {
      bool diag = (e2==0)||(e2==4)||(e2==8);
      float v = BETA_*sg[e2] + (diag ? ((1.0f-BETA_)*s2 + JITTER_) : 0.0f);
      out[orow + 387 + e2] = v * nmv;
    }
    out[orow + 384] = e.x;
    out[orow + 385] = e.y;
    out[orow + 386] = e.z;
  }
}

extern "C" void kernel_launch(void* const* d_in, const int* in_sizes, int n_in,
                              void* d_out, int out_size, void* d_ws, size_t ws_size,
                              hipStream_t stream) {
  const float* s_parent    = (const float*)d_in[0];
  const float* mu_p        = (const float*)d_in[1];
  const float* Sig_p       = (const float*)d_in[2];
  const float* mask_parent = (const float*)d_in[3];
  const float* node_mask   = (const float*)d_in[4];
  const float* s_trunk     = (const float*)d_in[5];
  const float* Wq   = (const float*)d_in[6];
  const float* Wk   = (const float*)d_in[7];
  const float* Wv   = (const float*)d_in[8];
  const float* Wpos = (const float*)d_in[9];
  const float* lnq_g = (const float*)d_in[10];
  const float* lnq_b = (const float*)d_in[11];
  const float* lnk_g = (const float*)d_in[12];
  const float* lnk_b = (const float*)d_in[13];
  const float* lnv_g = (const float*)d_in[14];
  const float* lnv_b = (const float*)d_in[15];
  const float* mo_ln_g = (const float*)d_in[16];
  const float* mo_ln_b = (const float*)d_in[17];
  const float* mo_W1 = (const float*)d_in[18];
  const float* mo_b1 = (const float*)d_in[19];
  const float* mo_W2 = (const float*)d_in[20];
  const float* mo_b2 = (const float*)d_in[21];

  char* wsb = (char*)d_ws;
  u16* qhi  = (u16*)wsb;
  u16* qlo  = qhi + (size_t)B_*N_*C_;
  u16* khi  = (u16*)(wsb + 25165824);
  u16* klo  = khi + (size_t)B_*KP*C_;
  u16* vthi = (u16*)(wsb + 25165824 + 3145728);
  u16* vtlo = vthi + (size_t)B_*C_*KP;
  char* pfb = wsb + 25165824 + 2*3145728;
  u16* pf   = (u16*)pfb;
  u16* spt  = (u16*)(pfb + 12582912);
  float* wqT = (float*)(pfb + 12582912 + 1572864);
  float* wkT = wqT + (size_t)C_*C_;
  float* wvT = wkT + (size_t)C_*C_;
  u16* mshi = (u16*)(pfb + 12582912 + 1572864 + 3*589824);   // 65536 B
  u16* mslo = mshi + (size_t)B_*16*64*8;                     // 65536 B
  float* w1T = (float*)(wsb + 25165824);
  float* mu0 = (float*)(wsb + 25165824 + 2*3145728 + 25165824);
  float* sg  = mu0 + (size_t)B_*N_*3;
  float* out = (float*)d_out;

  dim3 tb(32, 8);
  dim3 tg(C_/32, C_/32);
  k_transpose<<<tg, tb, 0, stream>>>(Wq, wqT);
  k_transpose<<<tg, tb, 0, stream>>>(Wk, wkT);
  k_transpose<<<tg, tb, 0, stream>>>(Wv, wvT);
  k_sptr<<<dim3(KP/32, C_/32, B_), dim3(256), 0, stream>>>(s_parent, spt);
  k_musig<<<dim3(B_), dim3(256), 0, stream>>>(mu_p, Sig_p, mshi, mslo);

  k_kvproj<<<dim3(B_*KP/8), dim3(256), 0, stream>>>(
      s_parent, mu_p, lnk_g, lnk_b, lnv_g, lnv_b, wkT, wvT, Wpos,
      khi, klo, vthi, vtlo);
  k_qproj<<<dim3(B_*N_/16), dim3(384), 0, stream>>>(
      s_trunk, lnq_g, lnq_b, wqT, qhi, qlo);
  k_route<<<dim3(N_/16, B_), dim3(256), 0, stream>>>(
      qhi, qlo, khi, klo, vthi, vtlo, spt, mshi, mslo,
      mask_parent, node_mask, out, pf, mu0, sg);
  k_transpose<<<tg, tb, 0, stream>>>(mo_W1, w1T);
  k_mlp<<<dim3(B_*N_/16), dim3(384), 0, stream>>>(
      pf, mo_ln_g, mo_ln_b, w1T, mo_b1, mo_W2, mo_b2, node_mask, mu0);
  k_knn<<<dim3(N_/64, B_), dim3(256), 0, stream>>>(
      mu0, node_mask, sg, out);
}

// Round 7
// 474.217 us; speedup vs baseline: 4.3124x; 1.1259x over previous
//
#include <hip/hip_runtime.h>
#include <math.h>

#define B_ 4
#define N_ 4096
#define KP 512
#define C_ 384

typedef unsigned short u16;
typedef short s8v __attribute__((ext_vector_type(8)));
typedef float f4v __attribute__((ext_vector_type(4)));
#define MFMA(a,b,c) __builtin_amdgcn_mfma_f32_16x16x32_bf16(a,b,c,0,0,0)

constexpr float TAU_INV  = 10.0f;
constexpr float BETA_    = 0.85f;
constexpr float JITTER_  = 1e-6f;
constexpr float ALPHA_   = 1.5f;
constexpr float SFLOOR_  = 1e-3f;
constexpr float SCEIL_   = 100.0f;
constexpr float MU_SCALE_= 0.25f;
constexpr float NEGV     = -1e9f;
constexpr float BIG_     = 1e9f;

__device__ __forceinline__ u16 f2b_rne(float f) {
  unsigned int u = __float_as_uint(f);
  return (u16)((u + 0x7FFFu + ((u >> 16) & 1u)) >> 16);
}
__device__ __forceinline__ float b2f(u16 h) {
  return __uint_as_float(((unsigned int)h) << 16);
}
__device__ __forceinline__ void split_hl(float f, u16& hi, u16& lo) {
  unsigned int u = __float_as_uint(f);
  hi = (u16)(u >> 16);
  float fh = __uint_as_float(u & 0xFFFF0000u);
  lo = f2b_rne(f - fh);
}

// Packed fragment layouts (per 16x16x32 MFMA), 1KB contiguous per fragment:
//  K (A-op):   [b*32+kp_tile][cc(12)][lane][8], lane=(kp&15)+16*((c>>3)&3)
//  q (B-op):   [n>>4][cc(12)][lane][8],        lane=(n&15)+16*((c>>3)&3)
//  V^T/spT (B-op): [b*24+c_tile][ks(16)][lane][8], lane=(c&15)+16*((kp>>3)&3)
//  musig (B-op): [b][ks(16)][lane][8], cols 0-2=mu, 3-11=symSig, 12-15=0

// ---------------- K0: 384x384 fp32 transpose ----------------
__global__ __launch_bounds__(256) void k_transpose(
    const float* __restrict__ W, float* __restrict__ WT) {
  __shared__ float tile[32][33];
  int bx = blockIdx.x * 32, by = blockIdx.y * 32;
  int tx = threadIdx.x, ty = threadIdx.y;   // 32 x 8
  #pragma unroll
  for (int j = 0; j < 32; j += 8)
    tile[ty + j][tx] = W[(size_t)(by + ty + j) * C_ + bx + tx];
  __syncthreads();
  #pragma unroll
  for (int j = 0; j < 32; j += 8)
    WT[(size_t)(bx + ty + j) * C_ + by + tx] = tile[tx][ty + j];
}

// ---------------- K0b: s_parent -> spT bf16 packed fragments ----------------
__global__ __launch_bounds__(256) void k_sptr(
    const float* __restrict__ sp, u16* __restrict__ spt) {
  __shared__ float tl[32][33];
  int bx = blockIdx.x * 32;   // kp
  int by = blockIdx.y * 32;   // c
  int bz = blockIdx.z;        // b
  const float* s = sp + (size_t)bz * KP * C_;
  int tx = threadIdx.x & 31, ty4 = threadIdx.x >> 5;
  #pragma unroll
  for (int j = 0; j < 32; j += 8)
    tl[ty4 + j][tx] = s[(size_t)(bx + ty4 + j) * C_ + by + tx];  // tl[kp_l][c_l]
  __syncthreads();
  int t = threadIdx.x;
  if (t < 128) {
    int c_l = t >> 2, krun = t & 3;
    int kp0r = krun * 8;
    u16 hh[8];
    #pragma unroll
    for (int e = 0; e < 8; ++e) hh[e] = f2b_rne(tl[kp0r + e][c_l]);
    int cg = by + c_l;
    int lane = (cg & 15) + 16 * krun;
    size_t fo = (((size_t)bz*24 + (cg >> 4))*16 + (bx >> 5))*512 + (size_t)lane*8;
    *(ushort4*)&spt[fo]   = make_ushort4(hh[0],hh[1],hh[2],hh[3]);
    *(ushort4*)&spt[fo+4] = make_ushort4(hh[4],hh[5],hh[6],hh[7]);
  }
}

// ---------------- K0c: mu_p + sym(Sig_p) -> packed hi/lo B fragments ----------------
__global__ __launch_bounds__(256) void k_musig(
    const float* __restrict__ mu_p, const float* __restrict__ Sig_p,
    u16* __restrict__ mshi, u16* __restrict__ mslo) {
  int b = blockIdx.x;
  int t = threadIdx.x;
  for (int s = t; s < 1024; s += 256) {
    int ks = s >> 6, lane = s & 63;
    int col = lane & 15, kb = lane >> 4;
    u16 hh[8], ll[8];
    #pragma unroll
    for (int e = 0; e < 8; ++e) {
      int kp = ks*32 + kb*8 + e;
      float v = 0.f;
      if (col < 3) {
        v = mu_p[((size_t)b*KP + kp)*3 + col];
      } else if (col < 12) {
        int ee = col - 3, ii = ee/3, jj = ee%3;
        const float* sg = &Sig_p[((size_t)b*KP + kp)*9];
        v = 0.5f*(sg[ii*3+jj] + sg[jj*3+ii]);
      }
      split_hl(v, hh[e], ll[e]);
    }
    size_t fo = (((size_t)b*16 + ks)*64 + lane)*8;
    *(ushort4*)&mshi[fo]   = make_ushort4(hh[0],hh[1],hh[2],hh[3]);
    *(ushort4*)&mshi[fo+4] = make_ushort4(hh[4],hh[5],hh[6],hh[7]);
    *(ushort4*)&mslo[fo]   = make_ushort4(ll[0],ll[1],ll[2],ll[3]);
    *(ushort4*)&mslo[fo+4] = make_ushort4(ll[4],ll[5],ll[6],ll[7]);
  }
}

// ---------------- K1: parents -> K hi/lo packed, V^T hi/lo packed ----------------
__global__ __launch_bounds__(256) void k_kvproj(
    const float* __restrict__ sp, const float* __restrict__ mu_p,
    const float* __restrict__ gk, const float* __restrict__ bk,
    const float* __restrict__ gv, const float* __restrict__ bv,
    const float* __restrict__ wkT, const float* __restrict__ wvT,
    const float* __restrict__ Wpos,
    u16* __restrict__ khi, u16* __restrict__ klo,
    u16* __restrict__ vthi, u16* __restrict__ vtlo) {
  __shared__ float sm[2*8*C_];
  float* xk  = sm;
  float* xvn = sm + 8*C_;
  int t = threadIdx.x;
  int pr0 = blockIdx.x * 8;
  if (t < 128) {
    int r = t >> 4, l = t & 15;
    const float* xr = sp + (size_t)(pr0 + r) * C_;
    float xv[24]; float s = 0.f;
    #pragma unroll
    for (int j = 0; j < 24; ++j) { xv[j] = xr[l + 16*j]; s += xv[j]; }
    #pragma unroll
    for (int m = 1; m < 16; m <<= 1) s += __shfl_xor(s, m);
    float mean = s * (1.0f/C_);
    float vs = 0.f;
    #pragma unroll
    for (int j = 0; j < 24; ++j) { float d = xv[j]-mean; vs += d*d; }
    #pragma unroll
    for (int m = 1; m < 16; m <<= 1) vs += __shfl_xor(vs, m);
    float rs = 1.0f / sqrtf(vs * (1.0f/C_) + 1e-5f);
    #pragma unroll
    for (int j = 0; j < 24; ++j) {
      int c = l + 16*j;
      float xc = (xv[j]-mean)*rs;
      xk [r*C_ + c] = xc*gk[c] + bk[c];
      xvn[r*C_ + c] = xc*gv[c] + bv[c];
    }
  }
  __syncthreads();
  int w = t >> 6, ch = t & 63;
  int r0 = w * 2;
  float accK[2][6], accV[2][6];
  #pragma unroll
  for (int j=0;j<2;++j)
    #pragma unroll
    for (int sI=0;sI<6;++sI) { accK[j][sI]=0.f; accV[j][sI]=0.f; }
  #pragma unroll 2
  for (int c = 0; c < C_; ++c) {
    float a0 = xk [(r0+0)*C_+c], a1 = xk [(r0+1)*C_+c];
    float b0 = xvn[(r0+0)*C_+c], b1 = xvn[(r0+1)*C_+c];
    #pragma unroll
    for (int sI=0;sI<6;++sI) {
      float wk = wkT[(size_t)c*C_ + ch + 64*sI];
      float wv = wvT[(size_t)c*C_ + ch + 64*sI];
      accK[0][sI] += a0*wk; accK[1][sI] += a1*wk;
      accV[0][sI] += b0*wv; accV[1][sI] += b1*wv;
    }
  }
  #pragma unroll
  for (int j=0;j<2;++j) {
    int prow = pr0 + r0 + j;
    float m0 = mu_p[(size_t)prow*3+0];
    float m1 = mu_p[(size_t)prow*3+1];
    float m2 = mu_p[(size_t)prow*3+2];
    #pragma unroll
    for (int sI=0;sI<6;++sI) {
      int i = ch + 64*sI;
      accK[j][sI] += m0*Wpos[i*3+0] + m1*Wpos[i*3+1] + m2*Wpos[i*3+2];
    }
  }
  __syncthreads();
  float* stg = sm;
  #pragma unroll
  for (int j=0;j<2;++j)
    #pragma unroll
    for (int sI=0;sI<6;++sI)
      stg[(ch + 64*sI)*9 + (r0+j)] = accK[j][sI];
  __syncthreads();
  int kp0 = pr0 & (KP-1);
  int kp_tile_g = pr0 >> 4;
  int rhalf = kp0 & 8;
  int b = pr0 >> 9;
  for (int u = t; u < 384; u += 256) {
    int cc = u / 32, rem = u % 32, l4g = rem >> 3, row = rem & 7;
    int c0 = cc*32 + l4g*8;
    u16 hh[8], ll[8];
    #pragma unroll
    for (int e = 0; e < 8; ++e) split_hl(stg[(c0+e)*9 + row], hh[e], ll[e]);
    int lane = (rhalf + row) + 16*l4g;
    size_t fo = ((size_t)kp_tile_g*12 + cc)*512 + (size_t)lane*8;
    *(ushort4*)&khi[fo]   = make_ushort4(hh[0],hh[1],hh[2],hh[3]);
    *(ushort4*)&khi[fo+4] = make_ushort4(hh[4],hh[5],hh[6],hh[7]);
    *(ushort4*)&klo[fo]   = make_ushort4(ll[0],ll[1],ll[2],ll[3]);
    *(ushort4*)&klo[fo+4] = make_ushort4(ll[4],ll[5],ll[6],ll[7]);
  }
  __syncthreads();
  #pragma unroll
  for (int j=0;j<2;++j)
    #pragma unroll
    for (int sI=0;sI<6;++sI)
      stg[(ch + 64*sI)*9 + (r0+j)] = accV[j][sI];
  __syncthreads();
  int kpc = kp0 >> 5, l4gv = (kp0 >> 3) & 3;
  for (int u = t; u < 384; u += 256) {
    int c = u;
    u16 hh[8], ll[8];
    #pragma unroll
    for (int e = 0; e < 8; ++e) split_hl(stg[c*9 + e], hh[e], ll[e]);
    int lane = (c & 15) + 16*l4gv;
    size_t fo = (((size_t)b*24 + (c >> 4))*16 + kpc)*512 + (size_t)lane*8;
    *(ushort4*)&vthi[fo]   = make_ushort4(hh[0],hh[1],hh[2],hh[3]);
    *(ushort4*)&vthi[fo+4] = make_ushort4(hh[4],hh[5],hh[6],hh[7]);
    *(ushort4*)&vtlo[fo]   = make_ushort4(ll[0],ll[1],ll[2],ll[3]);
    *(ushort4*)&vtlo[fo+4] = make_ushort4(ll[4],ll[5],ll[6],ll[7]);
  }
}

// ---------------- K2: s_trunk -> q hi/lo packed ----------------
__global__ __launch_bounds__(384) void k_qproj(
    const float* __restrict__ st, const float* __restrict__ g,
    const float* __restrict__ bb, const float* __restrict__ WT,
    u16* __restrict__ qhi, u16* __restrict__ qlo) {
  __shared__ float xln[16*C_];
  int t = threadIdx.x;
  int row0 = blockIdx.x * 16;
  if (t < 256) {
    int r = t >> 4, l = t & 15;
    const float* xr = st + (size_t)(row0 + r) * C_;
    float xv[24]; float s = 0.f;
    #pragma unroll
    for (int j = 0; j < 24; ++j) { xv[j] = xr[l + 16*j]; s += xv[j]; }
    #pragma unroll
    for (int m = 1; m < 16; m <<= 1) s += __shfl_xor(s, m);
    float mean = s * (1.0f/C_);
    float vs = 0.f;
    #pragma unroll
    for (int j = 0; j < 24; ++j) { float d = xv[j]-mean; vs += d*d; }
    #pragma unroll
    for (int m = 1; m < 16; m <<= 1) vs += __shfl_xor(vs, m);
    float rs = 1.0f / sqrtf(vs * (1.0f/C_) + 1e-5f);
    #pragma unroll
    for (int j = 0; j < 24; ++j) {
      int c = l + 16*j;
      xln[r*C_ + c] = (xv[j]-mean)*rs*g[c] + bb[c];
    }
  }
  __syncthreads();
  int g96 = t % 96, rg = t / 96;
  int i0 = g96 * 4, r0 = rg * 4;
  float4 a0 = make_float4(0,0,0,0), a1 = a0, a2 = a0, a3 = a0;
  #pragma unroll 4
  for (int c = 0; c < C_; ++c) {
    float4 wv = *(const float4*)&WT[(size_t)c*C_ + i0];
    float x0 = xln[(r0+0)*C_+c];
    float x1 = xln[(r0+1)*C_+c];
    float x2 = xln[(r0+2)*C_+c];
    float x3 = xln[(r0+3)*C_+c];
    a0.x += x0*wv.x; a0.y += x0*wv.y; a0.z += x0*wv.z; a0.w += x0*wv.w;
    a1.x += x1*wv.x; a1.y += x1*wv.y; a1.z += x1*wv.z; a1.w += x1*wv.w;
    a2.x += x2*wv.x; a2.y += x2*wv.y; a2.z += x2*wv.z; a2.w += x2*wv.w;
    a3.x += x3*wv.x; a3.y += x3*wv.y; a3.z += x3*wv.z; a3.w += x3*wv.w;
  }
  float4 av[4] = {a0, a1, a2, a3};
  #pragma unroll
  for (int j = 0; j < 4; ++j) {
    int nrow = row0 + r0 + j;
    u16 h0,l0,h1,l1,h2,l2,h3,l3;
    split_hl(av[j].x, h0, l0); split_hl(av[j].y, h1, l1);
    split_hl(av[j].z, h2, l2); split_hl(av[j].w, h3, l3);
    size_t fo = (((size_t)(nrow >> 4))*12 + (i0 >> 5))*512
              + (size_t)(((nrow & 15) + 16*((i0 >> 3) & 3))*8 + (i0 & 7));
    *(ushort4*)&qhi[fo] = make_ushort4(h0,h1,h2,h3);
    *(ushort4*)&qlo[fo] = make_ushort4(l0,l1,l2,l3);
  }
}

// ---------------- K3: MFMA router: 16-n tile, 4 waves = 4 kp-quarters ----------------
__global__ __launch_bounds__(256, 4) void k_route(
    const u16* __restrict__ qhi, const u16* __restrict__ qlo,
    const u16* __restrict__ khi, const u16* __restrict__ klo,
    const u16* __restrict__ vthi, const u16* __restrict__ vtlo,
    const u16* __restrict__ spt,
    const u16* __restrict__ mshi, const u16* __restrict__ mslo,
    const float* __restrict__ mask_parent, const float* __restrict__ node_mask,
    float* __restrict__ out, u16* __restrict__ pf,
    float* __restrict__ mu0, float* __restrict__ sigpc) {
  __shared__ u16   wlds[16*512];       // 16 KB, XOR-swizzled rows
  __shared__ float smask[KP];          // 2 KB
  __shared__ float red[4][2][16];      // 512 B
  __shared__ float musred[4][64][4];   // 4 KB

  int t = threadIdx.x;
  int bb = blockIdx.y;
  int nb = blockIdx.x * 16;
  int wh = t >> 6, lane = t & 63;
  int l15 = lane & 15, l4 = lane >> 4;

  {
    const float4* ms = (const float4*)(mask_parent + (size_t)bb*KP);
    for (int i = t; i < 128; i += 256) ((float4*)smask)[i] = ms[i];
  }
  __syncthreads();

  // ---- phase 1: logits^T, wave wh covers kp quarter [wh*128, wh*128+128) ----
  const u16* qhB = qhi + ((size_t)(bb*256 + (nb >> 4)))*12*512;
  const u16* qlB = qlo + ((size_t)(bb*256 + (nb >> 4)))*12*512;
  const u16* khB = khi + ((size_t)(bb*32 + wh*8))*12*512;
  const u16* klB = klo + ((size_t)(bb*32 + wh*8))*12*512;
  f4v acc[8];
  #pragma unroll
  for (int kt = 0; kt < 8; ++kt) acc[kt] = (f4v){0.f,0.f,0.f,0.f};
  for (int cs = 0; cs < 12; ++cs) {
    s8v bqh = *(const s8v*)&qhB[(size_t)cs*512 + lane*8];
    s8v bql = *(const s8v*)&qlB[(size_t)cs*512 + lane*8];
    #pragma unroll
    for (int kt = 0; kt < 8; ++kt) {
      s8v ah = *(const s8v*)&khB[((size_t)kt*12 + cs)*512 + lane*8];
      s8v al = *(const s8v*)&klB[((size_t)kt*12 + cs)*512 + lane*8];
      acc[kt] = MFMA(ah, bqh, acc[kt]);
      acc[kt] = MFMA(ah, bql, acc[kt]);
      acc[kt] = MFMA(al, bqh, acc[kt]);
    }
  }

  // ---- mask + scale + softmax over kp (128 per wave, cross-wave via LDS) ----
  float mx = -3.4e38f;
  #pragma unroll
  for (int kt = 0; kt < 8; ++kt) {
    const float4 m4 = *(const float4*)&smask[wh*128 + kt*16 + l4*4];
    acc[kt][0] = (m4.x > 0.5f) ? acc[kt][0]*TAU_INV : NEGV;
    acc[kt][1] = (m4.y > 0.5f) ? acc[kt][1]*TAU_INV : NEGV;
    acc[kt][2] = (m4.z > 0.5f) ? acc[kt][2]*TAU_INV : NEGV;
    acc[kt][3] = (m4.w > 0.5f) ? acc[kt][3]*TAU_INV : NEGV;
    mx = fmaxf(mx, fmaxf(fmaxf(acc[kt][0], acc[kt][1]), fmaxf(acc[kt][2], acc[kt][3])));
  }
  mx = fmaxf(mx, __shfl_xor(mx, 16));
  mx = fmaxf(mx, __shfl_xor(mx, 32));
  if (lane < 16) red[wh][0][lane] = mx;
  __syncthreads();
  mx = fmaxf(fmaxf(red[0][0][l15], red[1][0][l15]),
             fmaxf(red[2][0][l15], red[3][0][l15]));
  float smv = 0.f;
  #pragma unroll
  for (int kt = 0; kt < 8; ++kt) {
    #pragma unroll
    for (int r = 0; r < 4; ++r) {
      float e = __expf(acc[kt][r] - mx);
      acc[kt][r] = e; smv += e;
    }
  }
  smv += __shfl_xor(smv, 16);
  smv += __shfl_xor(smv, 32);
  if (lane < 16) red[wh][1][lane] = smv;
  __syncthreads();
  smv = red[0][1][l15] + red[1][1][l15] + red[2][1][l15] + red[3][1][l15];
  float nm = node_mask[(size_t)bb*N_ + nb + l15];
  float scl = nm / smv;
  bool uni = !(nm > 0.5f);
  float uval = nm * (1.0f/KP);
  #pragma unroll
  for (int kt = 0; kt < 8; ++kt) {
    ushort4 wv;
    wv.x = f2b_rne(uni ? uval : acc[kt][0]*scl);
    wv.y = f2b_rne(uni ? uval : acc[kt][1]*scl);
    wv.z = f2b_rne(uni ? uval : acc[kt][2]*scl);
    wv.w = f2b_rne(uni ? uval : acc[kt][3]*scl);
    int kpl = wh*128 + kt*16 + l4*4;
    int bo = (l15*1024 + kpl*2) ^ ((l15 & 7) << 4);
    *(ushort4*)&wlds[bo >> 1] = wv;
  }
  __syncthreads();

  // ---- phase 3: s0 = w@V (hi+lo), pf = w@sp ; wave wh covers 96 c ----
  for (int ct = 0; ct < 6; ++ct) {
    int c_tile = wh*6 + ct;
    int c = c_tile*16 + l15;
    f4v aS = (f4v){0.f,0.f,0.f,0.f};
    f4v aP = (f4v){0.f,0.f,0.f,0.f};
    const u16* vhB = vthi + (((size_t)bb*24 + c_tile)*16)*512;
    const u16* vlB = vtlo + (((size_t)bb*24 + c_tile)*16)*512;
    const u16* spB = spt  + (((size_t)bb*24 + c_tile)*16)*512;
    #pragma unroll
    for (int ks = 0; ks < 16; ++ks) {
      int kp = ks*32 + l4*8;
      int bo = (l15*1024 + kp*2) ^ ((l15 & 7) << 4);
      s8v aw = *(const s8v*)&wlds[bo >> 1];
      s8v bh = *(const s8v*)&vhB[(size_t)ks*512 + lane*8];
      s8v bl = *(const s8v*)&vlB[(size_t)ks*512 + lane*8];
      s8v bs = *(const s8v*)&spB[(size_t)ks*512 + lane*8];
      aS = MFMA(aw, bh, aS);
      aS = MFMA(aw, bl, aS);
      aP = MFMA(aw, bs, aP);
    }
    #pragma unroll
    for (int r = 0; r < 4; ++r) {
      int n = nb + l4*4 + r;
      size_t row = (size_t)bb*N_ + n;
      out[row*396 + c] = aS[r];
      pf[row*C_ + c] = f2b_rne(aP[r]);
    }
  }

  // ---- tail via MFMA: D[n][col] = w @ musig (hi+lo), partial per wave ----
  {
    f4v pMS = (f4v){0.f,0.f,0.f,0.f};
    #pragma unroll
    for (int k2 = 0; k2 < 4; ++k2) {
      int ks = wh*4 + k2;
      int kp = ks*32 + l4*8;
      int bo = (l15*1024 + kp*2) ^ ((l15 & 7) << 4);
      s8v aw = *(const s8v*)&wlds[bo >> 1];
      s8v bh = *(const s8v*)&mshi[(((size_t)bb*16 + ks)*64 + lane)*8];
      s8v bl = *(const s8v*)&mslo[(((size_t)bb*16 + ks)*64 + lane)*8];
      pMS = MFMA(aw, bh, pMS);
      pMS = MFMA(aw, bl, pMS);
    }
    #pragma unroll
    for (int r = 0; r < 4; ++r) musred[wh][lane][r] = pMS[r];
  }
  __syncthreads();
  if (wh == 0) {
    int col = l15;
    #pragma unroll
    for (int r = 0; r < 4; ++r) {
      float d = musred[0][lane][r] + musred[1][lane][r]
              + musred[2][lane][r] + musred[3][lane][r];
      int n = nb + l4*4 + r;
      size_t row = (size_t)bb*N_ + n;
      if (col < 3) {
        mu0[row*3 + col] = d;
      } else if (col < 12) {
        int e = col - 3;
        if (e == 0 || e == 4 || e == 8) d += JITTER_;
        sigpc[row*9 + e] = d;
      }
    }
  }
}

// ---------------- K4: mu-offset MLP (pf bf16 in) ----------------
__global__ __launch_bounds__(384) void k_mlp(
    const u16* __restrict__ pf, const float* __restrict__ g,
    const float* __restrict__ bb, const float* __restrict__ W1T,
    const float* __restrict__ b1, const float* __restrict__ W2,
    const float* __restrict__ b2v, const float* __restrict__ node_mask,
    float* __restrict__ mu0) {
  __shared__ float xln[16*C_];
  __shared__ float h[16*C_];
  int t = threadIdx.x;
  int row0 = blockIdx.x * 16;
  if (t < 256) {
    int r = t >> 4, l = t & 15;
    const u16* xr = pf + (size_t)(row0 + r) * C_;
    float xv[24]; float s = 0.f;
    #pragma unroll
    for (int j = 0; j < 24; ++j) { xv[j] = b2f(xr[l + 16*j]); s += xv[j]; }
    #pragma unroll
    for (int m = 1; m < 16; m <<= 1) s += __shfl_xor(s, m);
    float mean = s * (1.0f/C_);
    float vs = 0.f;
    #pragma unroll
    for (int j = 0; j < 24; ++j) { float d = xv[j]-mean; vs += d*d; }
    #pragma unroll
    for (int m = 1; m < 16; m <<= 1) vs += __shfl_xor(vs, m);
    float rs = 1.0f / sqrtf(vs * (1.0f/C_) + 1e-5f);
    #pragma unroll
    for (int j = 0; j < 24; ++j) {
      int c = l + 16*j;
      xln[r*C_ + c] = (xv[j]-mean)*rs*g[c] + bb[c];
    }
  }
  __syncthreads();
  {
    int g96 = t % 96, rg = t / 96;
    int i0 = g96 * 4, r0 = rg * 4;
    float4 a0 = make_float4(0,0,0,0), a1 = a0, a2 = a0, a3 = a0;
    #pragma unroll 4
    for (int c = 0; c < C_; ++c) {
      float4 wv = *(const float4*)&W1T[(size_t)c*C_ + i0];
      float x0 = xln[(r0+0)*C_+c];
      float x1 = xln[(r0+1)*C_+c];
      float x2 = xln[(r0+2)*C_+c];
      float x3 = xln[(r0+3)*C_+c];
      a0.x += x0*wv.x; a0.y += x0*wv.y; a0.z += x0*wv.z; a0.w += x0*wv.w;
      a1.x += x1*wv.x; a1.y += x1*wv.y; a1.z += x1*wv.z; a1.w += x1*wv.w;
      a2.x += x2*wv.x; a2.y += x2*wv.y; a2.z += x2*wv.z; a2.w += x2*wv.w;
      a3.x += x3*wv.x; a3.y += x3*wv.y; a3.z += x3*wv.z; a3.w += x3*wv.w;
    }
    float4 bv4 = *(const float4*)&b1[i0];
    float4 av[4] = {a0, a1, a2, a3};
    #pragma unroll
    for (int j = 0; j < 4; ++j) {
      float4 v = av[j];
      v.x += bv4.x; v.y += bv4.y; v.z += bv4.z; v.w += bv4.w;
      v.x = v.x / (1.0f + __expf(-v.x));
      v.y = v.y / (1.0f + __expf(-v.y));
      v.z = v.z / (1.0f + __expf(-v.z));
      v.w = v.w / (1.0f + __expf(-v.w));
      *(float4*)&h[(r0+j)*C_ + i0] = v;
    }
  }
  __syncthreads();
  if (t < 256) {
    int r = t >> 4, l = t & 15;
    const float* hr = &h[r*C_];
    float pd0=0.f, pd1=0.f, pd2=0.f;
    #pragma unroll
    for (int j=0;j<24;++j) {
      int c = l + 16*j;
      float hv = hr[c];
      pd0 += hv*W2[c];
      pd1 += hv*W2[C_ + c];
      pd2 += hv*W2[2*C_ + c];
    }
    #pragma unroll
    for (int m = 1; m < 16; m <<= 1) {
      pd0 += __shfl_xor(pd0, m);
      pd1 += __shfl_xor(pd1, m);
      pd2 += __shfl_xor(pd2, m);
    }
    if (l == 0) {
      size_t row = (size_t)(row0 + r);
      float nmv = node_mask[row];
      float d0 = (pd0 + b2v[0]) * MU_SCALE_;
      float d1 = (pd1 + b2v[1]) * MU_SCALE_;
      float d2 = (pd2 + b2v[2]) * MU_SCALE_;
      mu0[row*3+0] = (mu0[row*3+0] + d0) * nmv;
      mu0[row*3+1] = (mu0[row*3+1] + d1) * nmv;
      mu0[row*3+2] = (mu0[row*3+2] + d2) * nmv;
    }
  }
}

// ---------------- K5: kNN sigma + Sig0 + mu0 out ----------------
// 32 rows/block, 16 scan-threads/row (512 thr). Register bitonic merge
// across the 16 lanes of a row (no LDS merge buffer).
__global__ __launch_bounds__(512, 4) void k_knn(
    const float* __restrict__ mu0, const float* __restrict__ node_mask,
    const float* __restrict__ sigpc, float* __restrict__ out) {
  __shared__ float4 cand[N_];        // 64 KB
  int t = threadIdx.x;
  int b = blockIdx.y;
  int n0 = blockIdx.x * 32;
  const float* mb = mu0 + (size_t)b*N_*3;
  const float* nmB = node_mask + (size_t)b*N_;
  for (int idx = t; idx < N_; idx += 512) {
    float x = mb[idx*3+0], y = mb[idx*3+1], z = mb[idx*3+2];
    float w = (nmB[idx] > 0.5f) ? 0.f : BIG_;
    cand[idx] = make_float4(x, y, z, w);
  }
  __syncthreads();
  int r = t >> 4, qq = t & 15;
  int n = n0 + r;
  float4 e = cand[n];
  float best[8];
  #pragma unroll
  for (int i=0;i<8;++i) best[i] = BIG_;
  int base = qq * 256;
  #pragma unroll 4
  for (int i = 0; i < 256; ++i) {
    int m = base + ((i + qq) & 255);     // rotate: 16 readers on 8 bank-groups
    float4 c = cand[m];
    float dx = c.x - e.x, dy = c.y - e.y, dz = c.z - e.z;
    float d2 = dx*dx + dy*dy + dz*dz + c.w;
    if (m == n) d2 = BIG_;
    if (d2 < best[7]) {
      #pragma unroll
      for (int i2 = 7; i2 >= 1; --i2)
        best[i2] = (best[i2] > d2) ? ((best[i2-1] > d2) ? best[i2-1] : d2) : best[i2];
      best[0] = (best[0] > d2) ? d2 : best[0];
    }
  }
  // ---- register bitonic merge across the row's 16 lanes (masks 1,2,4,8) ----
  #pragma unroll
  for (int mk = 1; mk <= 8; mk <<= 1) {
    float ob[8];
    #pragma unroll
    for (int i = 0; i < 8; ++i) ob[i] = __shfl_xor(best[7-i], mk);
    #pragma unroll
    for (int i = 0; i < 8; ++i) best[i] = fminf(best[i], ob[i]);
    // best[] is bitonic; sort ascending: compare-exchange strides 4,2,1
    #pragma unroll
    for (int i = 0; i < 4; ++i) {
      float lo = fminf(best[i], best[i+4]);
      float hi = fmaxf(best[i], best[i+4]);
      best[i] = lo; best[i+4] = hi;
    }
    #pragma unroll
    for (int gI = 0; gI < 2; ++gI) {
      int o = gI*4;
      float lo0 = fminf(best[o+0], best[o+2]);
      float hi0 = fmaxf(best[o+0], best[o+2]);
      float lo1 = fminf(best[o+1], best[o+3]);
      float hi1 = fmaxf(best[o+1], best[o+3]);
      best[o+0]=lo0; best[o+2]=hi0; best[o+1]=lo1; best[o+3]=hi1;
    }
    #pragma unroll
    for (int p = 0; p < 8; p += 2) {
      float lo = fminf(best[p], best[p+1]);
      float hi = fmaxf(best[p], best[p+1]);
      best[p] = lo; best[p+1] = hi;
    }
  }
  if (qq == 0) {
    float ssum = 0.f;
    #pragma unroll
    for (int i = 0; i < 8; ++i) ssum += sqrtf(fmaxf(best[i], 0.f));
    float sigma = fminf(fmaxf(ALPHA_ * (ssum * 0.125f), SFLOOR_), SCEIL_);
    float s2 = sigma*sigma + JITTER_;
    size_t row = (size_t)b*N_ + n;
    float nmv = nmB[n];
    size_t orow = row * 396;
    const float* sg = &sigpc[row*9];
    #pragma unroll
    for (int e2=0;e2<9;++e2) {
      bool diag = (e2==0)||(e2==4)||(e2==8);
      float v = BETA_*sg[e2] + (diag ? ((1.0f-BETA_)*s2 + JITTER_) : 0.0f);
      out[orow + 387 + e2] = v * nmv;
    }
    out[orow + 384] = e.x;
    out[orow + 385] = e.y;
    out[orow + 386] = e.z;
  }
}

extern "C" void kernel_launch(void* const* d_in, const int* in_sizes, int n_in,
                              void* d_out, int out_size, void* d_ws, size_t ws_size,
                              hipStream_t stream) {
  const float* s_parent    = (const float*)d_in[0];
  const float* mu_p        = (const float*)d_in[1];
  const float* Sig_p       = (const float*)d_in[2];
  const float* mask_parent = (const float*)d_in[3];
  const float* node_mask   = (const float*)d_in[4];
  const float* s_trunk     = (const float*)d_in[5];
  const float* Wq   = (const float*)d_in[6];
  const float* Wk   = (const float*)d_in[7];
  const float* Wv   = (const float*)d_in[8];
  const float* Wpos = (const float*)d_in[9];
  const float* lnq_g = (const float*)d_in[10];
  const float* lnq_b = (const float*)d_in[11];
  const float* lnk_g = (const float*)d_in[12];
  const float* lnk_b = (const float*)d_in[13];
  const float* lnv_g = (const float*)d_in[14];
  const float* lnv_b = (const float*)d_in[15];
  const float* mo_ln_g = (const float*)d_in[16];
  const float* mo_ln_b = (const float*)d_in[17];
  const float* mo_W1 = (const float*)d_in[18];
  const float* mo_b1 = (const float*)d_in[19];
  const float* mo_W2 = (const float*)d_in[20];
  const float* mo_b2 = (const float*)d_in[21];

  char* wsb = (char*)d_ws;
  u16* qhi  = (u16*)wsb;
  u16* qlo  = qhi + (size_t)B_*N_*C_;
  u16* khi  = (u16*)(wsb + 25165824);
  u16* klo  = khi + (size_t)B_*KP*C_;
  u16* vthi = (u16*)(wsb + 25165824 + 3145728);
  u16* vtlo = vthi + (size_t)B_*C_*KP;
  char* pfb = wsb + 25165824 + 2*3145728;
  u16* pf   = (u16*)pfb;
  u16* spt  = (u16*)(pfb + 12582912);
  float* wqT = (float*)(pfb + 12582912 + 1572864);
  float* wkT = wqT + (size_t)C_*C_;
  float* wvT = wkT + (size_t)C_*C_;
  u16* mshi = (u16*)(pfb + 12582912 + 1572864 + 3*589824);   // 65536 B
  u16* mslo = mshi + (size_t)B_*16*64*8;                     // 65536 B
  float* w1T = (float*)(wsb + 25165824);
  float* mu0 = (float*)(wsb + 25165824 + 2*3145728 + 25165824);
  float* sg  = mu0 + (size_t)B_*N_*3;
  float* out = (float*)d_out;

  dim3 tb(32, 8);
  dim3 tg(C_/32, C_/32);
  k_transpose<<<tg, tb, 0, stream>>>(Wq, wqT);
  k_transpose<<<tg, tb, 0, stream>>>(Wk, wkT);
  k_transpose<<<tg, tb, 0, stream>>>(Wv, wvT);
  k_sptr<<<dim3(KP/32, C_/32, B_), dim3(256), 0, stream>>>(s_parent, spt);
  k_musig<<<dim3(B_), dim3(256), 0, stream>>>(mu_p, Sig_p, mshi, mslo);

  k_kvproj<<<dim3(B_*KP/8), dim3(256), 0, stream>>>(
      s_parent, mu_p, lnk_g, lnk_b, lnv_g, lnv_b, wkT, wvT, Wpos,
      khi, klo, vthi, vtlo);
  k_qproj<<<dim3(B_*N_/16), dim3(384), 0, stream>>>(
      s_trunk, lnq_g, lnq_b, wqT, qhi, qlo);
  k_route<<<dim3(N_/16, B_), dim3(256), 0, stream>>>(
      qhi, qlo, khi, klo, vthi, vtlo, spt, mshi, mslo,
      mask_parent, node_mask, out, pf, mu0, sg);
  k_transpose<<<tg, tb, 0, stream>>>(mo_W1, w1T);
  k_mlp<<<dim3(B_*N_/16), dim3(384), 0, stream>>>(
      pf, mo_ln_g, mo_ln_b, w1T, mo_b1, mo_W2, mo_b2, node_mask, mu0);
  k_knn<<<dim3(N_/32, B_), dim3(512), 0, stream>>>(
      mu0, node_mask, sg, out);
}

// Round 8
// 418.603 us; speedup vs baseline: 4.8853x; 1.1329x over previous
//
#include <hip/hip_runtime.h>
#include <math.h>

#define B_ 4
#define N_ 4096
#define KP 512
#define C_ 384

typedef unsigned short u16;
typedef short s8v __attribute__((ext_vector_type(8)));
typedef float f4v __attribute__((ext_vector_type(4)));
#define MFMA(a,b,c) __builtin_amdgcn_mfma_f32_16x16x32_bf16(a,b,c,0,0,0)

constexpr float TAU_INV  = 10.0f;
constexpr float BETA_    = 0.85f;
constexpr float JITTER_  = 1e-6f;
constexpr float ALPHA_   = 1.5f;
constexpr float SFLOOR_  = 1e-3f;
constexpr float SCEIL_   = 100.0f;
constexpr float MU_SCALE_= 0.25f;
constexpr float NEGV     = -1e9f;
constexpr float BIG_     = 1e9f;

__device__ __forceinline__ u16 f2b_rne(float f) {
  unsigned int u = __float_as_uint(f);
  return (u16)((u + 0x7FFFu + ((u >> 16) & 1u)) >> 16);
}
__device__ __forceinline__ float b2f(u16 h) {
  return __uint_as_float(((unsigned int)h) << 16);
}
__device__ __forceinline__ void split_hl(float f, u16& hi, u16& lo) {
  unsigned int u = __float_as_uint(f);
  hi = (u16)(u >> 16);
  float fh = __uint_as_float(u & 0xFFFF0000u);
  lo = f2b_rne(f - fh);
}

// Packed fragment layouts (per 16x16x32 MFMA), 1KB contiguous per fragment:
//  K (A-op):   [b*32+kp_tile][cc(12)][lane][8], lane=(kp&15)+16*((c>>3)&3)
//  q (B-op):   [n>>4][cc(12)][lane][8],        lane=(n&15)+16*((c>>3)&3)
//  V^T/spT (B-op): [b*24+c_tile][ks(16)][lane][8], lane=(c&15)+16*((kp>>3)&3)
//  W (B-op):   [ot(24)][cs(12)][lane][8],      lane=(outc&15)+16*((inc>>3)&3)
//  musig (B-op): [b][ks(16)][lane][8], cols 0-2=mu, 3-11=symSig, 12-15=0

// ---------------- K0: 384x384 fp32 transpose ----------------
__global__ __launch_bounds__(256) void k_transpose(
    const float* __restrict__ W, float* __restrict__ WT) {
  __shared__ float tile[32][33];
  int bx = blockIdx.x * 32, by = blockIdx.y * 32;
  int tx = threadIdx.x, ty = threadIdx.y;   // 32 x 8
  #pragma unroll
  for (int j = 0; j < 32; j += 8)
    tile[ty + j][tx] = W[(size_t)(by + ty + j) * C_ + bx + tx];
  __syncthreads();
  #pragma unroll
  for (int j = 0; j < 32; j += 8)
    WT[(size_t)(bx + ty + j) * C_ + by + tx] = tile[tx][ty + j];
}

// ---------------- K0a: W row-major -> packed B-op hi/lo fragments ----------------
__global__ __launch_bounds__(256) void k_wpack(
    const float* __restrict__ W, u16* __restrict__ whi, u16* __restrict__ wlo) {
  int ot = blockIdx.x;
  for (int s = threadIdx.x; s < 768; s += 256) {
    int cs = s >> 6, lane = s & 63;
    int outc = ot*16 + (lane & 15);
    int inc0 = cs*32 + (lane >> 4)*8;
    u16 hh[8], ll[8];
    #pragma unroll
    for (int e = 0; e < 8; ++e)
      split_hl(W[(size_t)outc*C_ + inc0 + e], hh[e], ll[e]);
    size_t fo = ((size_t)ot*12 + cs)*512 + (size_t)lane*8;
    *(ushort4*)&whi[fo]   = make_ushort4(hh[0],hh[1],hh[2],hh[3]);
    *(ushort4*)&whi[fo+4] = make_ushort4(hh[4],hh[5],hh[6],hh[7]);
    *(ushort4*)&wlo[fo]   = make_ushort4(ll[0],ll[1],ll[2],ll[3]);
    *(ushort4*)&wlo[fo+4] = make_ushort4(ll[4],ll[5],ll[6],ll[7]);
  }
}

// ---------------- K0b: s_parent -> spT bf16 packed fragments ----------------
__global__ __launch_bounds__(256) void k_sptr(
    const float* __restrict__ sp, u16* __restrict__ spt) {
  __shared__ float tl[32][33];
  int bx = blockIdx.x * 32;   // kp
  int by = blockIdx.y * 32;   // c
  int bz = blockIdx.z;        // b
  const float* s = sp + (size_t)bz * KP * C_;
  int tx = threadIdx.x & 31, ty4 = threadIdx.x >> 5;
  #pragma unroll
  for (int j = 0; j < 32; j += 8)
    tl[ty4 + j][tx] = s[(size_t)(bx + ty4 + j) * C_ + by + tx];  // tl[kp_l][c_l]
  __syncthreads();
  int t = threadIdx.x;
  if (t < 128) {
    int c_l = t >> 2, krun = t & 3;
    int kp0r = krun * 8;
    u16 hh[8];
    #pragma unroll
    for (int e = 0; e < 8; ++e) hh[e] = f2b_rne(tl[kp0r + e][c_l]);
    int cg = by + c_l;
    int lane = (cg & 15) + 16 * krun;
    size_t fo = (((size_t)bz*24 + (cg >> 4))*16 + (bx >> 5))*512 + (size_t)lane*8;
    *(ushort4*)&spt[fo]   = make_ushort4(hh[0],hh[1],hh[2],hh[3]);
    *(ushort4*)&spt[fo+4] = make_ushort4(hh[4],hh[5],hh[6],hh[7]);
  }
}

// ---------------- K0c: mu_p + sym(Sig_p) -> packed hi/lo B fragments ----------------
__global__ __launch_bounds__(256) void k_musig(
    const float* __restrict__ mu_p, const float* __restrict__ Sig_p,
    u16* __restrict__ mshi, u16* __restrict__ mslo) {
  int b = blockIdx.x;
  int t = threadIdx.x;
  for (int s = t; s < 1024; s += 256) {
    int ks = s >> 6, lane = s & 63;
    int col = lane & 15, kb = lane >> 4;
    u16 hh[8], ll[8];
    #pragma unroll
    for (int e = 0; e < 8; ++e) {
      int kp = ks*32 + kb*8 + e;
      float v = 0.f;
      if (col < 3) {
        v = mu_p[((size_t)b*KP + kp)*3 + col];
      } else if (col < 12) {
        int ee = col - 3, ii = ee/3, jj = ee%3;
        const float* sg = &Sig_p[((size_t)b*KP + kp)*9];
        v = 0.5f*(sg[ii*3+jj] + sg[jj*3+ii]);
      }
      split_hl(v, hh[e], ll[e]);
    }
    size_t fo = (((size_t)b*16 + ks)*64 + lane)*8;
    *(ushort4*)&mshi[fo]   = make_ushort4(hh[0],hh[1],hh[2],hh[3]);
    *(ushort4*)&mshi[fo+4] = make_ushort4(hh[4],hh[5],hh[6],hh[7]);
    *(ushort4*)&mslo[fo]   = make_ushort4(ll[0],ll[1],ll[2],ll[3]);
    *(ushort4*)&mslo[fo+4] = make_ushort4(ll[4],ll[5],ll[6],ll[7]);
  }
}

// ---------------- K1: parents -> K hi/lo packed, V^T hi/lo packed (MFMA) ----------------
// 16 rows/block (one kp_tile), grid = B*KP/16 = 128. LDS 48KB x-fragments.
__global__ __launch_bounds__(256) void k_kvproj(
    const float* __restrict__ sp, const float* __restrict__ mu_p,
    const float* __restrict__ gk, const float* __restrict__ bk,
    const float* __restrict__ gv, const float* __restrict__ bv,
    const u16* __restrict__ wkhi, const u16* __restrict__ wklo,
    const u16* __restrict__ wvhi, const u16* __restrict__ wvlo,
    const float* __restrict__ Wpos,
    u16* __restrict__ khi, u16* __restrict__ klo,
    u16* __restrict__ vthi, u16* __restrict__ vtlo) {
  __shared__ u16 fr[4*6144];   // xk_hi | xk_lo | xv_hi | xv_lo (12288B each)
  float* stage = (float*)fr;   // overlays xk_hi+xk_lo (16*384 f32 = 24576B)
  int t = threadIdx.x;
  int pr0 = blockIdx.x * 16;
  // ---- LN, write X fragments (both K-norm and V-norm, hi/lo) ----
  {
    int r = t >> 4, l = t & 15;
    const float* xr = sp + (size_t)(pr0 + r) * C_;
    float xv[24]; float s = 0.f;
    #pragma unroll
    for (int j = 0; j < 24; ++j) { xv[j] = xr[l + 16*j]; s += xv[j]; }
    #pragma unroll
    for (int m = 1; m < 16; m <<= 1) s += __shfl_xor(s, m);
    float mean = s * (1.0f/C_);
    float vs = 0.f;
    #pragma unroll
    for (int j = 0; j < 24; ++j) { float d = xv[j]-mean; vs += d*d; }
    #pragma unroll
    for (int m = 1; m < 16; m <<= 1) vs += __shfl_xor(vs, m);
    float rs = 1.0f / sqrtf(vs * (1.0f/C_) + 1e-5f);
    #pragma unroll
    for (int j = 0; j < 24; ++j) {
      int c = l + 16*j;
      float xc = (xv[j]-mean)*rs;
      int idx = (c >> 5)*512 + ((r & 15) + 16*((c >> 3) & 3))*8 + (c & 7);
      u16 h, lo_;
      split_hl(xc*gk[c] + bk[c], h, lo_);
      fr[idx] = h; fr[6144 + idx] = lo_;
      split_hl(xc*gv[c] + bv[c], h, lo_);
      fr[12288 + idx] = h; fr[18432 + idx] = lo_;
    }
  }
  __syncthreads();
  int wv_ = t >> 6, lane = t & 63;
  int l15 = lane & 15, l4 = lane >> 4;
  // preload mu for this lane's 4 rows
  float mur[4][3];
  #pragma unroll
  for (int rr = 0; rr < 4; ++rr) {
    int prow = pr0 + l4*4 + rr;
    mur[rr][0] = mu_p[(size_t)prow*3+0];
    mur[rr][1] = mu_p[(size_t)prow*3+1];
    mur[rr][2] = mu_p[(size_t)prow*3+2];
  }
  // ---- K = X @ Wk (3-MFMA split), 6 outc tiles per wave ----
  f4v acc[6];
  #pragma unroll
  for (int i = 0; i < 6; ++i) acc[i] = (f4v){0.f,0.f,0.f,0.f};
  for (int cs = 0; cs < 12; ++cs) {
    s8v ah = *(const s8v*)&fr[cs*512 + lane*8];
    s8v al = *(const s8v*)&fr[6144 + cs*512 + lane*8];
    #pragma unroll
    for (int o6 = 0; o6 < 6; ++o6) {
      int ot = wv_*6 + o6;
      s8v bh = *(const s8v*)&wkhi[((size_t)ot*12 + cs)*512 + lane*8];
      s8v bl = *(const s8v*)&wklo[((size_t)ot*12 + cs)*512 + lane*8];
      acc[o6] = MFMA(ah, bh, acc[o6]);
      acc[o6] = MFMA(al, bh, acc[o6]);
      acc[o6] = MFMA(ah, bl, acc[o6]);
    }
  }
  // mu-pos add
  #pragma unroll
  for (int o6 = 0; o6 < 6; ++o6) {
    int outc = (wv_*6 + o6)*16 + l15;
    float w0 = Wpos[outc*3+0], w1 = Wpos[outc*3+1], w2 = Wpos[outc*3+2];
    #pragma unroll
    for (int rr = 0; rr < 4; ++rr)
      acc[o6][rr] += mur[rr][0]*w0 + mur[rr][1]*w1 + mur[rr][2]*w2;
  }
  __syncthreads();          // all K-MFMA reads of xk frags done
  #pragma unroll
  for (int o6 = 0; o6 < 6; ++o6) {
    int c = (wv_*6 + o6)*16 + l15;
    #pragma unroll
    for (int rr = 0; rr < 4; ++rr)
      stage[(l4*4 + rr)*C_ + c] = acc[o6][rr];
  }
  __syncthreads();
  // pack khi/klo (A-op over c)
  for (int s2 = t; s2 < 768; s2 += 256) {
    int cc = s2 >> 6, lp = s2 & 63;
    int kp_l = lp & 15, l4g = lp >> 4;
    int c0 = cc*32 + l4g*8;
    u16 hh[8], ll[8];
    #pragma unroll
    for (int e = 0; e < 8; ++e) split_hl(stage[kp_l*C_ + c0 + e], hh[e], ll[e]);
    size_t fo = ((size_t)blockIdx.x*12 + cc)*512 + (size_t)lp*8;
    *(ushort4*)&khi[fo]   = make_ushort4(hh[0],hh[1],hh[2],hh[3]);
    *(ushort4*)&khi[fo+4] = make_ushort4(hh[4],hh[5],hh[6],hh[7]);
    *(ushort4*)&klo[fo]   = make_ushort4(ll[0],ll[1],ll[2],ll[3]);
    *(ushort4*)&klo[fo+4] = make_ushort4(ll[4],ll[5],ll[6],ll[7]);
  }
  // ---- V = X @ Wv (3-MFMA split) ----
  f4v vac[6];
  #pragma unroll
  for (int i = 0; i < 6; ++i) vac[i] = (f4v){0.f,0.f,0.f,0.f};
  for (int cs = 0; cs < 12; ++cs) {
    s8v ah = *(const s8v*)&fr[12288 + cs*512 + lane*8];
    s8v al = *(const s8v*)&fr[18432 + cs*512 + lane*8];
    #pragma unroll
    for (int o6 = 0; o6 < 6; ++o6) {
      int ot = wv_*6 + o6;
      s8v bh = *(const s8v*)&wvhi[((size_t)ot*12 + cs)*512 + lane*8];
      s8v bl = *(const s8v*)&wvlo[((size_t)ot*12 + cs)*512 + lane*8];
      vac[o6] = MFMA(ah, bh, vac[o6]);
      vac[o6] = MFMA(al, bh, vac[o6]);
      vac[o6] = MFMA(ah, bl, vac[o6]);
    }
  }
  __syncthreads();          // khi pack reads of stage done
  #pragma unroll
  for (int o6 = 0; o6 < 6; ++o6) {
    int c = (wv_*6 + o6)*16 + l15;
    #pragma unroll
    for (int rr = 0; rr < 4; ++rr)
      stage[(l4*4 + rr)*C_ + c] = vac[o6][rr];
  }
  __syncthreads();
  // pack vthi/vtlo (B-op over kp)
  {
    int b = blockIdx.x >> 5;
    int ks = (blockIdx.x & 31) >> 1;
    int lg0 = (blockIdx.x & 1) * 2;
    for (int s2 = t; s2 < 768; s2 += 256) {
      int c = s2 >> 1, half = s2 & 1;
      int lp = (c & 15) + 16*(lg0 + half);
      u16 hh[8], ll[8];
      #pragma unroll
      for (int e = 0; e < 8; ++e)
        split_hl(stage[(half*8 + e)*C_ + c], hh[e], ll[e]);
      size_t fo = (((size_t)b*24 + (c >> 4))*16 + ks)*512 + (size_t)lp*8;
      *(ushort4*)&vthi[fo]   = make_ushort4(hh[0],hh[1],hh[2],hh[3]);
      *(ushort4*)&vthi[fo+4] = make_ushort4(hh[4],hh[5],hh[6],hh[7]);
      *(ushort4*)&vtlo[fo]   = make_ushort4(ll[0],ll[1],ll[2],ll[3]);
      *(ushort4*)&vtlo[fo+4] = make_ushort4(ll[4],ll[5],ll[6],ll[7]);
    }
  }
}

// ---------------- K2: s_trunk -> q hi/lo packed ----------------
__global__ __launch_bounds__(384) void k_qproj(
    const float* __restrict__ st, const float* __restrict__ g,
    const float* __restrict__ bb, const float* __restrict__ WT,
    u16* __restrict__ qhi, u16* __restrict__ qlo) {
  __shared__ float xln[16*C_];
  int t = threadIdx.x;
  int row0 = blockIdx.x * 16;
  if (t < 256) {
    int r = t >> 4, l = t & 15;
    const float* xr = st + (size_t)(row0 + r) * C_;
    float xv[24]; float s = 0.f;
    #pragma unroll
    for (int j = 0; j < 24; ++j) { xv[j] = xr[l + 16*j]; s += xv[j]; }
    #pragma unroll
    for (int m = 1; m < 16; m <<= 1) s += __shfl_xor(s, m);
    float mean = s * (1.0f/C_);
    float vs = 0.f;
    #pragma unroll
    for (int j = 0; j < 24; ++j) { float d = xv[j]-mean; vs += d*d; }
    #pragma unroll
    for (int m = 1; m < 16; m <<= 1) vs += __shfl_xor(vs, m);
    float rs = 1.0f / sqrtf(vs * (1.0f/C_) + 1e-5f);
    #pragma unroll
    for (int j = 0; j < 24; ++j) {
      int c = l + 16*j;
      xln[r*C_ + c] = (xv[j]-mean)*rs*g[c] + bb[c];
    }
  }
  __syncthreads();
  int g96 = t % 96, rg = t / 96;
  int i0 = g96 * 4, r0 = rg * 4;
  float4 a0 = make_float4(0,0,0,0), a1 = a0, a2 = a0, a3 = a0;
  #pragma unroll 4
  for (int c = 0; c < C_; ++c) {
    float4 wv = *(const float4*)&WT[(size_t)c*C_ + i0];
    float x0 = xln[(r0+0)*C_+c];
    float x1 = xln[(r0+1)*C_+c];
    float x2 = xln[(r0+2)*C_+c];
    float x3 = xln[(r0+3)*C_+c];
    a0.x += x0*wv.x; a0.y += x0*wv.y; a0.z += x0*wv.z; a0.w += x0*wv.w;
    a1.x += x1*wv.x; a1.y += x1*wv.y; a1.z += x1*wv.z; a1.w += x1*wv.w;
    a2.x += x2*wv.x; a2.y += x2*wv.y; a2.z += x2*wv.z; a2.w += x2*wv.w;
    a3.x += x3*wv.x; a3.y += x3*wv.y; a3.z += x3*wv.z; a3.w += x3*wv.w;
  }
  float4 av[4] = {a0, a1, a2, a3};
  #pragma unroll
  for (int j = 0; j < 4; ++j) {
    int nrow = row0 + r0 + j;
    u16 h0,l0,h1,l1,h2,l2,h3,l3;
    split_hl(av[j].x, h0, l0); split_hl(av[j].y, h1, l1);
    split_hl(av[j].z, h2, l2); split_hl(av[j].w, h3, l3);
    size_t fo = (((size_t)(nrow >> 4))*12 + (i0 >> 5))*512
              + (size_t)(((nrow & 15) + 16*((i0 >> 3) & 3))*8 + (i0 & 7));
    *(ushort4*)&qhi[fo] = make_ushort4(h0,h1,h2,h3);
    *(ushort4*)&qlo[fo] = make_ushort4(l0,l1,l2,l3);
  }
}

// ---------------- K3: MFMA router: 16-n tile, 4 waves = 4 kp-quarters ----------------
__global__ __launch_bounds__(256, 4) void k_route(
    const u16* __restrict__ qhi, const u16* __restrict__ qlo,
    const u16* __restrict__ khi, const u16* __restrict__ klo,
    const u16* __restrict__ vthi, const u16* __restrict__ vtlo,
    const u16* __restrict__ spt,
    const u16* __restrict__ mshi, const u16* __restrict__ mslo,
    const float* __restrict__ mask_parent, const float* __restrict__ node_mask,
    float* __restrict__ out, u16* __restrict__ pf,
    float* __restrict__ mu0, float* __restrict__ sigpc) {
  __shared__ u16   wlds[16*512];       // 16 KB, XOR-swizzled rows
  __shared__ float smask[KP];          // 2 KB
  __shared__ float red[4][2][16];      // 512 B
  __shared__ float musred[4][64][4];   // 4 KB

  int t = threadIdx.x;
  int bb = blockIdx.y;
  int nb = blockIdx.x * 16;
  int wh = t >> 6, lane = t & 63;
  int l15 = lane & 15, l4 = lane >> 4;

  {
    const float4* ms = (const float4*)(mask_parent + (size_t)bb*KP);
    for (int i = t; i < 128; i += 256) ((float4*)smask)[i] = ms[i];
  }
  __syncthreads();

  const u16* qhB = qhi + ((size_t)(bb*256 + (nb >> 4)))*12*512;
  const u16* qlB = qlo + ((size_t)(bb*256 + (nb >> 4)))*12*512;
  const u16* khB = khi + ((size_t)(bb*32 + wh*8))*12*512;
  const u16* klB = klo + ((size_t)(bb*32 + wh*8))*12*512;
  f4v acc[8];
  #pragma unroll
  for (int kt = 0; kt < 8; ++kt) acc[kt] = (f4v){0.f,0.f,0.f,0.f};
  for (int cs = 0; cs < 12; ++cs) {
    s8v bqh = *(const s8v*)&qhB[(size_t)cs*512 + lane*8];
    s8v bql = *(const s8v*)&qlB[(size_t)cs*512 + lane*8];
    #pragma unroll
    for (int kt = 0; kt < 8; ++kt) {
      s8v ah = *(const s8v*)&khB[((size_t)kt*12 + cs)*512 + lane*8];
      s8v al = *(const s8v*)&klB[((size_t)kt*12 + cs)*512 + lane*8];
      acc[kt] = MFMA(ah, bqh, acc[kt]);
      acc[kt] = MFMA(ah, bql, acc[kt]);
      acc[kt] = MFMA(al, bqh, acc[kt]);
    }
  }

  float mx = -3.4e38f;
  #pragma unroll
  for (int kt = 0; kt < 8; ++kt) {
    const float4 m4 = *(const float4*)&smask[wh*128 + kt*16 + l4*4];
    acc[kt][0] = (m4.x > 0.5f) ? acc[kt][0]*TAU_INV : NEGV;
    acc[kt][1] = (m4.y > 0.5f) ? acc[kt][1]*TAU_INV : NEGV;
    acc[kt][2] = (m4.z > 0.5f) ? acc[kt][2]*TAU_INV : NEGV;
    acc[kt][3] = (m4.w > 0.5f) ? acc[kt][3]*TAU_INV : NEGV;
    mx = fmaxf(mx, fmaxf(fmaxf(acc[kt][0], acc[kt][1]), fmaxf(acc[kt][2], acc[kt][3])));
  }
  mx = fmaxf(mx, __shfl_xor(mx, 16));
  mx = fmaxf(mx, __shfl_xor(mx, 32));
  if (lane < 16) red[wh][0][lane] = mx;
  __syncthreads();
  mx = fmaxf(fmaxf(red[0][0][l15], red[1][0][l15]),
             fmaxf(red[2][0][l15], red[3][0][l15]));
  float smv = 0.f;
  #pragma unroll
  for (int kt = 0; kt < 8; ++kt) {
    #pragma unroll
    for (int r = 0; r < 4; ++r) {
      float e = __expf(acc[kt][r] - mx);
      acc[kt][r] = e; smv += e;
    }
  }
  smv += __shfl_xor(smv, 16);
  smv += __shfl_xor(smv, 32);
  if (lane < 16) red[wh][1][lane] = smv;
  __syncthreads();
  smv = red[0][1][l15] + red[1][1][l15] + red[2][1][l15] + red[3][1][l15];
  float nm = node_mask[(size_t)bb*N_ + nb + l15];
  float scl = nm / smv;
  bool uni = !(nm > 0.5f);
  float uval = nm * (1.0f/KP);
  #pragma unroll
  for (int kt = 0; kt < 8; ++kt) {
    ushort4 wv;
    wv.x = f2b_rne(uni ? uval : acc[kt][0]*scl);
    wv.y = f2b_rne(uni ? uval : acc[kt][1]*scl);
    wv.z = f2b_rne(uni ? uval : acc[kt][2]*scl);
    wv.w = f2b_rne(uni ? uval : acc[kt][3]*scl);
    int kpl = wh*128 + kt*16 + l4*4;
    int bo = (l15*1024 + kpl*2) ^ ((l15 & 7) << 4);
    *(ushort4*)&wlds[bo >> 1] = wv;
  }
  __syncthreads();

  for (int ct = 0; ct < 6; ++ct) {
    int c_tile = wh*6 + ct;
    int c = c_tile*16 + l15;
    f4v aS = (f4v){0.f,0.f,0.f,0.f};
    f4v aP = (f4v){0.f,0.f,0.f,0.f};
    const u16* vhB = vthi + (((size_t)bb*24 + c_tile)*16)*512;
    const u16* vlB = vtlo + (((size_t)bb*24 + c_tile)*16)*512;
    const u16* spB = spt  + (((size_t)bb*24 + c_tile)*16)*512;
    #pragma unroll
    for (int ks = 0; ks < 16; ++ks) {
      int kp = ks*32 + l4*8;
      int bo = (l15*1024 + kp*2) ^ ((l15 & 7) << 4);
      s8v aw = *(const s8v*)&wlds[bo >> 1];
      s8v bh = *(const s8v*)&vhB[(size_t)ks*512 + lane*8];
      s8v bl = *(const s8v*)&vlB[(size_t)ks*512 + lane*8];
      s8v bs = *(const s8v*)&spB[(size_t)ks*512 + lane*8];
      aS = MFMA(aw, bh, aS);
      aS = MFMA(aw, bl, aS);
      aP = MFMA(aw, bs, aP);
    }
    #pragma unroll
    for (int r = 0; r < 4; ++r) {
      int n = nb + l4*4 + r;
      size_t row = (size_t)bb*N_ + n;
      out[row*396 + c] = aS[r];
      pf[row*C_ + c] = f2b_rne(aP[r]);
    }
  }

  {
    f4v pMS = (f4v){0.f,0.f,0.f,0.f};
    #pragma unroll
    for (int k2 = 0; k2 < 4; ++k2) {
      int ks = wh*4 + k2;
      int kp = ks*32 + l4*8;
      int bo = (l15*1024 + kp*2) ^ ((l15 & 7) << 4);
      s8v aw = *(const s8v*)&wlds[bo >> 1];
      s8v bh = *(const s8v*)&mshi[(((size_t)bb*16 + ks)*64 + lane)*8];
      s8v bl = *(const s8v*)&mslo[(((size_t)bb*16 + ks)*64 + lane)*8];
      pMS = MFMA(aw, bh, pMS);
      pMS = MFMA(aw, bl, pMS);
    }
    #pragma unroll
    for (int r = 0; r < 4; ++r) musred[wh][lane][r] = pMS[r];
  }
  __syncthreads();
  if (wh == 0) {
    int col = l15;
    #pragma unroll
    for (int r = 0; r < 4; ++r) {
      float d = musred[0][lane][r] + musred[1][lane][r]
              + musred[2][lane][r] + musred[3][lane][r];
      int n = nb + l4*4 + r;
      size_t row = (size_t)bb*N_ + n;
      if (col < 3) {
        mu0[row*3 + col] = d;
      } else if (col < 12) {
        int e = col - 3;
        if (e == 0 || e == 4 || e == 8) d += JITTER_;
        sigpc[row*9 + e] = d;
      }
    }
  }
}

// ---------------- K4: mu-offset MLP (pf bf16 in) ----------------
__global__ __launch_bounds__(384) void k_mlp(
    const u16* __restrict__ pf, const float* __restrict__ g,
    const float* __restrict__ bb, const float* __restrict__ W1T,
    const float* __restrict__ b1, const float* __restrict__ W2,
    const float* __restrict__ b2v, const float* __restrict__ node_mask,
    float* __restrict__ mu0) {
  __shared__ float xln[16*C_];
  __shared__ float h[16*C_];
  int t = threadIdx.x;
  int row0 = blockIdx.x * 16;
  if (t < 256) {
    int r = t >> 4, l = t & 15;
    const u16* xr = pf + (size_t)(row0 + r) * C_;
    float xv[24]; float s = 0.f;
    #pragma unroll
    for (int j = 0; j < 24; ++j) { xv[j] = b2f(xr[l + 16*j]); s += xv[j]; }
    #pragma unroll
    for (int m = 1; m < 16; m <<= 1) s += __shfl_xor(s, m);
    float mean = s * (1.0f/C_);
    float vs = 0.f;
    #pragma unroll
    for (int j = 0; j < 24; ++j) { float d = xv[j]-mean; vs += d*d; }
    #pragma unroll
    for (int m = 1; m < 16; m <<= 1) vs += __shfl_xor(vs, m);
    float rs = 1.0f / sqrtf(vs * (1.0f/C_) + 1e-5f);
    #pragma unroll
    for (int j = 0; j < 24; ++j) {
      int c = l + 16*j;
      xln[r*C_ + c] = (xv[j]-mean)*rs*g[c] + bb[c];
    }
  }
  __syncthreads();
  {
    int g96 = t % 96, rg = t / 96;
    int i0 = g96 * 4, r0 = rg * 4;
    float4 a0 = make_float4(0,0,0,0), a1 = a0, a2 = a0, a3 = a0;
    #pragma unroll 4
    for (int c = 0; c < C_; ++c) {
      float4 wv = *(const float4*)&W1T[(size_t)c*C_ + i0];
      float x0 = xln[(r0+0)*C_+c];
      float x1 = xln[(r0+1)*C_+c];
      float x2 = xln[(r0+2)*C_+c];
      float x3 = xln[(r0+3)*C_+c];
      a0.x += x0*wv.x; a0.y += x0*wv.y; a0.z += x0*wv.z; a0.w += x0*wv.w;
      a1.x += x1*wv.x; a1.y += x1*wv.y; a1.z += x1*wv.z; a1.w += x1*wv.w;
      a2.x += x2*wv.x; a2.y += x2*wv.y; a2.z += x2*wv.z; a2.w += x2*wv.w;
      a3.x += x3*wv.x; a3.y += x3*wv.y; a3.z += x3*wv.z; a3.w += x3*wv.w;
    }
    float4 bv4 = *(const float4*)&b1[i0];
    float4 av[4] = {a0, a1, a2, a3};
    #pragma unroll
    for (int j = 0; j < 4; ++j) {
      float4 v = av[j];
      v.x += bv4.x; v.y += bv4.y; v.z += bv4.z; v.w += bv4.w;
      v.x = v.x / (1.0f + __expf(-v.x));
      v.y = v.y / (1.0f + __expf(-v.y));
      v.z = v.z / (1.0f + __expf(-v.z));
      v.w = v.w / (1.0f + __expf(-v.w));
      *(float4*)&h[(r0+j)*C_ + i0] = v;
    }
  }
  __syncthreads();
  if (t < 256) {
    int r = t >> 4, l = t & 15;
    const float* hr = &h[r*C_];
    float pd0=0.f, pd1=0.f, pd2=0.f;
    #pragma unroll
    for (int j=0;j<24;++j) {
      int c = l + 16*j;
      float hv = hr[c];
      pd0 += hv*W2[c];
      pd1 += hv*W2[C_ + c];
      pd2 += hv*W2[2*C_ + c];
    }
    #pragma unroll
    for (int m = 1; m < 16; m <<= 1) {
      pd0 += __shfl_xor(pd0, m);
      pd1 += __shfl_xor(pd1, m);
      pd2 += __shfl_xor(pd2, m);
    }
    if (l == 0) {
      size_t row = (size_t)(row0 + r);
      float nmv = node_mask[row];
      float d0 = (pd0 + b2v[0]) * MU_SCALE_;
      float d1 = (pd1 + b2v[1]) * MU_SCALE_;
      float d2 = (pd2 + b2v[2]) * MU_SCALE_;
      mu0[row*3+0] = (mu0[row*3+0] + d0) * nmv;
      mu0[row*3+1] = (mu0[row*3+1] + d1) * nmv;
      mu0[row*3+2] = (mu0[row*3+2] + d2) * nmv;
    }
  }
}

// ---------------- K5: kNN sigma + Sig0 + mu0 out ----------------
__global__ __launch_bounds__(512, 4) void k_knn(
    const float* __restrict__ mu0, const float* __restrict__ node_mask,
    const float* __restrict__ sigpc, float* __restrict__ out) {
  __shared__ float4 cand[N_];        // 64 KB
  int t = threadIdx.x;
  int b = blockIdx.y;
  int n0 = blockIdx.x * 32;
  const float* mb = mu0 + (size_t)b*N_*3;
  const float* nmB = node_mask + (size_t)b*N_;
  for (int idx = t; idx < N_; idx += 512) {
    float x = mb[idx*3+0], y = mb[idx*3+1], z = mb[idx*3+2];
    float w = (nmB[idx] > 0.5f) ? 0.f : BIG_;
    cand[idx] = make_float4(x, y, z, w);
  }
  __syncthreads();
  int r = t >> 4, qq = t & 15;
  int n = n0 + r;
  float4 e = cand[n];
  float best[8];
  #pragma unroll
  for (int i=0;i<8;++i) best[i] = BIG_;
  int base = qq * 256;
  #pragma unroll 4
  for (int i = 0; i < 256; ++i) {
    int m = base + ((i + qq) & 255);
    float4 c = cand[m];
    float dx = c.x - e.x, dy = c.y - e.y, dz = c.z - e.z;
    float d2 = dx*dx + dy*dy + dz*dz + c.w;
    if (m == n) d2 = BIG_;
    if (d2 < best[7]) {
      #pragma unroll
      for (int i2 = 7; i2 >= 1; --i2)
        best[i2] = (best[i2] > d2) ? ((best[i2-1] > d2) ? best[i2-1] : d2) : best[i2];
      best[0] = (best[0] > d2) ? d2 : best[0];
    }
  }
  #pragma unroll
  for (int mk = 1; mk <= 8; mk <<= 1) {
    float ob[8];
    #pragma unroll
    for (int i = 0; i < 8; ++i) ob[i] = __shfl_xor(best[7-i], mk);
    #pragma unroll
    for (int i = 0; i < 8; ++i) best[i] = fminf(best[i], ob[i]);
    #pragma unroll
    for (int i = 0; i < 4; ++i) {
      float lo = fminf(best[i], best[i+4]);
      float hi = fmaxf(best[i], best[i+4]);
      best[i] = lo; best[i+4] = hi;
    }
    #pragma unroll
    for (int gI = 0; gI < 2; ++gI) {
      int o = gI*4;
      float lo0 = fminf(best[o+0], best[o+2]);
      float hi0 = fmaxf(best[o+0], best[o+2]);
      float lo1 = fminf(best[o+1], best[o+3]);
      float hi1 = fmaxf(best[o+1], best[o+3]);
      best[o+0]=lo0; best[o+2]=hi0; best[o+1]=lo1; best[o+3]=hi1;
    }
    #pragma unroll
    for (int p = 0; p < 8; p += 2) {
      float lo = fminf(best[p], best[p+1]);
      float hi = fmaxf(best[p], best[p+1]);
      best[p] = lo; best[p+1] = hi;
    }
  }
  if (qq == 0) {
    float ssum = 0.f;
    #pragma unroll
    for (int i = 0; i < 8; ++i) ssum += sqrtf(fmaxf(best[i], 0.f));
    float sigma = fminf(fmaxf(ALPHA_ * (ssum * 0.125f), SFLOOR_), SCEIL_);
    float s2 = sigma*sigma + JITTER_;
    size_t row = (size_t)b*N_ + n;
    float nmv = nmB[n];
    size_t orow = row * 396;
    const float* sg = &sigpc[row*9];
    #pragma unroll
    for (int e2=0;e2<9;++e2) {
      bool diag = (e2==0)||(e2==4)||(e2==8);
      float v = BETA_*sg[e2] + (diag ? ((1.0f-BETA_)*s2 + JITTER_) : 0.0f);
      out[orow + 387 + e2] = v * nmv;
    }
    out[orow + 384] = e.x;
    out[orow + 385] = e.y;
    out[orow + 386] = e.z;
  }
}

extern "C" void kernel_launch(void* const* d_in, const int* in_sizes, int n_in,
                              void* d_out, int out_size, void* d_ws, size_t ws_size,
                              hipStream_t stream) {
  const float* s_parent    = (const float*)d_in[0];
  const float* mu_p        = (const float*)d_in[1];
  const float* Sig_p       = (const float*)d_in[2];
  const float* mask_parent = (const float*)d_in[3];
  const float* node_mask   = (const float*)d_in[4];
  const float* s_trunk     = (const float*)d_in[5];
  const float* Wq   = (const float*)d_in[6];
  const float* Wk   = (const float*)d_in[7];
  const float* Wv   = (const float*)d_in[8];
  const float* Wpos = (const float*)d_in[9];
  const float* lnq_g = (const float*)d_in[10];
  const float* lnq_b = (const float*)d_in[11];
  const float* lnk_g = (const float*)d_in[12];
  const float* lnk_b = (const float*)d_in[13];
  const float* lnv_g = (const float*)d_in[14];
  const float* lnv_b = (const float*)d_in[15];
  const float* mo_ln_g = (const float*)d_in[16];
  const float* mo_ln_b = (const float*)d_in[17];
  const float* mo_W1 = (const float*)d_in[18];
  const float* mo_b1 = (const float*)d_in[19];
  const float* mo_W2 = (const float*)d_in[20];
  const float* mo_b2 = (const float*)d_in[21];

  char* wsb = (char*)d_ws;
  u16* qhi  = (u16*)wsb;
  u16* qlo  = qhi + (size_t)B_*N_*C_;
  u16* khi  = (u16*)(wsb + 25165824);
  u16* klo  = khi + (size_t)B_*KP*C_;
  u16* vthi = (u16*)(wsb + 25165824 + 3145728);
  u16* vtlo = vthi + (size_t)B_*C_*KP;
  char* pfb = wsb + 25165824 + 2*3145728;
  u16* pf   = (u16*)pfb;
  u16* spt  = (u16*)(pfb + 12582912);
  char* pw  = pfb + 12582912 + 1572864;
  float* wqT = (float*)pw;                       // 589824 B
  u16* wkhi  = (u16*)(pw + 589824);              // 294912 B each
  u16* wklo  = (u16*)(pw + 884736);
  u16* wvhi  = (u16*)(pw + 1179648);
  u16* wvlo  = (u16*)(pw + 1474560);
  u16* mshi  = (u16*)(pw + 1769472);             // 65536 B
  u16* mslo  = mshi + (size_t)B_*16*64*8;        // 65536 B
  float* w1T = (float*)(wsb + 25165824);         // reuses K region after k_route
  float* mu0 = (float*)(wsb + 25165824 + 2*3145728 + 25165824);
  float* sg  = mu0 + (size_t)B_*N_*3;
  float* out = (float*)d_out;

  dim3 tb(32, 8);
  dim3 tg(C_/32, C_/32);
  k_transpose<<<tg, tb, 0, stream>>>(Wq, wqT);
  k_wpack<<<dim3(24), dim3(256), 0, stream>>>(Wk, wkhi, wklo);
  k_wpack<<<dim3(24), dim3(256), 0, stream>>>(Wv, wvhi, wvlo);
  k_sptr<<<dim3(KP/32, C_/32, B_), dim3(256), 0, stream>>>(s_parent, spt);
  k_musig<<<dim3(B_), dim3(256), 0, stream>>>(mu_p, Sig_p, mshi, mslo);

  k_kvproj<<<dim3(B_*KP/16), dim3(256), 0, stream>>>(
      s_parent, mu_p, lnk_g, lnk_b, lnv_g, lnv_b,
      wkhi, wklo, wvhi, wvlo, Wpos,
      khi, klo, vthi, vtlo);
  k_qproj<<<dim3(B_*N_/16), dim3(384), 0, stream>>>(
      s_trunk, lnq_g, lnq_b, wqT, qhi, qlo);
  k_route<<<dim3(N_/16, B_), dim3(256), 0, stream>>>(
      qhi, qlo, khi, klo, vthi, vtlo, spt, mshi, mslo,
      mask_parent, node_mask, out, pf, mu0, sg);
  k_transpose<<<tg, tb, 0, stream>>>(mo_W1, w1T);
  k_mlp<<<dim3(B_*N_/16), dim3(384), 0, stream>>>(
      pf, mo_ln_g, mo_ln_b, w1T, mo_b1, mo_W2, mo_b2, node_mask, mu0);
  k_knn<<<dim3(N_/32, B_), dim3(512), 0, stream>>>(
      mu0, node_mask, sg, out);
}

// Round 9
// 308.451 us; speedup vs baseline: 6.6299x; 1.3571x over previous
//
#include <hip/hip_runtime.h>
#include <math.h>

#define B_ 4
#define N_ 4096
#define KP 512
#define C_ 384

typedef unsigned short u16;
typedef short s8v __attribute__((ext_vector_type(8)));
typedef float f4v __attribute__((ext_vector_type(4)));
#define MFMA(a,b,c) __builtin_amdgcn_mfma_f32_16x16x32_bf16(a,b,c,0,0,0)

constexpr float TAU_INV  = 10.0f;
constexpr float BETA_    = 0.85f;
constexpr float JITTER_  = 1e-6f;
constexpr float ALPHA_   = 1.5f;
constexpr float SFLOOR_  = 1e-3f;
constexpr float SCEIL_   = 100.0f;
constexpr float MU_SCALE_= 0.25f;
constexpr float NEGV     = -1e9f;
constexpr float BIG_     = 1e9f;

__device__ __forceinline__ u16 f2b_rne(float f) {
  unsigned int u = __float_as_uint(f);
  return (u16)((u + 0x7FFFu + ((u >> 16) & 1u)) >> 16);
}
__device__ __forceinline__ float b2f(u16 h) {
  return __uint_as_float(((unsigned int)h) << 16);
}
__device__ __forceinline__ void split_hl(float f, u16& hi, u16& lo) {
  unsigned int u = __float_as_uint(f);
  hi = (u16)(u >> 16);
  float fh = __uint_as_float(u & 0xFFFF0000u);
  lo = f2b_rne(f - fh);
}

// Packed fragment layouts (per 16x16x32 MFMA), 1KB contiguous per fragment:
//  K (A-op):   [b*32+kp_tile][cc(12)][lane][8], lane=(kp&15)+16*((c>>3)&3)
//  q (B-op):   [n>>4][cc(12)][lane][8],        lane=(n&15)+16*((c>>3)&3)
//  V^T/spT (B-op): [b*24+c_tile][ks(16)][lane][8], lane=(c&15)+16*((kp>>3)&3)
//  W (B-op):   [ot(24)][cs(12)][lane][8],      lane=(outc&15)+16*((inc>>3)&3)
//  musig (B-op): [b][ks(16)][lane][8], cols 0-2=mu, 3-11=symSig, 12-15=0

// ---------------- K0a: W row-major -> packed B-op hi/lo fragments ----------------
__global__ __launch_bounds__(256) void k_wpack(
    const float* __restrict__ W, u16* __restrict__ whi, u16* __restrict__ wlo) {
  int ot = blockIdx.x;
  for (int s = threadIdx.x; s < 768; s += 256) {
    int cs = s >> 6, lane = s & 63;
    int outc = ot*16 + (lane & 15);
    int inc0 = cs*32 + (lane >> 4)*8;
    u16 hh[8], ll[8];
    #pragma unroll
    for (int e = 0; e < 8; ++e)
      split_hl(W[(size_t)outc*C_ + inc0 + e], hh[e], ll[e]);
    size_t fo = ((size_t)ot*12 + cs)*512 + (size_t)lane*8;
    *(ushort4*)&whi[fo]   = make_ushort4(hh[0],hh[1],hh[2],hh[3]);
    *(ushort4*)&whi[fo+4] = make_ushort4(hh[4],hh[5],hh[6],hh[7]);
    *(ushort4*)&wlo[fo]   = make_ushort4(ll[0],ll[1],ll[2],ll[3]);
    *(ushort4*)&wlo[fo+4] = make_ushort4(ll[4],ll[5],ll[6],ll[7]);
  }
}

// ---------------- K0b: s_parent -> spT bf16 packed fragments ----------------
__global__ __launch_bounds__(256) void k_sptr(
    const float* __restrict__ sp, u16* __restrict__ spt) {
  __shared__ float tl[32][33];
  int bx = blockIdx.x * 32;   // kp
  int by = blockIdx.y * 32;   // c
  int bz = blockIdx.z;        // b
  const float* s = sp + (size_t)bz * KP * C_;
  int tx = threadIdx.x & 31, ty4 = threadIdx.x >> 5;
  #pragma unroll
  for (int j = 0; j < 32; j += 8)
    tl[ty4 + j][tx] = s[(size_t)(bx + ty4 + j) * C_ + by + tx];  // tl[kp_l][c_l]
  __syncthreads();
  int t = threadIdx.x;
  if (t < 128) {
    int c_l = t >> 2, krun = t & 3;
    int kp0r = krun * 8;
    u16 hh[8];
    #pragma unroll
    for (int e = 0; e < 8; ++e) hh[e] = f2b_rne(tl[kp0r + e][c_l]);
    int cg = by + c_l;
    int lane = (cg & 15) + 16 * krun;
    size_t fo = (((size_t)bz*24 + (cg >> 4))*16 + (bx >> 5))*512 + (size_t)lane*8;
    *(ushort4*)&spt[fo]   = make_ushort4(hh[0],hh[1],hh[2],hh[3]);
    *(ushort4*)&spt[fo+4] = make_ushort4(hh[4],hh[5],hh[6],hh[7]);
  }
}

// ---------------- K0c: mu_p + sym(Sig_p) -> packed hi/lo B fragments ----------------
__global__ __launch_bounds__(256) void k_musig(
    const float* __restrict__ mu_p, const float* __restrict__ Sig_p,
    u16* __restrict__ mshi, u16* __restrict__ mslo) {
  int b = blockIdx.x;
  int t = threadIdx.x;
  for (int s = t; s < 1024; s += 256) {
    int ks = s >> 6, lane = s & 63;
    int col = lane & 15, kb = lane >> 4;
    u16 hh[8], ll[8];
    #pragma unroll
    for (int e = 0; e < 8; ++e) {
      int kp = ks*32 + kb*8 + e;
      float v = 0.f;
      if (col < 3) {
        v = mu_p[((size_t)b*KP + kp)*3 + col];
      } else if (col < 12) {
        int ee = col - 3, ii = ee/3, jj = ee%3;
        const float* sg = &Sig_p[((size_t)b*KP + kp)*9];
        v = 0.5f*(sg[ii*3+jj] + sg[jj*3+ii]);
      }
      split_hl(v, hh[e], ll[e]);
    }
    size_t fo = (((size_t)b*16 + ks)*64 + lane)*8;
    *(ushort4*)&mshi[fo]   = make_ushort4(hh[0],hh[1],hh[2],hh[3]);
    *(ushort4*)&mshi[fo+4] = make_ushort4(hh[4],hh[5],hh[6],hh[7]);
    *(ushort4*)&mslo[fo]   = make_ushort4(ll[0],ll[1],ll[2],ll[3]);
    *(ushort4*)&mslo[fo+4] = make_ushort4(ll[4],ll[5],ll[6],ll[7]);
  }
}

// ---------------- K1: parents -> K hi/lo packed, V^T hi/lo packed (MFMA) ----------------
__global__ __launch_bounds__(256) void k_kvproj(
    const float* __restrict__ sp, const float* __restrict__ mu_p,
    const float* __restrict__ gk, const float* __restrict__ bk,
    const float* __restrict__ gv, const float* __restrict__ bv,
    const u16* __restrict__ wkhi, const u16* __restrict__ wklo,
    const u16* __restrict__ wvhi, const u16* __restrict__ wvlo,
    const float* __restrict__ Wpos,
    u16* __restrict__ khi, u16* __restrict__ klo,
    u16* __restrict__ vthi, u16* __restrict__ vtlo) {
  __shared__ u16 fr[4*6144];   // xk_hi | xk_lo | xv_hi | xv_lo (12288B each)
  float* stage = (float*)fr;   // overlays xk_hi+xk_lo (16*384 f32 = 24576B)
  int t = threadIdx.x;
  int pr0 = blockIdx.x * 16;
  {
    int r = t >> 4, l = t & 15;
    const float* xr = sp + (size_t)(pr0 + r) * C_;
    float xv[24]; float s = 0.f;
    #pragma unroll
    for (int j = 0; j < 24; ++j) { xv[j] = xr[l + 16*j]; s += xv[j]; }
    #pragma unroll
    for (int m = 1; m < 16; m <<= 1) s += __shfl_xor(s, m);
    float mean = s * (1.0f/C_);
    float vs = 0.f;
    #pragma unroll
    for (int j = 0; j < 24; ++j) { float d = xv[j]-mean; vs += d*d; }
    #pragma unroll
    for (int m = 1; m < 16; m <<= 1) vs += __shfl_xor(vs, m);
    float rs = 1.0f / sqrtf(vs * (1.0f/C_) + 1e-5f);
    #pragma unroll
    for (int j = 0; j < 24; ++j) {
      int c = l + 16*j;
      float xc = (xv[j]-mean)*rs;
      int idx = (c >> 5)*512 + ((r & 15) + 16*((c >> 3) & 3))*8 + (c & 7);
      u16 h, lo_;
      split_hl(xc*gk[c] + bk[c], h, lo_);
      fr[idx] = h; fr[6144 + idx] = lo_;
      split_hl(xc*gv[c] + bv[c], h, lo_);
      fr[12288 + idx] = h; fr[18432 + idx] = lo_;
    }
  }
  __syncthreads();
  int wv_ = t >> 6, lane = t & 63;
  int l15 = lane & 15, l4 = lane >> 4;
  float mur[4][3];
  #pragma unroll
  for (int rr = 0; rr < 4; ++rr) {
    int prow = pr0 + l4*4 + rr;
    mur[rr][0] = mu_p[(size_t)prow*3+0];
    mur[rr][1] = mu_p[(size_t)prow*3+1];
    mur[rr][2] = mu_p[(size_t)prow*3+2];
  }
  f4v acc[6];
  #pragma unroll
  for (int i = 0; i < 6; ++i) acc[i] = (f4v){0.f,0.f,0.f,0.f};
  for (int cs = 0; cs < 12; ++cs) {
    s8v ah = *(const s8v*)&fr[cs*512 + lane*8];
    s8v al = *(const s8v*)&fr[6144 + cs*512 + lane*8];
    #pragma unroll
    for (int o6 = 0; o6 < 6; ++o6) {
      int ot = wv_*6 + o6;
      s8v bh = *(const s8v*)&wkhi[((size_t)ot*12 + cs)*512 + lane*8];
      s8v bl = *(const s8v*)&wklo[((size_t)ot*12 + cs)*512 + lane*8];
      acc[o6] = MFMA(ah, bh, acc[o6]);
      acc[o6] = MFMA(al, bh, acc[o6]);
      acc[o6] = MFMA(ah, bl, acc[o6]);
    }
  }
  #pragma unroll
  for (int o6 = 0; o6 < 6; ++o6) {
    int outc = (wv_*6 + o6)*16 + l15;
    float w0 = Wpos[outc*3+0], w1 = Wpos[outc*3+1], w2 = Wpos[outc*3+2];
    #pragma unroll
    for (int rr = 0; rr < 4; ++rr)
      acc[o6][rr] += mur[rr][0]*w0 + mur[rr][1]*w1 + mur[rr][2]*w2;
  }
  __syncthreads();
  #pragma unroll
  for (int o6 = 0; o6 < 6; ++o6) {
    int c = (wv_*6 + o6)*16 + l15;
    #pragma unroll
    for (int rr = 0; rr < 4; ++rr)
      stage[(l4*4 + rr)*C_ + c] = acc[o6][rr];
  }
  __syncthreads();
  for (int s2 = t; s2 < 768; s2 += 256) {
    int cc = s2 >> 6, lp = s2 & 63;
    int kp_l = lp & 15, l4g = lp >> 4;
    int c0 = cc*32 + l4g*8;
    u16 hh[8], ll[8];
    #pragma unroll
    for (int e = 0; e < 8; ++e) split_hl(stage[kp_l*C_ + c0 + e], hh[e], ll[e]);
    size_t fo = ((size_t)blockIdx.x*12 + cc)*512 + (size_t)lp*8;
    *(ushort4*)&khi[fo]   = make_ushort4(hh[0],hh[1],hh[2],hh[3]);
    *(ushort4*)&khi[fo+4] = make_ushort4(hh[4],hh[5],hh[6],hh[7]);
    *(ushort4*)&klo[fo]   = make_ushort4(ll[0],ll[1],ll[2],ll[3]);
    *(ushort4*)&klo[fo+4] = make_ushort4(ll[4],ll[5],ll[6],ll[7]);
  }
  f4v vac[6];
  #pragma unroll
  for (int i = 0; i < 6; ++i) vac[i] = (f4v){0.f,0.f,0.f,0.f};
  for (int cs = 0; cs < 12; ++cs) {
    s8v ah = *(const s8v*)&fr[12288 + cs*512 + lane*8];
    s8v al = *(const s8v*)&fr[18432 + cs*512 + lane*8];
    #pragma unroll
    for (int o6 = 0; o6 < 6; ++o6) {
      int ot = wv_*6 + o6;
      s8v bh = *(const s8v*)&wvhi[((size_t)ot*12 + cs)*512 + lane*8];
      s8v bl = *(const s8v*)&wvlo[((size_t)ot*12 + cs)*512 + lane*8];
      vac[o6] = MFMA(ah, bh, vac[o6]);
      vac[o6] = MFMA(al, bh, vac[o6]);
      vac[o6] = MFMA(ah, bl, vac[o6]);
    }
  }
  __syncthreads();
  #pragma unroll
  for (int o6 = 0; o6 < 6; ++o6) {
    int c = (wv_*6 + o6)*16 + l15;
    #pragma unroll
    for (int rr = 0; rr < 4; ++rr)
      stage[(l4*4 + rr)*C_ + c] = vac[o6][rr];
  }
  __syncthreads();
  {
    int b = blockIdx.x >> 5;
    int ks = (blockIdx.x & 31) >> 1;
    int lg0 = (blockIdx.x & 1) * 2;
    for (int s2 = t; s2 < 768; s2 += 256) {
      int c = s2 >> 1, half = s2 & 1;
      int lp = (c & 15) + 16*(lg0 + half);
      u16 hh[8], ll[8];
      #pragma unroll
      for (int e = 0; e < 8; ++e)
        split_hl(stage[(half*8 + e)*C_ + c], hh[e], ll[e]);
      size_t fo = (((size_t)b*24 + (c >> 4))*16 + ks)*512 + (size_t)lp*8;
      *(ushort4*)&vthi[fo]   = make_ushort4(hh[0],hh[1],hh[2],hh[3]);
      *(ushort4*)&vthi[fo+4] = make_ushort4(hh[4],hh[5],hh[6],hh[7]);
      *(ushort4*)&vtlo[fo]   = make_ushort4(ll[0],ll[1],ll[2],ll[3]);
      *(ushort4*)&vtlo[fo+4] = make_ushort4(ll[4],ll[5],ll[6],ll[7]);
    }
  }
}

// ---------------- K2: s_trunk -> q hi/lo packed (MFMA) ----------------
__global__ __launch_bounds__(256) void k_qproj(
    const float* __restrict__ st, const float* __restrict__ g,
    const float* __restrict__ bb,
    const u16* __restrict__ wqhi, const u16* __restrict__ wqlo,
    u16* __restrict__ qhi, u16* __restrict__ qlo) {
  __shared__ u16 fr[2*6144];   // x_hi | x_lo
  float* stage = (float*)fr;   // overlays (24576 B)
  int t = threadIdx.x;
  int row0 = blockIdx.x * 16;
  {
    int r = t >> 4, l = t & 15;
    const float* xr = st + (size_t)(row0 + r) * C_;
    float xv[24]; float s = 0.f;
    #pragma unroll
    for (int j = 0; j < 24; ++j) { xv[j] = xr[l + 16*j]; s += xv[j]; }
    #pragma unroll
    for (int m = 1; m < 16; m <<= 1) s += __shfl_xor(s, m);
    float mean = s * (1.0f/C_);
    float vs = 0.f;
    #pragma unroll
    for (int j = 0; j < 24; ++j) { float d = xv[j]-mean; vs += d*d; }
    #pragma unroll
    for (int m = 1; m < 16; m <<= 1) vs += __shfl_xor(vs, m);
    float rs = 1.0f / sqrtf(vs * (1.0f/C_) + 1e-5f);
    #pragma unroll
    for (int j = 0; j < 24; ++j) {
      int c = l + 16*j;
      float xc = (xv[j]-mean)*rs*g[c] + bb[c];
      int idx = (c >> 5)*512 + ((r & 15) + 16*((c >> 3) & 3))*8 + (c & 7);
      u16 h, lo_;
      split_hl(xc, h, lo_);
      fr[idx] = h; fr[6144 + idx] = lo_;
    }
  }
  __syncthreads();
  int wv_ = t >> 6, lane = t & 63;
  int l15 = lane & 15, l4 = lane >> 4;
  f4v acc[6];
  #pragma unroll
  for (int i = 0; i < 6; ++i) acc[i] = (f4v){0.f,0.f,0.f,0.f};
  for (int cs = 0; cs < 12; ++cs) {
    s8v ah = *(const s8v*)&fr[cs*512 + lane*8];
    s8v al = *(const s8v*)&fr[6144 + cs*512 + lane*8];
    #pragma unroll
    for (int o6 = 0; o6 < 6; ++o6) {
      int ot = wv_*6 + o6;
      s8v bh = *(const s8v*)&wqhi[((size_t)ot*12 + cs)*512 + lane*8];
      s8v bl = *(const s8v*)&wqlo[((size_t)ot*12 + cs)*512 + lane*8];
      acc[o6] = MFMA(ah, bh, acc[o6]);
      acc[o6] = MFMA(al, bh, acc[o6]);
      acc[o6] = MFMA(ah, bl, acc[o6]);
    }
  }
  __syncthreads();
  #pragma unroll
  for (int o6 = 0; o6 < 6; ++o6) {
    int c = (wv_*6 + o6)*16 + l15;
    #pragma unroll
    for (int rr = 0; rr < 4; ++rr)
      stage[(l4*4 + rr)*C_ + c] = acc[o6][rr];
  }
  __syncthreads();
  for (int s2 = t; s2 < 768; s2 += 256) {
    int cc = s2 >> 6, lp = s2 & 63;
    int n_l = lp & 15, l4g = lp >> 4;
    int c0 = cc*32 + l4g*8;
    u16 hh[8], ll[8];
    #pragma unroll
    for (int e = 0; e < 8; ++e) split_hl(stage[n_l*C_ + c0 + e], hh[e], ll[e]);
    size_t fo = ((size_t)blockIdx.x*12 + cc)*512 + (size_t)lp*8;
    *(ushort4*)&qhi[fo] = make_ushort4(hh[0],hh[1],hh[2],hh[3]);
    *(ushort4*)&qhi[fo+4] = make_ushort4(hh[4],hh[5],hh[6],hh[7]);
    *(ushort4*)&qlo[fo] = make_ushort4(ll[0],ll[1],ll[2],ll[3]);
    *(ushort4*)&qlo[fo+4] = make_ushort4(ll[4],ll[5],ll[6],ll[7]);
  }
}

// ---------------- K3: MFMA router: 16-n tile, 4 waves = 4 kp-quarters ----------------
__global__ __launch_bounds__(256, 4) void k_route(
    const u16* __restrict__ qhi, const u16* __restrict__ qlo,
    const u16* __restrict__ khi, const u16* __restrict__ klo,
    const u16* __restrict__ vthi, const u16* __restrict__ vtlo,
    const u16* __restrict__ spt,
    const u16* __restrict__ mshi, const u16* __restrict__ mslo,
    const float* __restrict__ mask_parent, const float* __restrict__ node_mask,
    float* __restrict__ out, u16* __restrict__ pf,
    float* __restrict__ mu0, float* __restrict__ sigpc) {
  __shared__ u16   wlds[16*512];
  __shared__ float smask[KP];
  __shared__ float red[4][2][16];
  __shared__ float musred[4][64][4];

  int t = threadIdx.x;
  int bb = blockIdx.y;
  int nb = blockIdx.x * 16;
  int wh = t >> 6, lane = t & 63;
  int l15 = lane & 15, l4 = lane >> 4;

  {
    const float4* ms = (const float4*)(mask_parent + (size_t)bb*KP);
    for (int i = t; i < 128; i += 256) ((float4*)smask)[i] = ms[i];
  }
  __syncthreads();

  const u16* qhB = qhi + ((size_t)(bb*256 + (nb >> 4)))*12*512;
  const u16* qlB = qlo + ((size_t)(bb*256 + (nb >> 4)))*12*512;
  const u16* khB = khi + ((size_t)(bb*32 + wh*8))*12*512;
  const u16* klB = klo + ((size_t)(bb*32 + wh*8))*12*512;
  f4v acc[8];
  #pragma unroll
  for (int kt = 0; kt < 8; ++kt) acc[kt] = (f4v){0.f,0.f,0.f,0.f};
  for (int cs = 0; cs < 12; ++cs) {
    s8v bqh = *(const s8v*)&qhB[(size_t)cs*512 + lane*8];
    s8v bql = *(const s8v*)&qlB[(size_t)cs*512 + lane*8];
    #pragma unroll
    for (int kt = 0; kt < 8; ++kt) {
      s8v ah = *(const s8v*)&khB[((size_t)kt*12 + cs)*512 + lane*8];
      s8v al = *(const s8v*)&klB[((size_t)kt*12 + cs)*512 + lane*8];
      acc[kt] = MFMA(ah, bqh, acc[kt]);
      acc[kt] = MFMA(ah, bql, acc[kt]);
      acc[kt] = MFMA(al, bqh, acc[kt]);
    }
  }

  float mx = -3.4e38f;
  #pragma unroll
  for (int kt = 0; kt < 8; ++kt) {
    const float4 m4 = *(const float4*)&smask[wh*128 + kt*16 + l4*4];
    acc[kt][0] = (m4.x > 0.5f) ? acc[kt][0]*TAU_INV : NEGV;
    acc[kt][1] = (m4.y > 0.5f) ? acc[kt][1]*TAU_INV : NEGV;
    acc[kt][2] = (m4.z > 0.5f) ? acc[kt][2]*TAU_INV : NEGV;
    acc[kt][3] = (m4.w > 0.5f) ? acc[kt][3]*TAU_INV : NEGV;
    mx = fmaxf(mx, fmaxf(fmaxf(acc[kt][0], acc[kt][1]), fmaxf(acc[kt][2], acc[kt][3])));
  }
  mx = fmaxf(mx, __shfl_xor(mx, 16));
  mx = fmaxf(mx, __shfl_xor(mx, 32));
  if (lane < 16) red[wh][0][lane] = mx;
  __syncthreads();
  mx = fmaxf(fmaxf(red[0][0][l15], red[1][0][l15]),
             fmaxf(red[2][0][l15], red[3][0][l15]));
  float smv = 0.f;
  #pragma unroll
  for (int kt = 0; kt < 8; ++kt) {
    #pragma unroll
    for (int r = 0; r < 4; ++r) {
      float e = __expf(acc[kt][r] - mx);
      acc[kt][r] = e; smv += e;
    }
  }
  smv += __shfl_xor(smv, 16);
  smv += __shfl_xor(smv, 32);
  if (lane < 16) red[wh][1][lane] = smv;
  __syncthreads();
  smv = red[0][1][l15] + red[1][1][l15] + red[2][1][l15] + red[3][1][l15];
  float nm = node_mask[(size_t)bb*N_ + nb + l15];
  float scl = nm / smv;
  bool uni = !(nm > 0.5f);
  float uval = nm * (1.0f/KP);
  #pragma unroll
  for (int kt = 0; kt < 8; ++kt) {
    ushort4 wv;
    wv.x = f2b_rne(uni ? uval : acc[kt][0]*scl);
    wv.y = f2b_rne(uni ? uval : acc[kt][1]*scl);
    wv.z = f2b_rne(uni ? uval : acc[kt][2]*scl);
    wv.w = f2b_rne(uni ? uval : acc[kt][3]*scl);
    int kpl = wh*128 + kt*16 + l4*4;
    int bo = (l15*1024 + kpl*2) ^ ((l15 & 7) << 4);
    *(ushort4*)&wlds[bo >> 1] = wv;
  }
  __syncthreads();

  for (int ct = 0; ct < 6; ++ct) {
    int c_tile = wh*6 + ct;
    int c = c_tile*16 + l15;
    f4v aS = (f4v){0.f,0.f,0.f,0.f};
    f4v aP = (f4v){0.f,0.f,0.f,0.f};
    const u16* vhB = vthi + (((size_t)bb*24 + c_tile)*16)*512;
    const u16* vlB = vtlo + (((size_t)bb*24 + c_tile)*16)*512;
    const u16* spB = spt  + (((size_t)bb*24 + c_tile)*16)*512;
    #pragma unroll
    for (int ks = 0; ks < 16; ++ks) {
      int kp = ks*32 + l4*8;
      int bo = (l15*1024 + kp*2) ^ ((l15 & 7) << 4);
      s8v aw = *(const s8v*)&wlds[bo >> 1];
      s8v bh = *(const s8v*)&vhB[(size_t)ks*512 + lane*8];
      s8v bl = *(const s8v*)&vlB[(size_t)ks*512 + lane*8];
      s8v bs = *(const s8v*)&spB[(size_t)ks*512 + lane*8];
      aS = MFMA(aw, bh, aS);
      aS = MFMA(aw, bl, aS);
      aP = MFMA(aw, bs, aP);
    }
    #pragma unroll
    for (int r = 0; r < 4; ++r) {
      int n = nb + l4*4 + r;
      size_t row = (size_t)bb*N_ + n;
      out[row*396 + c] = aS[r];
      pf[row*C_ + c] = f2b_rne(aP[r]);
    }
  }

  {
    f4v pMS = (f4v){0.f,0.f,0.f,0.f};
    #pragma unroll
    for (int k2 = 0; k2 < 4; ++k2) {
      int ks = wh*4 + k2;
      int kp = ks*32 + l4*8;
      int bo = (l15*1024 + kp*2) ^ ((l15 & 7) << 4);
      s8v aw = *(const s8v*)&wlds[bo >> 1];
      s8v bh = *(const s8v*)&mshi[(((size_t)bb*16 + ks)*64 + lane)*8];
      s8v bl = *(const s8v*)&mslo[(((size_t)bb*16 + ks)*64 + lane)*8];
      pMS = MFMA(aw, bh, pMS);
      pMS = MFMA(aw, bl, pMS);
    }
    #pragma unroll
    for (int r = 0; r < 4; ++r) musred[wh][lane][r] = pMS[r];
  }
  __syncthreads();
  if (wh == 0) {
    int col = l15;
    #pragma unroll
    for (int r = 0; r < 4; ++r) {
      float d = musred[0][lane][r] + musred[1][lane][r]
              + musred[2][lane][r] + musred[3][lane][r];
      int n = nb + l4*4 + r;
      size_t row = (size_t)bb*N_ + n;
      if (col < 3) {
        mu0[row*3 + col] = d;
      } else if (col < 12) {
        int e = col - 3;
        if (e == 0 || e == 4 || e == 8) d += JITTER_;
        sigpc[row*9 + e] = d;
      }
    }
  }
}

// ---------------- K4: mu-offset MLP (MFMA) ----------------
__global__ __launch_bounds__(256) void k_mlp(
    const u16* __restrict__ pf, const float* __restrict__ g,
    const float* __restrict__ bb,
    const u16* __restrict__ w1hi, const u16* __restrict__ w1lo,
    const float* __restrict__ b1, const float* __restrict__ W2,
    const float* __restrict__ b2v, const float* __restrict__ node_mask,
    float* __restrict__ mu0) {
  __shared__ u16 fr[2*6144];   // x_hi | x_lo
  float* stage = (float*)fr;   // overlays: h stage [16][384] f32
  int t = threadIdx.x;
  int row0 = blockIdx.x * 16;
  {
    int r = t >> 4, l = t & 15;
    const u16* xr = pf + (size_t)(row0 + r) * C_;
    float xv[24]; float s = 0.f;
    #pragma unroll
    for (int j = 0; j < 24; ++j) { xv[j] = b2f(xr[l + 16*j]); s += xv[j]; }
    #pragma unroll
    for (int m = 1; m < 16; m <<= 1) s += __shfl_xor(s, m);
    float mean = s * (1.0f/C_);
    float vs = 0.f;
    #pragma unroll
    for (int j = 0; j < 24; ++j) { float d = xv[j]-mean; vs += d*d; }
    #pragma unroll
    for (int m = 1; m < 16; m <<= 1) vs += __shfl_xor(vs, m);
    float rs = 1.0f / sqrtf(vs * (1.0f/C_) + 1e-5f);
    #pragma unroll
    for (int j = 0; j < 24; ++j) {
      int c = l + 16*j;
      float xc = (xv[j]-mean)*rs*g[c] + bb[c];
      int idx = (c >> 5)*512 + ((r & 15) + 16*((c >> 3) & 3))*8 + (c & 7);
      u16 h, lo_;
      split_hl(xc, h, lo_);
      fr[idx] = h; fr[6144 + idx] = lo_;
    }
  }
  __syncthreads();
  int wv_ = t >> 6, lane = t & 63;
  int l15 = lane & 15, l4 = lane >> 4;
  f4v acc[6];
  #pragma unroll
  for (int i = 0; i < 6; ++i) acc[i] = (f4v){0.f,0.f,0.f,0.f};
  for (int cs = 0; cs < 12; ++cs) {
    s8v ah = *(const s8v*)&fr[cs*512 + lane*8];
    s8v al = *(const s8v*)&fr[6144 + cs*512 + lane*8];
    #pragma unroll
    for (int o6 = 0; o6 < 6; ++o6) {
      int ot = wv_*6 + o6;
      s8v bh = *(const s8v*)&w1hi[((size_t)ot*12 + cs)*512 + lane*8];
      s8v bl = *(const s8v*)&w1lo[((size_t)ot*12 + cs)*512 + lane*8];
      acc[o6] = MFMA(ah, bh, acc[o6]);
      acc[o6] = MFMA(al, bh, acc[o6]);
      acc[o6] = MFMA(ah, bl, acc[o6]);
    }
  }
  __syncthreads();
  #pragma unroll
  for (int o6 = 0; o6 < 6; ++o6) {
    int c = (wv_*6 + o6)*16 + l15;
    float bv = b1[c];
    #pragma unroll
    for (int rr = 0; rr < 4; ++rr) {
      float v = acc[o6][rr] + bv;
      stage[(l4*4 + rr)*C_ + c] = v / (1.0f + __expf(-v));
    }
  }
  __syncthreads();
  {
    int r = t >> 4, l = t & 15;
    const float* hr = &stage[r*C_];
    float pd0=0.f, pd1=0.f, pd2=0.f;
    #pragma unroll
    for (int j=0;j<24;++j) {
      int c = l + 16*j;
      float hv = hr[c];
      pd0 += hv*W2[c];
      pd1 += hv*W2[C_ + c];
      pd2 += hv*W2[2*C_ + c];
    }
    #pragma unroll
    for (int m = 1; m < 16; m <<= 1) {
      pd0 += __shfl_xor(pd0, m);
      pd1 += __shfl_xor(pd1, m);
      pd2 += __shfl_xor(pd2, m);
    }
    if (l == 0) {
      size_t row = (size_t)(row0 + r);
      float nmv = node_mask[row];
      float d0 = (pd0 + b2v[0]) * MU_SCALE_;
      float d1 = (pd1 + b2v[1]) * MU_SCALE_;
      float d2 = (pd2 + b2v[2]) * MU_SCALE_;
      mu0[row*3+0] = (mu0[row*3+0] + d0) * nmv;
      mu0[row*3+1] = (mu0[row*3+1] + d1) * nmv;
      mu0[row*3+2] = (mu0[row*3+2] + d2) * nmv;
    }
  }
}

// ---------------- K5: kNN sigma + Sig0 + mu0 out ----------------
__global__ __launch_bounds__(512, 4) void k_knn(
    const float* __restrict__ mu0, const float* __restrict__ node_mask,
    const float* __restrict__ sigpc, float* __restrict__ out) {
  __shared__ float4 cand[N_];        // 64 KB
  int t = threadIdx.x;
  int b = blockIdx.y;
  int n0 = blockIdx.x * 32;
  const float* mb = mu0 + (size_t)b*N_*3;
  const float* nmB = node_mask + (size_t)b*N_;
  for (int idx = t; idx < N_; idx += 512) {
    float x = mb[idx*3+0], y = mb[idx*3+1], z = mb[idx*3+2];
    float w = (nmB[idx] > 0.5f) ? 0.f : BIG_;
    cand[idx] = make_float4(x, y, z, w);
  }
  __syncthreads();
  int r = t >> 4, qq = t & 15;
  int n = n0 + r;
  float4 e = cand[n];
  float best[8];
  #pragma unroll
  for (int i=0;i<8;++i) best[i] = BIG_;
  int base = qq * 256;
  #pragma unroll 4
  for (int i = 0; i < 256; ++i) {
    int m = base + ((i + qq) & 255);
    float4 c = cand[m];
    float dx = c.x - e.x, dy = c.y - e.y, dz = c.z - e.z;
    float d2 = dx*dx + dy*dy + dz*dz + c.w;
    if (m == n) d2 = BIG_;
    if (d2 < best[7]) {
      #pragma unroll
      for (int i2 = 7; i2 >= 1; --i2)
        best[i2] = (best[i2] > d2) ? ((best[i2-1] > d2) ? best[i2-1] : d2) : best[i2];
      best[0] = (best[0] > d2) ? d2 : best[0];
    }
  }
  #pragma unroll
  for (int mk = 1; mk <= 8; mk <<= 1) {
    float ob[8];
    #pragma unroll
    for (int i = 0; i < 8; ++i) ob[i] = __shfl_xor(best[7-i], mk);
    #pragma unroll
    for (int i = 0; i < 8; ++i) best[i] = fminf(best[i], ob[i]);
    #pragma unroll
    for (int i = 0; i < 4; ++i) {
      float lo = fminf(best[i], best[i+4]);
      float hi = fmaxf(best[i], best[i+4]);
      best[i] = lo; best[i+4] = hi;
    }
    #pragma unroll
    for (int gI = 0; gI < 2; ++gI) {
      int o = gI*4;
      float lo0 = fminf(best[o+0], best[o+2]);
      float hi0 = fmaxf(best[o+0], best[o+2]);
      float lo1 = fminf(best[o+1], best[o+3]);
      float hi1 = fmaxf(best[o+1], best[o+3]);
      best[o+0]=lo0; best[o+2]=hi0; best[o+1]=lo1; best[o+3]=hi1;
    }
    #pragma unroll
    for (int p = 0; p < 8; p += 2) {
      float lo = fminf(best[p], best[p+1]);
      float hi = fmaxf(best[p], best[p+1]);
      best[p] = lo; best[p+1] = hi;
    }
  }
  if (qq == 0) {
    float ssum = 0.f;
    #pragma unroll
    for (int i = 0; i < 8; ++i) ssum += sqrtf(fmaxf(best[i], 0.f));
    float sigma = fminf(fmaxf(ALPHA_ * (ssum * 0.125f), SFLOOR_), SCEIL_);
    float s2 = sigma*sigma + JITTER_;
    size_t row = (size_t)b*N_ + n;
    float nmv = nmB[n];
    size_t orow = row * 396;
    const float* sg = &sigpc[row*9];
    #pragma unroll
    for (int e2=0;e2<9;++e2) {
      bool diag = (e2==0)||(e2==4)||(e2==8);
      float v = BETA_*sg[e2] + (diag ? ((1.0f-BETA_)*s2 + JITTER_) : 0.0f);
      out[orow + 387 + e2] = v * nmv;
    }
    out[orow + 384] = e.x;
    out[orow + 385] = e.y;
    out[orow + 386] = e.z;
  }
}

extern "C" void kernel_launch(void* const* d_in, const int* in_sizes, int n_in,
                              void* d_out, int out_size, void* d_ws, size_t ws_size,
                              hipStream_t stream) {
  const float* s_parent    = (const float*)d_in[0];
  const float* mu_p        = (const float*)d_in[1];
  const float* Sig_p       = (const float*)d_in[2];
  const float* mask_parent = (const float*)d_in[3];
  const float* node_mask   = (const float*)d_in[4];
  const float* s_trunk     = (const float*)d_in[5];
  const float* Wq   = (const float*)d_in[6];
  const float* Wk   = (const float*)d_in[7];
  const float* Wv   = (const float*)d_in[8];
  const float* Wpos = (const float*)d_in[9];
  const float* lnq_g = (const float*)d_in[10];
  const float* lnq_b = (const float*)d_in[11];
  const float* lnk_g = (const float*)d_in[12];
  const float* lnk_b = (const float*)d_in[13];
  const float* lnv_g = (const float*)d_in[14];
  const float* lnv_b = (const float*)d_in[15];
  const float* mo_ln_g = (const float*)d_in[16];
  const float* mo_ln_b = (const float*)d_in[17];
  const float* mo_W1 = (const float*)d_in[18];
  const float* mo_b1 = (const float*)d_in[19];
  const float* mo_W2 = (const float*)d_in[20];
  const float* mo_b2 = (const float*)d_in[21];

  char* wsb = (char*)d_ws;
  u16* qhi  = (u16*)wsb;
  u16* qlo  = qhi + (size_t)B_*N_*C_;
  u16* khi  = (u16*)(wsb + 25165824);
  u16* klo  = khi + (size_t)B_*KP*C_;
  u16* vthi = (u16*)(wsb + 25165824 + 3145728);
  u16* vtlo = vthi + (size_t)B_*C_*KP;
  char* pfb = wsb + 25165824 + 2*3145728;
  u16* pf   = (u16*)pfb;
  u16* spt  = (u16*)(pfb + 12582912);
  char* pw  = pfb + 12582912 + 1572864;
  u16* wqhi  = (u16*)pw;                         // 294912 B each
  u16* wqlo  = (u16*)(pw + 294912);
  u16* wkhi  = (u16*)(pw + 589824);
  u16* wklo  = (u16*)(pw + 884736);
  u16* wvhi  = (u16*)(pw + 1179648);
  u16* wvlo  = (u16*)(pw + 1474560);
  u16* mshi  = (u16*)(pw + 1769472);             // 65536 B
  u16* mslo  = mshi + (size_t)B_*16*64*8;        // 65536 B
  u16* w1hi  = (u16*)(wsb + 25165824);           // reuses K region after k_route
  u16* w1lo  = w1hi + (size_t)C_*C_;
  float* mu0 = (float*)(wsb + 25165824 + 2*3145728 + 25165824);
  float* sg  = mu0 + (size_t)B_*N_*3;
  float* out = (float*)d_out;

  k_wpack<<<dim3(24), dim3(256), 0, stream>>>(Wq, wqhi, wqlo);
  k_wpack<<<dim3(24), dim3(256), 0, stream>>>(Wk, wkhi, wklo);
  k_wpack<<<dim3(24), dim3(256), 0, stream>>>(Wv, wvhi, wvlo);
  k_sptr<<<dim3(KP/32, C_/32, B_), dim3(256), 0, stream>>>(s_parent, spt);
  k_musig<<<dim3(B_), dim3(256), 0, stream>>>(mu_p, Sig_p, mshi, mslo);

  k_kvproj<<<dim3(B_*KP/16), dim3(256), 0, stream>>>(
      s_parent, mu_p, lnk_g, lnk_b, lnv_g, lnv_b,
      wkhi, wklo, wvhi, wvlo, Wpos,
      khi, klo, vthi, vtlo);
  k_qproj<<<dim3(B_*N_/16), dim3(256), 0, stream>>>(
      s_trunk, lnq_g, lnq_b, wqhi, wqlo, qhi, qlo);
  k_route<<<dim3(N_/16, B_), dim3(256), 0, stream>>>(
      qhi, qlo, khi, klo, vthi, vtlo, spt, mshi, mslo,
      mask_parent, node_mask, out, pf, mu0, sg);
  k_wpack<<<dim3(24), dim3(256), 0, stream>>>(mo_W1, w1hi, w1lo);
  k_mlp<<<dim3(B_*N_/16), dim3(256), 0, stream>>>(
      pf, mo_ln_g, mo_ln_b, w1hi, w1lo, mo_b1, mo_W2, mo_b2, node_mask, mu0);
  k_knn<<<dim3(N_/32, B_), dim3(512), 0, stream>>>(
      mu0, node_mask, sg, out);
}

// Round 10
// 291.229 us; speedup vs baseline: 7.0220x; 1.0591x over previous
//
#include <hip/hip_runtime.h>
#include <math.h>

#define B_ 4
#define N_ 4096
#define KP 512
#define C_ 384

typedef unsigned short u16;
typedef short s8v __attribute__((ext_vector_type(8)));
typedef float f4v __attribute__((ext_vector_type(4)));
#define MFMA(a,b,c) __builtin_amdgcn_mfma_f32_16x16x32_bf16(a,b,c,0,0,0)

constexpr float TAU_INV  = 10.0f;
constexpr float BETA_    = 0.85f;
constexpr float JITTER_  = 1e-6f;
constexpr float ALPHA_   = 1.5f;
constexpr float SFLOOR_  = 1e-3f;
constexpr float SCEIL_   = 100.0f;
constexpr float MU_SCALE_= 0.25f;
constexpr float NEGV     = -1e9f;
constexpr float BIG_     = 1e9f;

__device__ __forceinline__ u16 f2b_rne(float f) {
  unsigned int u = __float_as_uint(f);
  return (u16)((u + 0x7FFFu + ((u >> 16) & 1u)) >> 16);
}
__device__ __forceinline__ float b2f(u16 h) {
  return __uint_as_float(((unsigned int)h) << 16);
}
__device__ __forceinline__ void split_hl(float f, u16& hi, u16& lo) {
  unsigned int u = __float_as_uint(f);
  hi = (u16)(u >> 16);
  float fh = __uint_as_float(u & 0xFFFF0000u);
  lo = f2b_rne(f - fh);
}

// Packed fragment layouts (per 16x16x32 MFMA), 1KB contiguous per fragment:
//  K (A-op):   [b*32+kp_tile][cc(12)][lane][8], lane=(kp&15)+16*((c>>3)&3)
//  q (B-op):   [n>>4][cc(12)][lane][8],        lane=(n&15)+16*((c>>3)&3)
//  V^T/spT (B-op): [b*24+c_tile][ks(16)][lane][8], lane=(c&15)+16*((kp>>3)&3)
//  W (B-op):   [ot(24)][cs(12)][lane][8],      lane=(outc&15)+16*((inc>>3)&3)
//  musig (B-op): [b][ks(16)][lane][8], cols 0-2=mu, 3-11=symSig, 12-15=0

// ---------------- K0a: W row-major -> packed B-op hi/lo fragments ----------------
__global__ __launch_bounds__(256) void k_wpack(
    const float* __restrict__ W, u16* __restrict__ whi, u16* __restrict__ wlo) {
  int ot = blockIdx.x;
  for (int s = threadIdx.x; s < 768; s += 256) {
    int cs = s >> 6, lane = s & 63;
    int outc = ot*16 + (lane & 15);
    int inc0 = cs*32 + (lane >> 4)*8;
    u16 hh[8], ll[8];
    #pragma unroll
    for (int e = 0; e < 8; ++e)
      split_hl(W[(size_t)outc*C_ + inc0 + e], hh[e], ll[e]);
    size_t fo = ((size_t)ot*12 + cs)*512 + (size_t)lane*8;
    *(ushort4*)&whi[fo]   = make_ushort4(hh[0],hh[1],hh[2],hh[3]);
    *(ushort4*)&whi[fo+4] = make_ushort4(hh[4],hh[5],hh[6],hh[7]);
    *(ushort4*)&wlo[fo]   = make_ushort4(ll[0],ll[1],ll[2],ll[3]);
    *(ushort4*)&wlo[fo+4] = make_ushort4(ll[4],ll[5],ll[6],ll[7]);
  }
}

// ---------------- K0b: s_parent -> spT bf16 packed fragments ----------------
__global__ __launch_bounds__(256) void k_sptr(
    const float* __restrict__ sp, u16* __restrict__ spt) {
  __shared__ float tl[32][33];
  int bx = blockIdx.x * 32;   // kp
  int by = blockIdx.y * 32;   // c
  int bz = blockIdx.z;        // b
  const float* s = sp + (size_t)bz * KP * C_;
  int tx = threadIdx.x & 31, ty4 = threadIdx.x >> 5;
  #pragma unroll
  for (int j = 0; j < 32; j += 8)
    tl[ty4 + j][tx] = s[(size_t)(bx + ty4 + j) * C_ + by + tx];  // tl[kp_l][c_l]
  __syncthreads();
  int t = threadIdx.x;
  if (t < 128) {
    int c_l = t >> 2, krun = t & 3;
    int kp0r = krun * 8;
    u16 hh[8];
    #pragma unroll
    for (int e = 0; e < 8; ++e) hh[e] = f2b_rne(tl[kp0r + e][c_l]);
    int cg = by + c_l;
    int lane = (cg & 15) + 16 * krun;
    size_t fo = (((size_t)bz*24 + (cg >> 4))*16 + (bx >> 5))*512 + (size_t)lane*8;
    *(ushort4*)&spt[fo]   = make_ushort4(hh[0],hh[1],hh[2],hh[3]);
    *(ushort4*)&spt[fo+4] = make_ushort4(hh[4],hh[5],hh[6],hh[7]);
  }
}

// ---------------- K0c: mu_p + sym(Sig_p) -> packed hi/lo B fragments ----------------
__global__ __launch_bounds__(256) void k_musig(
    const float* __restrict__ mu_p, const float* __restrict__ Sig_p,
    u16* __restrict__ mshi, u16* __restrict__ mslo) {
  int b = blockIdx.x;
  int t = threadIdx.x;
  for (int s = t; s < 1024; s += 256) {
    int ks = s >> 6, lane = s & 63;
    int col = lane & 15, kb = lane >> 4;
    u16 hh[8], ll[8];
    #pragma unroll
    for (int e = 0; e < 8; ++e) {
      int kp = ks*32 + kb*8 + e;
      float v = 0.f;
      if (col < 3) {
        v = mu_p[((size_t)b*KP + kp)*3 + col];
      } else if (col < 12) {
        int ee = col - 3, ii = ee/3, jj = ee%3;
        const float* sg = &Sig_p[((size_t)b*KP + kp)*9];
        v = 0.5f*(sg[ii*3+jj] + sg[jj*3+ii]);
      }
      split_hl(v, hh[e], ll[e]);
    }
    size_t fo = (((size_t)b*16 + ks)*64 + lane)*8;
    *(ushort4*)&mshi[fo]   = make_ushort4(hh[0],hh[1],hh[2],hh[3]);
    *(ushort4*)&mshi[fo+4] = make_ushort4(hh[4],hh[5],hh[6],hh[7]);
    *(ushort4*)&mslo[fo]   = make_ushort4(ll[0],ll[1],ll[2],ll[3]);
    *(ushort4*)&mslo[fo+4] = make_ushort4(ll[4],ll[5],ll[6],ll[7]);
  }
}

// ---------------- K1: parents -> K hi/lo packed, V^T hi/lo packed (MFMA) ----------------
__global__ __launch_bounds__(256) void k_kvproj(
    const float* __restrict__ sp, const float* __restrict__ mu_p,
    const float* __restrict__ gk, const float* __restrict__ bk,
    const float* __restrict__ gv, const float* __restrict__ bv,
    const u16* __restrict__ wkhi, const u16* __restrict__ wklo,
    const u16* __restrict__ wvhi, const u16* __restrict__ wvlo,
    const float* __restrict__ Wpos,
    u16* __restrict__ khi, u16* __restrict__ klo,
    u16* __restrict__ vthi, u16* __restrict__ vtlo) {
  __shared__ u16 fr[4*6144];   // xk_hi | xk_lo | xv_hi | xv_lo (12288B each)
  float* stage = (float*)fr;   // overlays xk_hi+xk_lo (16*384 f32 = 24576B)
  int t = threadIdx.x;
  int pr0 = blockIdx.x * 16;
  {
    int r = t >> 4, l = t & 15;
    const float* xr = sp + (size_t)(pr0 + r) * C_;
    float xv[24]; float s = 0.f;
    #pragma unroll
    for (int j = 0; j < 24; ++j) { xv[j] = xr[l + 16*j]; s += xv[j]; }
    #pragma unroll
    for (int m = 1; m < 16; m <<= 1) s += __shfl_xor(s, m);
    float mean = s * (1.0f/C_);
    float vs = 0.f;
    #pragma unroll
    for (int j = 0; j < 24; ++j) { float d = xv[j]-mean; vs += d*d; }
    #pragma unroll
    for (int m = 1; m < 16; m <<= 1) vs += __shfl_xor(vs, m);
    float rs = 1.0f / sqrtf(vs * (1.0f/C_) + 1e-5f);
    #pragma unroll
    for (int j = 0; j < 24; ++j) {
      int c = l + 16*j;
      float xc = (xv[j]-mean)*rs;
      int idx = (c >> 5)*512 + ((r & 15) + 16*((c >> 3) & 3))*8 + (c & 7);
      u16 h, lo_;
      split_hl(xc*gk[c] + bk[c], h, lo_);
      fr[idx] = h; fr[6144 + idx] = lo_;
      split_hl(xc*gv[c] + bv[c], h, lo_);
      fr[12288 + idx] = h; fr[18432 + idx] = lo_;
    }
  }
  __syncthreads();
  int wv_ = t >> 6, lane = t & 63;
  int l15 = lane & 15, l4 = lane >> 4;
  float mur[4][3];
  #pragma unroll
  for (int rr = 0; rr < 4; ++rr) {
    int prow = pr0 + l4*4 + rr;
    mur[rr][0] = mu_p[(size_t)prow*3+0];
    mur[rr][1] = mu_p[(size_t)prow*3+1];
    mur[rr][2] = mu_p[(size_t)prow*3+2];
  }
  f4v acc[6];
  #pragma unroll
  for (int i = 0; i < 6; ++i) acc[i] = (f4v){0.f,0.f,0.f,0.f};
  for (int cs = 0; cs < 12; ++cs) {
    s8v ah = *(const s8v*)&fr[cs*512 + lane*8];
    s8v al = *(const s8v*)&fr[6144 + cs*512 + lane*8];
    #pragma unroll
    for (int o6 = 0; o6 < 6; ++o6) {
      int ot = wv_*6 + o6;
      s8v bh = *(const s8v*)&wkhi[((size_t)ot*12 + cs)*512 + lane*8];
      s8v bl = *(const s8v*)&wklo[((size_t)ot*12 + cs)*512 + lane*8];
      acc[o6] = MFMA(ah, bh, acc[o6]);
      acc[o6] = MFMA(al, bh, acc[o6]);
      acc[o6] = MFMA(ah, bl, acc[o6]);
    }
  }
  #pragma unroll
  for (int o6 = 0; o6 < 6; ++o6) {
    int outc = (wv_*6 + o6)*16 + l15;
    float w0 = Wpos[outc*3+0], w1 = Wpos[outc*3+1], w2 = Wpos[outc*3+2];
    #pragma unroll
    for (int rr = 0; rr < 4; ++rr)
      acc[o6][rr] += mur[rr][0]*w0 + mur[rr][1]*w1 + mur[rr][2]*w2;
  }
  __syncthreads();
  #pragma unroll
  for (int o6 = 0; o6 < 6; ++o6) {
    int c = (wv_*6 + o6)*16 + l15;
    #pragma unroll
    for (int rr = 0; rr < 4; ++rr)
      stage[(l4*4 + rr)*C_ + c] = acc[o6][rr];
  }
  __syncthreads();
  for (int s2 = t; s2 < 768; s2 += 256) {
    int cc = s2 >> 6, lp = s2 & 63;
    int kp_l = lp & 15, l4g = lp >> 4;
    int c0 = cc*32 + l4g*8;
    u16 hh[8], ll[8];
    #pragma unroll
    for (int e = 0; e < 8; ++e) split_hl(stage[kp_l*C_ + c0 + e], hh[e], ll[e]);
    size_t fo = ((size_t)blockIdx.x*12 + cc)*512 + (size_t)lp*8;
    *(ushort4*)&khi[fo]   = make_ushort4(hh[0],hh[1],hh[2],hh[3]);
    *(ushort4*)&khi[fo+4] = make_ushort4(hh[4],hh[5],hh[6],hh[7]);
    *(ushort4*)&klo[fo]   = make_ushort4(ll[0],ll[1],ll[2],ll[3]);
    *(ushort4*)&klo[fo+4] = make_ushort4(ll[4],ll[5],ll[6],ll[7]);
  }
  f4v vac[6];
  #pragma unroll
  for (int i = 0; i < 6; ++i) vac[i] = (f4v){0.f,0.f,0.f,0.f};
  for (int cs = 0; cs < 12; ++cs) {
    s8v ah = *(const s8v*)&fr[12288 + cs*512 + lane*8];
    s8v al = *(const s8v*)&fr[18432 + cs*512 + lane*8];
    #pragma unroll
    for (int o6 = 0; o6 < 6; ++o6) {
      int ot = wv_*6 + o6;
      s8v bh = *(const s8v*)&wvhi[((size_t)ot*12 + cs)*512 + lane*8];
      s8v bl = *(const s8v*)&wvlo[((size_t)ot*12 + cs)*512 + lane*8];
      vac[o6] = MFMA(ah, bh, vac[o6]);
      vac[o6] = MFMA(al, bh, vac[o6]);
      vac[o6] = MFMA(ah, bl, vac[o6]);
    }
  }
  __syncthreads();
  #pragma unroll
  for (int o6 = 0; o6 < 6; ++o6) {
    int c = (wv_*6 + o6)*16 + l15;
    #pragma unroll
    for (int rr = 0; rr < 4; ++rr)
      stage[(l4*4 + rr)*C_ + c] = vac[o6][rr];
  }
  __syncthreads();
  {
    int b = blockIdx.x >> 5;
    int ks = (blockIdx.x & 31) >> 1;
    int lg0 = (blockIdx.x & 1) * 2;
    for (int s2 = t; s2 < 768; s2 += 256) {
      int c = s2 >> 1, half = s2 & 1;
      int lp = (c & 15) + 16*(lg0 + half);
      u16 hh[8], ll[8];
      #pragma unroll
      for (int e = 0; e < 8; ++e)
        split_hl(stage[(half*8 + e)*C_ + c], hh[e], ll[e]);
      size_t fo = (((size_t)b*24 + (c >> 4))*16 + ks)*512 + (size_t)lp*8;
      *(ushort4*)&vthi[fo]   = make_ushort4(hh[0],hh[1],hh[2],hh[3]);
      *(ushort4*)&vthi[fo+4] = make_ushort4(hh[4],hh[5],hh[6],hh[7]);
      *(ushort4*)&vtlo[fo]   = make_ushort4(ll[0],ll[1],ll[2],ll[3]);
      *(ushort4*)&vtlo[fo+4] = make_ushort4(ll[4],ll[5],ll[6],ll[7]);
    }
  }
}

// ---------------- K2: s_trunk -> q hi/lo packed (MFMA) ----------------
__global__ __launch_bounds__(256) void k_qproj(
    const float* __restrict__ st, const float* __restrict__ g,
    const float* __restrict__ bb,
    const u16* __restrict__ wqhi, const u16* __restrict__ wqlo,
    u16* __restrict__ qhi, u16* __restrict__ qlo) {
  __shared__ u16 fr[2*6144];   // x_hi | x_lo
  float* stage = (float*)fr;   // overlays (24576 B)
  int t = threadIdx.x;
  int row0 = blockIdx.x * 16;
  {
    int r = t >> 4, l = t & 15;
    const float* xr = st + (size_t)(row0 + r) * C_;
    float xv[24]; float s = 0.f;
    #pragma unroll
    for (int j = 0; j < 24; ++j) { xv[j] = xr[l + 16*j]; s += xv[j]; }
    #pragma unroll
    for (int m = 1; m < 16; m <<= 1) s += __shfl_xor(s, m);
    float mean = s * (1.0f/C_);
    float vs = 0.f;
    #pragma unroll
    for (int j = 0; j < 24; ++j) { float d = xv[j]-mean; vs += d*d; }
    #pragma unroll
    for (int m = 1; m < 16; m <<= 1) vs += __shfl_xor(vs, m);
    float rs = 1.0f / sqrtf(vs * (1.0f/C_) + 1e-5f);
    #pragma unroll
    for (int j = 0; j < 24; ++j) {
      int c = l + 16*j;
      float xc = (xv[j]-mean)*rs*g[c] + bb[c];
      int idx = (c >> 5)*512 + ((r & 15) + 16*((c >> 3) & 3))*8 + (c & 7);
      u16 h, lo_;
      split_hl(xc, h, lo_);
      fr[idx] = h; fr[6144 + idx] = lo_;
    }
  }
  __syncthreads();
  int wv_ = t >> 6, lane = t & 63;
  int l15 = lane & 15, l4 = lane >> 4;
  f4v acc[6];
  #pragma unroll
  for (int i = 0; i < 6; ++i) acc[i] = (f4v){0.f,0.f,0.f,0.f};
  for (int cs = 0; cs < 12; ++cs) {
    s8v ah = *(const s8v*)&fr[cs*512 + lane*8];
    s8v al = *(const s8v*)&fr[6144 + cs*512 + lane*8];
    #pragma unroll
    for (int o6 = 0; o6 < 6; ++o6) {
      int ot = wv_*6 + o6;
      s8v bh = *(const s8v*)&wqhi[((size_t)ot*12 + cs)*512 + lane*8];
      s8v bl = *(const s8v*)&wqlo[((size_t)ot*12 + cs)*512 + lane*8];
      acc[o6] = MFMA(ah, bh, acc[o6]);
      acc[o6] = MFMA(al, bh, acc[o6]);
      acc[o6] = MFMA(ah, bl, acc[o6]);
    }
  }
  __syncthreads();
  #pragma unroll
  for (int o6 = 0; o6 < 6; ++o6) {
    int c = (wv_*6 + o6)*16 + l15;
    #pragma unroll
    for (int rr = 0; rr < 4; ++rr)
      stage[(l4*4 + rr)*C_ + c] = acc[o6][rr];
  }
  __syncthreads();
  for (int s2 = t; s2 < 768; s2 += 256) {
    int cc = s2 >> 6, lp = s2 & 63;
    int n_l = lp & 15, l4g = lp >> 4;
    int c0 = cc*32 + l4g*8;
    u16 hh[8], ll[8];
    #pragma unroll
    for (int e = 0; e < 8; ++e) split_hl(stage[n_l*C_ + c0 + e], hh[e], ll[e]);
    size_t fo = ((size_t)blockIdx.x*12 + cc)*512 + (size_t)lp*8;
    *(ushort4*)&qhi[fo] = make_ushort4(hh[0],hh[1],hh[2],hh[3]);
    *(ushort4*)&qhi[fo+4] = make_ushort4(hh[4],hh[5],hh[6],hh[7]);
    *(ushort4*)&qlo[fo] = make_ushort4(ll[0],ll[1],ll[2],ll[3]);
    *(ushort4*)&qlo[fo+4] = make_ushort4(ll[4],ll[5],ll[6],ll[7]);
  }
}

// ---------------- K3: MFMA router: 32-n tile, 4 waves = 4 kp-quarters x 2 n-tiles ----------------
__global__ __launch_bounds__(256, 2) void k_route(
    const u16* __restrict__ qhi, const u16* __restrict__ qlo,
    const u16* __restrict__ khi, const u16* __restrict__ klo,
    const u16* __restrict__ vthi, const u16* __restrict__ vtlo,
    const u16* __restrict__ spt,
    const u16* __restrict__ mshi, const u16* __restrict__ mslo,
    const float* __restrict__ mask_parent, const float* __restrict__ node_mask,
    float* __restrict__ out, u16* __restrict__ pf,
    float* __restrict__ mu0, float* __restrict__ sigpc) {
  __shared__ u16   wlds[32*512];        // 32 KB, XOR-swizzled rows (row = n-local 0..31)
  __shared__ float smask[KP];           // 2 KB
  __shared__ float red[4][2][2][16];    // [wave][ntile][max/sum][n] 1 KB
  __shared__ float musred[4][2][64][4]; // 8 KB

  int t = threadIdx.x;
  int bb = blockIdx.y;
  int nb = blockIdx.x * 32;
  int wh = t >> 6, lane = t & 63;
  int l15 = lane & 15, l4 = lane >> 4;

  {
    const float4* ms = (const float4*)(mask_parent + (size_t)bb*KP);
    for (int i = t; i < 128; i += 256) ((float4*)smask)[i] = ms[i];
  }
  __syncthreads();

  // ---- phase 1: logits^T for 2 n-tiles; wave wh covers kp quarter ----
  const u16* qhB0 = qhi + ((size_t)(bb*256 + (nb >> 4)))*12*512;
  const u16* qlB0 = qlo + ((size_t)(bb*256 + (nb >> 4)))*12*512;
  const u16* qhB1 = qhB0 + 12*512;
  const u16* qlB1 = qlB0 + 12*512;
  const u16* khB = khi + ((size_t)(bb*32 + wh*8))*12*512;
  const u16* klB = klo + ((size_t)(bb*32 + wh*8))*12*512;
  f4v acc0[8], acc1[8];
  #pragma unroll
  for (int kt = 0; kt < 8; ++kt) {
    acc0[kt] = (f4v){0.f,0.f,0.f,0.f};
    acc1[kt] = (f4v){0.f,0.f,0.f,0.f};
  }
  for (int cs = 0; cs < 12; ++cs) {
    s8v bqh0 = *(const s8v*)&qhB0[(size_t)cs*512 + lane*8];
    s8v bql0 = *(const s8v*)&qlB0[(size_t)cs*512 + lane*8];
    s8v bqh1 = *(const s8v*)&qhB1[(size_t)cs*512 + lane*8];
    s8v bql1 = *(const s8v*)&qlB1[(size_t)cs*512 + lane*8];
    #pragma unroll
    for (int kt = 0; kt < 8; ++kt) {
      s8v ah = *(const s8v*)&khB[((size_t)kt*12 + cs)*512 + lane*8];
      s8v al = *(const s8v*)&klB[((size_t)kt*12 + cs)*512 + lane*8];
      acc0[kt] = MFMA(ah, bqh0, acc0[kt]);
      acc0[kt] = MFMA(ah, bql0, acc0[kt]);
      acc0[kt] = MFMA(al, bqh0, acc0[kt]);
      acc1[kt] = MFMA(ah, bqh1, acc1[kt]);
      acc1[kt] = MFMA(ah, bql1, acc1[kt]);
      acc1[kt] = MFMA(al, bqh1, acc1[kt]);
    }
  }

  // ---- mask + scale + softmax per n-tile (cross-wave over 4 kp-quarters) ----
  float mx0 = -3.4e38f, mx1 = -3.4e38f;
  #pragma unroll
  for (int kt = 0; kt < 8; ++kt) {
    const float4 m4 = *(const float4*)&smask[wh*128 + kt*16 + l4*4];
    acc0[kt][0] = (m4.x > 0.5f) ? acc0[kt][0]*TAU_INV : NEGV;
    acc0[kt][1] = (m4.y > 0.5f) ? acc0[kt][1]*TAU_INV : NEGV;
    acc0[kt][2] = (m4.z > 0.5f) ? acc0[kt][2]*TAU_INV : NEGV;
    acc0[kt][3] = (m4.w > 0.5f) ? acc0[kt][3]*TAU_INV : NEGV;
    acc1[kt][0] = (m4.x > 0.5f) ? acc1[kt][0]*TAU_INV : NEGV;
    acc1[kt][1] = (m4.y > 0.5f) ? acc1[kt][1]*TAU_INV : NEGV;
    acc1[kt][2] = (m4.z > 0.5f) ? acc1[kt][2]*TAU_INV : NEGV;
    acc1[kt][3] = (m4.w > 0.5f) ? acc1[kt][3]*TAU_INV : NEGV;
    mx0 = fmaxf(mx0, fmaxf(fmaxf(acc0[kt][0], acc0[kt][1]), fmaxf(acc0[kt][2], acc0[kt][3])));
    mx1 = fmaxf(mx1, fmaxf(fmaxf(acc1[kt][0], acc1[kt][1]), fmaxf(acc1[kt][2], acc1[kt][3])));
  }
  mx0 = fmaxf(mx0, __shfl_xor(mx0, 16));
  mx0 = fmaxf(mx0, __shfl_xor(mx0, 32));
  mx1 = fmaxf(mx1, __shfl_xor(mx1, 16));
  mx1 = fmaxf(mx1, __shfl_xor(mx1, 32));
  if (lane < 16) { red[wh][0][0][lane] = mx0; red[wh][1][0][lane] = mx1; }
  __syncthreads();
  mx0 = fmaxf(fmaxf(red[0][0][0][l15], red[1][0][0][l15]),
              fmaxf(red[2][0][0][l15], red[3][0][0][l15]));
  mx1 = fmaxf(fmaxf(red[0][1][0][l15], red[1][1][0][l15]),
              fmaxf(red[2][1][0][l15], red[3][1][0][l15]));
  float sm0 = 0.f, sm1 = 0.f;
  #pragma unroll
  for (int kt = 0; kt < 8; ++kt) {
    #pragma unroll
    for (int r = 0; r < 4; ++r) {
      float e0 = __expf(acc0[kt][r] - mx0);
      float e1 = __expf(acc1[kt][r] - mx1);
      acc0[kt][r] = e0; sm0 += e0;
      acc1[kt][r] = e1; sm1 += e1;
    }
  }
  sm0 += __shfl_xor(sm0, 16); sm0 += __shfl_xor(sm0, 32);
  sm1 += __shfl_xor(sm1, 16); sm1 += __shfl_xor(sm1, 32);
  if (lane < 16) { red[wh][0][1][lane] = sm0; red[wh][1][1][lane] = sm1; }
  __syncthreads();
  sm0 = red[0][0][1][l15] + red[1][0][1][l15] + red[2][0][1][l15] + red[3][0][1][l15];
  sm1 = red[0][1][1][l15] + red[1][1][1][l15] + red[2][1][1][l15] + red[3][1][1][l15];
  float nm0 = node_mask[(size_t)bb*N_ + nb + l15];
  float nm1 = node_mask[(size_t)bb*N_ + nb + 16 + l15];
  float scl0 = nm0 / sm0, scl1 = nm1 / sm1;
  bool uni0 = !(nm0 > 0.5f), uni1 = !(nm1 > 0.5f);
  float uv0 = nm0 * (1.0f/KP), uv1 = nm1 * (1.0f/KP);
  #pragma unroll
  for (int kt = 0; kt < 8; ++kt) {
    int kpl = wh*128 + kt*16 + l4*4;
    ushort4 wv0, wv1;
    wv0.x = f2b_rne(uni0 ? uv0 : acc0[kt][0]*scl0);
    wv0.y = f2b_rne(uni0 ? uv0 : acc0[kt][1]*scl0);
    wv0.z = f2b_rne(uni0 ? uv0 : acc0[kt][2]*scl0);
    wv0.w = f2b_rne(uni0 ? uv0 : acc0[kt][3]*scl0);
    wv1.x = f2b_rne(uni1 ? uv1 : acc1[kt][0]*scl1);
    wv1.y = f2b_rne(uni1 ? uv1 : acc1[kt][1]*scl1);
    wv1.z = f2b_rne(uni1 ? uv1 : acc1[kt][2]*scl1);
    wv1.w = f2b_rne(uni1 ? uv1 : acc1[kt][3]*scl1);
    int bo0 = (l15*1024 + kpl*2) ^ ((l15 & 7) << 4);
    int bo1 = ((l15+16)*1024 + kpl*2) ^ ((l15 & 7) << 4);
    *(ushort4*)&wlds[bo0 >> 1] = wv0;
    *(ushort4*)&wlds[bo1 >> 1] = wv1;
  }
  __syncthreads();

  // ---- phase 3: s0/pf for both n-tiles; wave wh covers 96 c ----
  for (int ct = 0; ct < 6; ++ct) {
    int c_tile = wh*6 + ct;
    int c = c_tile*16 + l15;
    f4v aS0 = (f4v){0.f,0.f,0.f,0.f}, aS1 = aS0;
    f4v aP0 = aS0, aP1 = aS0;
    const u16* vhB = vthi + (((size_t)bb*24 + c_tile)*16)*512;
    const u16* vlB = vtlo + (((size_t)bb*24 + c_tile)*16)*512;
    const u16* spB = spt  + (((size_t)bb*24 + c_tile)*16)*512;
    #pragma unroll
    for (int ks = 0; ks < 16; ++ks) {
      int kp = ks*32 + l4*8;
      int bo0 = (l15*1024 + kp*2) ^ ((l15 & 7) << 4);
      int bo1 = ((l15+16)*1024 + kp*2) ^ ((l15 & 7) << 4);
      s8v aw0 = *(const s8v*)&wlds[bo0 >> 1];
      s8v aw1 = *(const s8v*)&wlds[bo1 >> 1];
      s8v bh = *(const s8v*)&vhB[(size_t)ks*512 + lane*8];
      s8v bl = *(const s8v*)&vlB[(size_t)ks*512 + lane*8];
      s8v bs = *(const s8v*)&spB[(size_t)ks*512 + lane*8];
      aS0 = MFMA(aw0, bh, aS0);
      aS0 = MFMA(aw0, bl, aS0);
      aP0 = MFMA(aw0, bs, aP0);
      aS1 = MFMA(aw1, bh, aS1);
      aS1 = MFMA(aw1, bl, aS1);
      aP1 = MFMA(aw1, bs, aP1);
    }
    #pragma unroll
    for (int r = 0; r < 4; ++r) {
      int n0r = nb + l4*4 + r;
      int n1r = n0r + 16;
      size_t row0_ = (size_t)bb*N_ + n0r;
      size_t row1_ = (size_t)bb*N_ + n1r;
      out[row0_*396 + c] = aS0[r];
      out[row1_*396 + c] = aS1[r];
      pf[row0_*C_ + c] = f2b_rne(aP0[r]);
      pf[row1_*C_ + c] = f2b_rne(aP1[r]);
    }
  }

  // ---- tail via MFMA: mu/sig for both n-tiles, partial per wave ----
  {
    f4v p0 = (f4v){0.f,0.f,0.f,0.f}, p1 = p0;
    #pragma unroll
    for (int k2 = 0; k2 < 4; ++k2) {
      int ks = wh*4 + k2;
      int kp = ks*32 + l4*8;
      int bo0 = (l15*1024 + kp*2) ^ ((l15 & 7) << 4);
      int bo1 = ((l15+16)*1024 + kp*2) ^ ((l15 & 7) << 4);
      s8v aw0 = *(const s8v*)&wlds[bo0 >> 1];
      s8v aw1 = *(const s8v*)&wlds[bo1 >> 1];
      s8v bh = *(const s8v*)&mshi[(((size_t)bb*16 + ks)*64 + lane)*8];
      s8v bl = *(const s8v*)&mslo[(((size_t)bb*16 + ks)*64 + lane)*8];
      p0 = MFMA(aw0, bh, p0);
      p0 = MFMA(aw0, bl, p0);
      p1 = MFMA(aw1, bh, p1);
      p1 = MFMA(aw1, bl, p1);
    }
    #pragma unroll
    for (int r = 0; r < 4; ++r) {
      musred[wh][0][lane][r] = p0[r];
      musred[wh][1][lane][r] = p1[r];
    }
  }
  __syncthreads();
  if (wh < 2) {
    int tile = wh;
    int col = l15;
    #pragma unroll
    for (int r = 0; r < 4; ++r) {
      float d = musred[0][tile][lane][r] + musred[1][tile][lane][r]
              + musred[2][tile][lane][r] + musred[3][tile][lane][r];
      int n = nb + tile*16 + l4*4 + r;
      size_t row = (size_t)bb*N_ + n;
      if (col < 3) {
        mu0[row*3 + col] = d;
      } else if (col < 12) {
        int e = col - 3;
        if (e == 0 || e == 4 || e == 8) d += JITTER_;
        sigpc[row*9 + e] = d;
      }
    }
  }
}

// ---------------- K4: mu-offset MLP (MFMA) ----------------
__global__ __launch_bounds__(256) void k_mlp(
    const u16* __restrict__ pf, const float* __restrict__ g,
    const float* __restrict__ bb,
    const u16* __restrict__ w1hi, const u16* __restrict__ w1lo,
    const float* __restrict__ b1, const float* __restrict__ W2,
    const float* __restrict__ b2v, const float* __restrict__ node_mask,
    float* __restrict__ mu0) {
  __shared__ u16 fr[2*6144];   // x_hi | x_lo
  float* stage = (float*)fr;   // overlays: h stage [16][384] f32
  int t = threadIdx.x;
  int row0 = blockIdx.x * 16;
  {
    int r = t >> 4, l = t & 15;
    const u16* xr = pf + (size_t)(row0 + r) * C_;
    float xv[24]; float s = 0.f;
    #pragma unroll
    for (int j = 0; j < 24; ++j) { xv[j] = b2f(xr[l + 16*j]); s += xv[j]; }
    #pragma unroll
    for (int m = 1; m < 16; m <<= 1) s += __shfl_xor(s, m);
    float mean = s * (1.0f/C_);
    float vs = 0.f;
    #pragma unroll
    for (int j = 0; j < 24; ++j) { float d = xv[j]-mean; vs += d*d; }
    #pragma unroll
    for (int m = 1; m < 16; m <<= 1) vs += __shfl_xor(vs, m);
    float rs = 1.0f / sqrtf(vs * (1.0f/C_) + 1e-5f);
    #pragma unroll
    for (int j = 0; j < 24; ++j) {
      int c = l + 16*j;
      float xc = (xv[j]-mean)*rs*g[c] + bb[c];
      int idx = (c >> 5)*512 + ((r & 15) + 16*((c >> 3) & 3))*8 + (c & 7);
      u16 h, lo_;
      split_hl(xc, h, lo_);
      fr[idx] = h; fr[6144 + idx] = lo_;
    }
  }
  __syncthreads();
  int wv_ = t >> 6, lane = t & 63;
  int l15 = lane & 15, l4 = lane >> 4;
  f4v acc[6];
  #pragma unroll
  for (int i = 0; i < 6; ++i) acc[i] = (f4v){0.f,0.f,0.f,0.f};
  for (int cs = 0; cs < 12; ++cs) {
    s8v ah = *(const s8v*)&fr[cs*512 + lane*8];
    s8v al = *(const s8v*)&fr[6144 + cs*512 + lane*8];
    #pragma unroll
    for (int o6 = 0; o6 < 6; ++o6) {
      int ot = wv_*6 + o6;
      s8v bh = *(const s8v*)&w1hi[((size_t)ot*12 + cs)*512 + lane*8];
      s8v bl = *(const s8v*)&w1lo[((size_t)ot*12 + cs)*512 + lane*8];
      acc[o6] = MFMA(ah, bh, acc[o6]);
      acc[o6] = MFMA(al, bh, acc[o6]);
      acc[o6] = MFMA(ah, bl, acc[o6]);
    }
  }
  __syncthreads();
  #pragma unroll
  for (int o6 = 0; o6 < 6; ++o6) {
    int c = (wv_*6 + o6)*16 + l15;
    float bv = b1[c];
    #pragma unroll
    for (int rr = 0; rr < 4; ++rr) {
      float v = acc[o6][rr] + bv;
      stage[(l4*4 + rr)*C_ + c] = v / (1.0f + __expf(-v));
    }
  }
  __syncthreads();
  {
    int r = t >> 4, l = t & 15;
    const float* hr = &stage[r*C_];
    float pd0=0.f, pd1=0.f, pd2=0.f;
    #pragma unroll
    for (int j=0;j<24;++j) {
      int c = l + 16*j;
      float hv = hr[c];
      pd0 += hv*W2[c];
      pd1 += hv*W2[C_ + c];
      pd2 += hv*W2[2*C_ + c];
    }
    #pragma unroll
    for (int m = 1; m < 16; m <<= 1) {
      pd0 += __shfl_xor(pd0, m);
      pd1 += __shfl_xor(pd1, m);
      pd2 += __shfl_xor(pd2, m);
    }
    if (l == 0) {
      size_t row = (size_t)(row0 + r);
      float nmv = node_mask[row];
      float d0 = (pd0 + b2v[0]) * MU_SCALE_;
      float d1 = (pd1 + b2v[1]) * MU_SCALE_;
      float d2 = (pd2 + b2v[2]) * MU_SCALE_;
      mu0[row*3+0] = (mu0[row*3+0] + d0) * nmv;
      mu0[row*3+1] = (mu0[row*3+1] + d1) * nmv;
      mu0[row*3+2] = (mu0[row*3+2] + d2) * nmv;
    }
  }
}

// ---------------- K5: kNN sigma + Sig0 + mu0 out ----------------
__global__ __launch_bounds__(512, 4) void k_knn(
    const float* __restrict__ mu0, const float* __restrict__ node_mask,
    const float* __restrict__ sigpc, float* __restrict__ out) {
  __shared__ float4 cand[N_];        // 64 KB
  int t = threadIdx.x;
  int b = blockIdx.y;
  int n0 = blockIdx.x * 32;
  const float* mb = mu0 + (size_t)b*N_*3;
  const float* nmB = node_mask + (size_t)b*N_;
  for (int idx = t; idx < N_; idx += 512) {
    float x = mb[idx*3+0], y = mb[idx*3+1], z = mb[idx*3+2];
    float w = (nmB[idx] > 0.5f) ? 0.f : BIG_;
    cand[idx] = make_float4(x, y, z, w);
  }
  __syncthreads();
  int r = t >> 4, qq = t & 15;
  int n = n0 + r;
  float4 e = cand[n];
  float best[8];
  #pragma unroll
  for (int i=0;i<8;++i) best[i] = BIG_;
  int base = qq * 256;
  #pragma unroll 4
  for (int i = 0; i < 256; ++i) {
    int m = base + ((i + qq) & 255);
    float4 c = cand[m];
    float dx = c.x - e.x, dy = c.y - e.y, dz = c.z - e.z;
    float d2 = dx*dx + dy*dy + dz*dz + c.w;
    if (m == n) d2 = BIG_;
    if (d2 < best[7]) {
      #pragma unroll
      for (int i2 = 7; i2 >= 1; --i2)
        best[i2] = (best[i2] > d2) ? ((best[i2-1] > d2) ? best[i2-1] : d2) : best[i2];
      best[0] = (best[0] > d2) ? d2 : best[0];
    }
  }
  #pragma unroll
  for (int mk = 1; mk <= 8; mk <<= 1) {
    float ob[8];
    #pragma unroll
    for (int i = 0; i < 8; ++i) ob[i] = __shfl_xor(best[7-i], mk);
    #pragma unroll
    for (int i = 0; i < 8; ++i) best[i] = fminf(best[i], ob[i]);
    #pragma unroll
    for (int i = 0; i < 4; ++i) {
      float lo = fminf(best[i], best[i+4]);
      float hi = fmaxf(best[i], best[i+4]);
      best[i] = lo; best[i+4] = hi;
    }
    #pragma unroll
    for (int gI = 0; gI < 2; ++gI) {
      int o = gI*4;
      float lo0 = fminf(best[o+0], best[o+2]);
      float hi0 = fmaxf(best[o+0], best[o+2]);
      float lo1 = fminf(best[o+1], best[o+3]);
      float hi1 = fmaxf(best[o+1], best[o+3]);
      best[o+0]=lo0; best[o+2]=hi0; best[o+1]=lo1; best[o+3]=hi1;
    }
    #pragma unroll
    for (int p = 0; p < 8; p += 2) {
      float lo = fminf(best[p], best[p+1]);
      float hi = fmaxf(best[p], best[p+1]);
      best[p] = lo; best[p+1] = hi;
    }
  }
  if (qq == 0) {
    float ssum = 0.f;
    #pragma unroll
    for (int i = 0; i < 8; ++i) ssum += sqrtf(fmaxf(best[i], 0.f));
    float sigma = fminf(fmaxf(ALPHA_ * (ssum * 0.125f), SFLOOR_), SCEIL_);
    float s2 = sigma*sigma + JITTER_;
    size_t row = (size_t)b*N_ + n;
    float nmv = nmB[n];
    size_t orow = row * 396;
    const float* sg = &sigpc[row*9];
    #pragma unroll
    for (int e2=0;e2<9;++e2) {
      bool diag = (e2==0)||(e2==4)||(e2==8);
      float v = BETA_*sg[e2] + (diag ? ((1.0f-BETA_)*s2 + JITTER_) : 0.0f);
      out[orow + 387 + e2] = v * nmv;
    }
    out[orow + 384] = e.x;
    out[orow + 385] = e.y;
    out[orow + 386] = e.z;
  }
}

extern "C" void kernel_launch(void* const* d_in, const int* in_sizes, int n_in,
                              void* d_out, int out_size, void* d_ws, size_t ws_size,
                              hipStream_t stream) {
  const float* s_parent    = (const float*)d_in[0];
  const float* mu_p        = (const float*)d_in[1];
  const float* Sig_p       = (const float*)d_in[2];
  const float* mask_parent = (const float*)d_in[3];
  const float* node_mask   = (const float*)d_in[4];
  const float* s_trunk     = (const float*)d_in[5];
  const float* Wq   = (const float*)d_in[6];
  const float* Wk   = (const float*)d_in[7];
  const float* Wv   = (const float*)d_in[8];
  const float* Wpos = (const float*)d_in[9];
  const float* lnq_g = (const float*)d_in[10];
  const float* lnq_b = (const float*)d_in[11];
  const float* lnk_g = (const float*)d_in[12];
  const float* lnk_b = (const float*)d_in[13];
  const float* lnv_g = (const float*)d_in[14];
  const float* lnv_b = (const float*)d_in[15];
  const float* mo_ln_g = (const float*)d_in[16];
  const float* mo_ln_b = (const float*)d_in[17];
  const float* mo_W1 = (const float*)d_in[18];
  const float* mo_b1 = (const float*)d_in[19];
  const float* mo_W2 = (const float*)d_in[20];
  const float* mo_b2 = (const float*)d_in[21];

  char* wsb = (char*)d_ws;
  u16* qhi  = (u16*)wsb;
  u16* qlo  = qhi + (size_t)B_*N_*C_;
  u16* khi  = (u16*)(wsb + 25165824);
  u16* klo  = khi + (size_t)B_*KP*C_;
  u16* vthi = (u16*)(wsb + 25165824 + 3145728);
  u16* vtlo = vthi + (size_t)B_*C_*KP;
  char* pfb = wsb + 25165824 + 2*3145728;
  u16* pf   = (u16*)pfb;
  u16* spt  = (u16*)(pfb + 12582912);
  char* pw  = pfb + 12582912 + 1572864;
  u16* wqhi  = (u16*)pw;                         // 294912 B each
  u16* wqlo  = (u16*)(pw + 294912);
  u16* wkhi  = (u16*)(pw + 589824);
  u16* wklo  = (u16*)(pw + 884736);
  u16* wvhi  = (u16*)(pw + 1179648);
  u16* wvlo  = (u16*)(pw + 1474560);
  u16* mshi  = (u16*)(pw + 1769472);             // 65536 B
  u16* mslo  = mshi + (size_t)B_*16*64*8;        // 65536 B
  u16* w1hi  = (u16*)(wsb + 25165824);           // reuses K region after k_route
  u16* w1lo  = w1hi + (size_t)C_*C_;
  float* mu0 = (float*)(wsb + 25165824 + 2*3145728 + 25165824);
  float* sg  = mu0 + (size_t)B_*N_*3;
  float* out = (float*)d_out;

  k_wpack<<<dim3(24), dim3(256), 0, stream>>>(Wq, wqhi, wqlo);
  k_wpack<<<dim3(24), dim3(256), 0, stream>>>(Wk, wkhi, wklo);
  k_wpack<<<dim3(24), dim3(256), 0, stream>>>(Wv, wvhi, wvlo);
  k_sptr<<<dim3(KP/32, C_/32, B_), dim3(256), 0, stream>>>(s_parent, spt);
  k_musig<<<dim3(B_), dim3(256), 0, stream>>>(mu_p, Sig_p, mshi, mslo);

  k_kvproj<<<dim3(B_*KP/16), dim3(256), 0, stream>>>(
      s_parent, mu_p, lnk_g, lnk_b, lnv_g, lnv_b,
      wkhi, wklo, wvhi, wvlo, Wpos,
      khi, klo, vthi, vtlo);
  k_qproj<<<dim3(B_*N_/16), dim3(256), 0, stream>>>(
      s_trunk, lnq_g, lnq_b, wqhi, wqlo, qhi, qlo);
  k_route<<<dim3(N_/32, B_), dim3(256), 0, stream>>>(
      qhi, qlo, khi, klo, vthi, vtlo, spt, mshi, mslo,
      mask_parent, node_mask, out, pf, mu0, sg);
  k_wpack<<<dim3(24), dim3(256), 0, stream>>>(mo_W1, w1hi, w1lo);
  k_mlp<<<dim3(B_*N_/16), dim3(256), 0, stream>>>(
      pf, mo_ln_g, mo_ln_b, w1hi, w1lo, mo_b1, mo_W2, mo_b2, node_mask, mu0);
  k_knn<<<dim3(N_/32, B_), dim3(512), 0, stream>>>(
      mu0, node_mask, sg, out);
}